// Round 12
// baseline (899.882 us; speedup 1.0000x reference)
//
#include <hip/hip_runtime.h>
#include <hip/hip_bf16.h>

typedef short bf16x8 __attribute__((ext_vector_type(8)));
typedef float f32x4 __attribute__((ext_vector_type(4)));

// ---------------- problem sizes ----------------
#define NB   4096
#define NEXP 16
#define DDIM 256
#define HDIM 1024
#define NCLS 1000

// ---------------- workspace layout (bytes) ----------------
#define OFF_B    ((size_t)0)
#define OFF_P0   ((size_t)0)           // f32 [4096][256] FC partial (K half 0)
#define OFF_P1   ((size_t)4194304)     // f32 [4096][256] FC partial (K half 1)
// MoE packed/split weights (written after conv3, when Bb is dead; after P0/P1):
#define OFF_W1TH ((size_t)8388608)     // bf16 packed [16][64 ht][8 ks][64 lane][8]  8 MB
#define OFF_W1TL ((size_t)16777216)
#define OFF_W2TH ((size_t)25165824)    // bf16 packed [16][16 dt][32 ks][64 lane][8] 8 MB
#define OFF_W2TL ((size_t)33554432)
#define OFF_C    ((size_t)67108864)    // conv3 out f32 [4096][2048]; ALSO wBh/wBl/wA1 before conv12
#define OFF_WBL  ((size_t)67145728)    // OFF_C + 36864
#define OFF_WA1H ((size_t)67182592)    // OFF_C + 73728 (2 KB)
#define OFF_WA1L ((size_t)67184640)    // +2 KB
#define OFF_FEAT ((size_t)100663296)   // f32 [4096][256]; ALSO wAh/wAl (288 KB) before k_gate
#define OFF_WAL  ((size_t)100810752)   // OFF_FEAT + 147456
#define OFF_MOE  ((size_t)104857600)   // f32 [4096][256]
#define OFF_CNT  ((size_t)109051904)   // int [16]
#define OFF_GSUM ((size_t)109051968)   // f32 [16]
#define OFF_LROW ((size_t)109052032)   // int [16][4096]
#define OFF_LG   ((size_t)109314176)   // f32 [16][4096]

__device__ inline unsigned short f2bf(float v) {
  __hip_bfloat16 h = __float2bfloat16(v);
  return *(unsigned short*)&h;
}
__device__ inline float bf2f(unsigned short u) {
  union { unsigned int i; float f; } c; c.i = ((unsigned int)u) << 16; return c.f;
}

// ====== conv1 weight prep: c1w[oc][27] -> wA1[oc][32 K] bf16 hi/lo (K=ic*9+tap, pad 32)
__global__ __launch_bounds__(256) void k_wt1b(const float* __restrict__ w,
    unsigned short* __restrict__ oh, unsigned short* __restrict__ ol) {
  int i = blockIdx.x*256 + threadIdx.x;   // over 32*32 = 1024
  if (i >= 1024) return;
  int k = i & 31, oc = i >> 5;
  float v = (k < 27) ? w[oc*27 + k] : 0.f;
  unsigned short h = f2bf(v);
  oh[i] = h;
  ol[i] = f2bf(v - bf2f(h));
}

// ====== conv2 weight prep: c2w[oc][ic][tap] -> wBh/wBl[tap][oc][ic] bf16 hi/lo ======
__global__ __launch_bounds__(256) void k_wt2b(const float* __restrict__ w,
    unsigned short* __restrict__ wBh, unsigned short* __restrict__ wBl) {
  int i = blockIdx.x*256 + threadIdx.x;   // over 9*64*32 = 18432
  if (i >= 9*64*32) return;
  int ic = i & 31, rem = i >> 5;
  int oc = rem & 63, tap = rem >> 6;
  float v = w[(oc*32 + ic)*9 + tap];
  unsigned short h = f2bf(v);
  wBh[i] = h;
  wBl[i] = f2bf(v - bf2f(h));
}

// ====== MFMA-native weight pack: in[e][R=k][C=n] -> packed[e][n/16][R/32][64 lane][8] hi/lo
__global__ __launch_bounds__(256) void k_pack(const float* __restrict__ in,
    unsigned short* __restrict__ oh, unsigned short* __restrict__ ol, int R, int C) {
  __shared__ float tile[64][65];
  const int t = threadIdx.x;
  const int e = blockIdx.z;
  const size_t eb = (size_t)e * R * C;
  const int c0 = blockIdx.x*64, r0 = blockIdx.y*64;
  const int cc = t & 63, r4 = t >> 6;
  #pragma unroll
  for (int j = 0; j < 16; ++j) {
    int rr = r4 + j*4;
    tile[rr][cc] = in[eb + (size_t)(r0+rr)*C + c0 + cc];
  }
  __syncthreads();
  const int K32 = R >> 5;
  #pragma unroll
  for (int j = 0; j < 16; ++j) {
    int idx = t + j*256;
    int jin = idx & 7, lane = (idx >> 3) & 63, ksl = (idx >> 9) & 1, ntl = idx >> 10;
    int kl = ksl*32 + ((lane >> 4) << 3) + jin;
    int nl = ntl*16 + (lane & 15);
    float v = tile[kl][nl];
    unsigned short h = f2bf(v);
    size_t o = eb + ((size_t)(((c0 >> 4) + ntl)*K32 + (r0 >> 5) + ksl)*64 + lane)*8 + jin;
    oh[o] = h;
    ol[o] = f2bf(v - bf2f(h));
  }
}

// im2col octet builder: K0 compile-time -> all ic/tap static. k = ic*9+tap.
template<int K0>
__device__ inline void build_oct(const float (*xs)[34][36], int Y, int X,
                                 unsigned int* hw, unsigned int* lw) {
  #pragma unroll
  for (int jj = 0; jj < 4; ++jj) {
    unsigned short hh[2], ll[2];
    #pragma unroll
    for (int b = 0; b < 2; ++b) {
      const int k = K0 + jj*2 + b;
      float v = 0.f;
      if (k < 27) {
        const int ic = k/9, tap = k - ic*9, dy = tap/3, dx = tap - dy*3;
        v = xs[ic][Y+dy][X+dx];
      }
      unsigned short h = f2bf(v);
      hh[b] = h; ll[b] = f2bf(v - bf2f(h));
    }
    hw[jj] = (unsigned int)hh[0] | ((unsigned int)hh[1] << 16);
    lw[jj] = (unsigned int)ll[0] | ((unsigned int)ll[1] << 16);
  }
}

// ============ fused conv1(bf16x2 MFMA im2col) + conv2(bf16x2 MFMA, 3-term) per image ========
__global__ __launch_bounds__(512, 4) void k_conv12(const float* __restrict__ x,
    const unsigned short* __restrict__ wA1h, const unsigned short* __restrict__ wA1l,
    const float* __restrict__ b1,
    const unsigned short* __restrict__ wBh, const unsigned short* __restrict__ wBl,
    const float* __restrict__ b2, float* __restrict__ outB) {
  __shared__ float xs[3][34][36];           // padded input image (14.7 KB)
  __shared__ unsigned short ishB[2][10368]; // conv1-out hi/lo swizzled (41.5 KB); reused for store stage
  __shared__ __align__(16) unsigned short i2ch[4096];  // im2col hi [128 px][32 K] swizzled (8 KB)
  __shared__ __align__(16) unsigned short i2cl[4096];  // im2col lo (8 KB)
  __shared__ float bs1[32];
  __shared__ float bs2[64];
  const int t = threadIdx.x;
  const int img = blockIdx.x;
  for (int i = t; i < 3*34*36; i += 512) ((float*)xs)[i] = 0.f;
  {
    unsigned int* z = (unsigned int*)&ishB[0][0];
    for (int i = t; i < 10368; i += 512) z[i] = 0u;
  }
  __syncthreads();
  for (int i = t; i < 3072; i += 512) {
    int ic = i >> 10, rem = i & 1023, y = rem >> 5, xx = rem & 31;
    xs[ic][y+1][xx+1] = x[(size_t)img*3072 + i];
  }
  if (t < 32) bs1[t] = b1[t];
  else if (t >= 64 && t < 128) bs2[t-64] = b2[t-64];

  const int lane = t & 63, wvv = t >> 6;
  const int lr = lane & 15, lq = lane >> 4;

  // conv1 A-frags (weights) — resident in VGPRs all kernel
  const int oct1 = wvv & 1;
  const bf16x8 a1h = *(const bf16x8*)&wA1h[((oct1*16 + lr) << 5) + lq*8];
  const bf16x8 a1l = *(const bf16x8*)&wA1l[((oct1*16 + lr) << 5) + lq*8];
  __syncthreads();

  // ---- conv1 via MFMA: 8 passes of 4 pre-pool rows (128 px) ----
  {
    const int rp  = wvv >> 1;
    const int ly0 = (rp >> 1) << 1;      // 0 or 2
    const int xh  = rp & 1;
    const int koct = t >> 7;             // wave-uniform
    const int pixb = t & 127;
    const int bly = pixb >> 5, bX = pixb & 31;
    for (int ps = 0; ps < 8; ++ps) {
      if (ps) __syncthreads();           // prev pass consumers done with i2c
      // build im2col for rows ps*4 .. ps*4+3
      {
        const int Y = ps*4 + bly;
        unsigned int hw[4], lw[4];
        if      (koct == 0) build_oct<0 >(xs, Y, bX, hw, lw);
        else if (koct == 1) build_oct<8 >(xs, Y, bX, hw, lw);
        else if (koct == 2) build_oct<16>(xs, Y, bX, hw, lw);
        else                build_oct<24>(xs, Y, bX, hw, lw);
        const int slot = pixb*4 + (koct ^ (pixb & 3));
        *reinterpret_cast<uint4*>(&i2ch[slot << 3]) = make_uint4(hw[0],hw[1],hw[2],hw[3]);
        *reinterpret_cast<uint4*>(&i2cl[slot << 3]) = make_uint4(lw[0],lw[1],lw[2],lw[3]);
      }
      __syncthreads();
      // consume: wave = (oct1, row-pair ly0/ly0+1, col-half xh)
      {
        const int ptA = ly0*2 + xh, ptB = (ly0+1)*2 + xh;
        const int pA = ptA*16 + lr, pB = ptB*16 + lr;
        const bf16x8 bhA = *(const bf16x8*)&i2ch[(pA*4 + (lq ^ (pA & 3))) << 3];
        const bf16x8 blA = *(const bf16x8*)&i2cl[(pA*4 + (lq ^ (pA & 3))) << 3];
        const bf16x8 bhB = *(const bf16x8*)&i2ch[(pB*4 + (lq ^ (pB & 3))) << 3];
        const bf16x8 blB = *(const bf16x8*)&i2cl[(pB*4 + (lq ^ (pB & 3))) << 3];
        f32x4 aA = (f32x4){0.f,0.f,0.f,0.f}, aB = (f32x4){0.f,0.f,0.f,0.f};
        aA = __builtin_amdgcn_mfma_f32_16x16x32_bf16(a1h, bhA, aA, 0, 0, 0);
        aB = __builtin_amdgcn_mfma_f32_16x16x32_bf16(a1h, bhB, aB, 0, 0, 0);
        aA = __builtin_amdgcn_mfma_f32_16x16x32_bf16(a1h, blA, aA, 0, 0, 0);
        aB = __builtin_amdgcn_mfma_f32_16x16x32_bf16(a1h, blB, aB, 0, 0, 0);
        aA = __builtin_amdgcn_mfma_f32_16x16x32_bf16(a1l, bhA, aA, 0, 0, 0);
        aB = __builtin_amdgcn_mfma_f32_16x16x32_bf16(a1l, bhB, aB, 0, 0, 0);
        #pragma unroll
        for (int r = 0; r < 4; ++r) {
          float v = fmaxf(aA[r], aB[r]);           // y-pool (row pair in-thread)
          v = fmaxf(v, __shfl_xor(v, 1, 64));      // x-pool (col pair)
          if ((lr & 1) == 0) {
            int oc = oct1*16 + lq*4 + r;           // D row = (lane>>4)*4+reg
            int Xp = xh*8 + (lr >> 1);
            int Yp = ps*2 + (ly0 >> 1);
            float m = fmaxf(v + bs1[oc], 0.f);
            unsigned short h = f2bf(m);
            unsigned short l = f2bf(m - bf2f(h));
            int pl = (Yp+1)*18 + (Xp+1);
            int sl = pl*4 + ((oc >> 3) ^ ((pl >> 1) & 3));
            int us = (sl << 3) | (oc & 7);
            ishB[0][us] = h; ishB[1][us] = l;
          }
        }
      }
    }
  }
  __syncthreads();
  // ---- conv2 bf16x2 MFMA (3-term) + fused pool + relu ----
  {
    const int mtp = (wvv & 1)*2;
    const int rq = wvv >> 1;
    f32x4 acc[2][4];
    #pragma unroll
    for (int i = 0; i < 2; ++i)
      #pragma unroll
      for (int j = 0; j < 4; ++j) acc[i][j] = (f32x4){0.f,0.f,0.f,0.f};
    bf16x8 nAh[2], nAl[2];
    #pragma unroll
    for (int m = 0; m < 2; ++m) {
      int off = (((mtp+m)*16 + lr) << 5) + lq*8;
      nAh[m] = *(const bf16x8*)&wBh[off];
      nAl[m] = *(const bf16x8*)&wBl[off];
    }
    #pragma unroll
    for (int tap = 0; tap < 9; ++tap) {
      bf16x8 ah0 = nAh[0], al0 = nAl[0], ah1 = nAh[1], al1 = nAl[1];
      if (tap < 8) {
        #pragma unroll
        for (int m = 0; m < 2; ++m) {
          int off = (((tap+1)*64 + (mtp+m)*16 + lr) << 5) + lq*8;
          nAh[m] = *(const bf16x8*)&wBh[off];
          nAl[m] = *(const bf16x8*)&wBl[off];
        }
      }
      const int dy = tap/3, dx = tap - dy*3;
      #pragma unroll
      for (int j = 0; j < 4; ++j) {
        int pl = (rq*4 + j + dy)*18 + lr + dx;
        int sl = pl*4 + (lq ^ ((pl >> 1) & 3));
        bf16x8 bh = *(const bf16x8*)&ishB[0][sl << 3];
        bf16x8 bl = *(const bf16x8*)&ishB[1][sl << 3];
        acc[0][j] = __builtin_amdgcn_mfma_f32_16x16x32_bf16(ah0, bh, acc[0][j], 0, 0, 0);
        acc[1][j] = __builtin_amdgcn_mfma_f32_16x16x32_bf16(ah1, bh, acc[1][j], 0, 0, 0);
        acc[0][j] = __builtin_amdgcn_mfma_f32_16x16x32_bf16(ah0, bl, acc[0][j], 0, 0, 0);
        acc[1][j] = __builtin_amdgcn_mfma_f32_16x16x32_bf16(ah1, bl, acc[1][j], 0, 0, 0);
        acc[0][j] = __builtin_amdgcn_mfma_f32_16x16x32_bf16(al0, bh, acc[0][j], 0, 0, 0);
        acc[1][j] = __builtin_amdgcn_mfma_f32_16x16x32_bf16(al1, bh, acc[1][j], 0, 0, 0);
      }
    }
    __syncthreads();
    float* ps2 = (float*)&ishB[0][0];   // [64 oc][65] padded
    #pragma unroll
    for (int m = 0; m < 2; ++m)
      #pragma unroll
      for (int k = 0; k < 2; ++k)
        #pragma unroll
        for (int r = 0; r < 4; ++r) {
          float v = fmaxf(acc[m][2*k][r], acc[m][2*k+1][r]);
          v = fmaxf(v, __shfl_xor(v, 1, 64));
          if ((lr & 1) == 0) {
            int oc = (mtp + m)*16 + lq*4 + r;
            int Y = rq*2 + k, X = lr >> 1;
            ps2[oc*65 + Y*8 + X] = fmaxf(v + bs2[oc], 0.f);
          }
        }
    __syncthreads();
    float* op = outB + (size_t)img*4096;
    #pragma unroll
    for (int jj = 0; jj < 8; ++jj) {
      int i = jj*512 + t;
      op[i] = ps2[(i >> 6)*65 + (i & 63)];
    }
  }
}

// ================= conv3 weight prep: c3w[oc][ic][tap] -> wAh/wAl[tap][oc][ic] bf16 hi/lo
__global__ __launch_bounds__(256) void k_wt3b(const float* __restrict__ w,
    unsigned short* __restrict__ wAh, unsigned short* __restrict__ wAl) {
  int i = blockIdx.x*256 + threadIdx.x;   // over 9*128*64 = 73728
  if (i >= 9*128*64) return;
  int ic = i & 63, rem = i >> 6;
  int oc = rem & 127, tap = rem >> 7;
  float v = w[(oc*64 + ic)*9 + tap];
  unsigned short h = f2bf(v);
  wAh[i] = h;
  wAl[i] = f2bf(v - bf2f(h));
}

// ================= conv3 v4: bf16x2 split MFMA (3-term) implicit GEMM ==================
__global__ __launch_bounds__(256) void k_conv3(const float* __restrict__ inB,
    const unsigned short* __restrict__ wAh, const unsigned short* __restrict__ wAl,
    const float* __restrict__ bias, float* __restrict__ outC) {
  __shared__ unsigned short ish[2][6400];
  const int t = threadIdx.x;
  const int img = blockIdx.x;
  {
    unsigned int* z = (unsigned int*)&ish[0][0];
    #pragma unroll
    for (int j = 0; j < 25; ++j) z[t + 256*j] = 0u;
  }
  __syncthreads();
  {
    const float* src = inB + (size_t)img*4096;
    #pragma unroll
    for (int j = 0; j < 16; ++j) {
      int f = t + 256*j;
      int ic = f >> 6, p = f & 63;
      int pl = ((p >> 3) + 1)*10 + (p & 7) + 1;
      float v = src[f];
      unsigned short h = f2bf(v);
      unsigned short l = f2bf(v - bf2f(h));
      int u = pl*64 + ic;
      int us = (((u >> 3) ^ (pl & 7)) << 3) | (u & 7);
      ish[0][us] = h; ish[1][us] = l;
    }
  }
  __syncthreads();

  const int lane = t & 63, wid = t >> 6;
  const int lr = lane & 15, lq = lane >> 4;
  const int mt0 = wid*2;
  const int yb = lr >> 3, xb = lr & 7;

  f32x4 acc[2][4];
  #pragma unroll
  for (int i = 0; i < 2; ++i)
    #pragma unroll
    for (int j = 0; j < 4; ++j) acc[i][j] = (f32x4){0.f,0.f,0.f,0.f};

  for (int tap = 0; tap < 9; ++tap) {
    const int dy = tap/3, dx = tap - dy*3;
    #pragma unroll
    for (int kc = 0; kc < 2; ++kc) {
      const int kb = kc*32 + lq*8;
      const int wbase = ((tap << 7) << 6) + kb;
      bf16x8 a0h = *(const bf16x8*)&wAh[wbase + ((mt0*16 + lr) << 6)];
      bf16x8 a0l = *(const bf16x8*)&wAl[wbase + ((mt0*16 + lr) << 6)];
      bf16x8 a1h = *(const bf16x8*)&wAh[wbase + (((mt0+1)*16 + lr) << 6)];
      bf16x8 a1l = *(const bf16x8*)&wAl[wbase + (((mt0+1)*16 + lr) << 6)];
      #pragma unroll
      for (int nt = 0; nt < 4; ++nt) {
        const int pl = (2*nt + yb + dy)*10 + xb + dx;
        const int u = pl*64 + kb;
        const int us = (((u >> 3) ^ (pl & 7)) << 3);
        bf16x8 bh = *(const bf16x8*)&ish[0][us];
        bf16x8 bl = *(const bf16x8*)&ish[1][us];
        acc[0][nt] = __builtin_amdgcn_mfma_f32_16x16x32_bf16(a0h, bh, acc[0][nt], 0, 0, 0);
        acc[0][nt] = __builtin_amdgcn_mfma_f32_16x16x32_bf16(a0h, bl, acc[0][nt], 0, 0, 0);
        acc[0][nt] = __builtin_amdgcn_mfma_f32_16x16x32_bf16(a0l, bh, acc[0][nt], 0, 0, 0);
        acc[1][nt] = __builtin_amdgcn_mfma_f32_16x16x32_bf16(a1h, bh, acc[1][nt], 0, 0, 0);
        acc[1][nt] = __builtin_amdgcn_mfma_f32_16x16x32_bf16(a1h, bl, acc[1][nt], 0, 0, 0);
        acc[1][nt] = __builtin_amdgcn_mfma_f32_16x16x32_bf16(a1l, bh, acc[1][nt], 0, 0, 0);
      }
    }
  }
  __syncthreads();
  float* stg = (float*)&ish[0][0];   // [128 oc][17]
  #pragma unroll
  for (int mtl = 0; mtl < 2; ++mtl)
    #pragma unroll
    for (int nt = 0; nt < 4; ++nt)
      #pragma unroll
      for (int r = 0; r < 4; ++r) {
        float v = acc[mtl][nt][r];
        v = fmaxf(v, __shfl_xor(v, 1, 64));
        v = fmaxf(v, __shfl_xor(v, 8, 64));
        if ((lane & 9) == 0) {
          int oc = (mt0 + mtl)*16 + lq*4 + r;
          int pix = nt*4 + (xb >> 1);
          stg[oc*17 + pix] = fmaxf(v + bias[oc], 0.f);
        }
      }
  __syncthreads();
  float* dst = outC + (size_t)img*2048;
  #pragma unroll
  for (int j = 0; j < 8; ++j) {
    int i = t + 256*j;
    dst[i] = stg[(i >> 4)*17 + (i & 15)];
  }
}

// ================= FC GEMM: [4096,2048] @ [2048,256], split-K=2, 64x64 tiles, 4x4 micro-tile
__global__ __launch_bounds__(256) void k_fc(const float* __restrict__ C,
    const float* __restrict__ fcw, float* __restrict__ P0, float* __restrict__ P1) {
  __shared__ float As[32][68];
  __shared__ float Bs[32][68];
  const int t = threadIdx.x;
  const int r0 = blockIdx.x * 64;
  const int nc = blockIdx.y * 64;
  const int kbase = blockIdx.z * 1024;
  float* __restrict__ P = blockIdx.z ? P1 : P0;
  const int tx = t & 15, ty = t >> 4;
  float acc[4][4];
  #pragma unroll
  for (int i = 0; i < 4; ++i)
    #pragma unroll
    for (int j = 0; j < 4; ++j) acc[i][j] = 0.f;
  const int ia0 = t*2, ia1 = t*2 + 1;
  for (int c = 0; c < 32; ++c) {
    const int k0 = kbase + c*32;
    __syncthreads();
    #pragma unroll
    for (int j = 0; j < 2; ++j) {
      int idx = (j ? ia1 : ia0);
      int row = idx >> 3, kq = idx & 7;
      float4 v = *(const float4*)&C[(size_t)(r0+row)*2048 + k0 + kq*4];
      As[kq*4+0][row] = v.x; As[kq*4+1][row] = v.y;
      As[kq*4+2][row] = v.z; As[kq*4+3][row] = v.w;
    }
    #pragma unroll
    for (int j = 0; j < 2; ++j) {
      int idx = (j ? ia1 : ia0);
      int krow = idx >> 4, c4 = idx & 15;
      float4 v = *(const float4*)&fcw[(size_t)(k0+krow)*256 + nc + c4*4];
      *(float4*)&Bs[krow][c4*4] = v;
    }
    __syncthreads();
    #pragma unroll 8
    for (int k = 0; k < 32; ++k) {
      float4 av = *(const float4*)&As[k][ty*4];
      float4 bv = *(const float4*)&Bs[k][tx*4];
      float a[4] = {av.x, av.y, av.z, av.w};
      float bbv[4] = {bv.x, bv.y, bv.z, bv.w};
      #pragma unroll
      for (int i = 0; i < 4; ++i)
        #pragma unroll
        for (int j = 0; j < 4; ++j)
          acc[i][j] = fmaf(a[i], bbv[j], acc[i][j]);
    }
  }
  #pragma unroll
  for (int i = 0; i < 4; ++i) {
    float4 v = make_float4(acc[i][0], acc[i][1], acc[i][2], acc[i][3]);
    *(float4*)&P[(size_t)(r0 + ty*4 + i)*256 + nc + tx*4] = v;
  }
}

// ================= gate: feat = P0+P1+fcb; logits; top-2 softmax; expert lists
__global__ __launch_bounds__(256) void k_gate(const float* __restrict__ P0,
    const float* __restrict__ P1, const float* __restrict__ fcb,
    const float* __restrict__ gw, const float* __restrict__ gb,
    float* __restrict__ feat, int* __restrict__ cnt, float* __restrict__ gsum,
    int* __restrict__ lrow, float* __restrict__ lg) {
  __shared__ float ft[16][256];
  __shared__ float lgs[16][16];
  __shared__ float gwl[4096];
  const int t = threadIdx.x;
  const int r0 = blockIdx.x * 16;
  for (int i = t; i < 4096; i += 256) gwl[i] = gw[i];
  float bb = fcb[t];
  #pragma unroll
  for (int r = 0; r < 16; ++r) {
    size_t off = (size_t)(r0+r)*256 + t;
    float v = P0[off] + P1[off] + bb;
    ft[r][t] = v;
    feat[off] = v;
  }
  __syncthreads();
  {
    int r = t >> 4, e = t & 15;
    float s = gb[e];
    for (int k = 0; k < 256; ++k) s = fmaf(ft[r][k], gwl[k*16 + e], s);
    lgs[r][e] = s;
  }
  __syncthreads();
  if (t < 16) {
    int r = t;
    float v1 = -3.402823e38f, v2 = -3.402823e38f;
    int i1 = 0, i2 = 0;
    for (int e = 0; e < 16; ++e) {
      float v = lgs[r][e];
      if (v > v1)      { v2 = v1; i2 = i1; v1 = v; i1 = e; }
      else if (v > v2) { v2 = v;  i2 = e; }
    }
    float ex = __expf(v2 - v1);
    float g1 = 1.f / (1.f + ex);
    float g2 = ex  / (1.f + ex);
    int row = r0 + r;
    int p1 = atomicAdd(&cnt[i1], 1); lrow[i1*4096 + p1] = row; lg[i1*4096 + p1] = g1;
    int p2 = atomicAdd(&cnt[i2], 1); lrow[i2*4096 + p2] = row; lg[i2*4096 + p2] = g2;
    atomicAdd(&gsum[i1], g1);
    atomicAdd(&gsum[i2], g2);
  }
}

// ================= MoE v4: 32-row tiles x split-K(8), bf16x2 MFMA 3-term, packed weights
__global__ __launch_bounds__(256) void k_moe(const float* __restrict__ feat,
    const unsigned short* __restrict__ w1th, const unsigned short* __restrict__ w1tl,
    const unsigned short* __restrict__ w2th, const unsigned short* __restrict__ w2tl,
    const float* __restrict__ eb1, const float* __restrict__ eb2,
    const int* __restrict__ cnt, const int* __restrict__ lrow, const float* __restrict__ lgw,
    float* __restrict__ moe) {
  const int e = blockIdx.y;
  const int n_e = cnt[e];
  const int start = blockIdx.x * 32;
  if (start >= n_e) return;
  const int c = blockIdx.z;        // h-chunk this block owns
  const int n = min(32, n_e - start);
  __shared__ unsigned short fh[8192], fl[8192];   // [32 rows][256 k] swizzled
  __shared__ unsigned short h1h[4096], h1l[4096]; // [32 rows][128 h] swizzled
  __shared__ int   rws[32];
  __shared__ float gws[32];
  const int t = threadIdx.x;
  if (t < 32) {
    rws[t] = (t < n) ? lrow[e*4096 + start + t] : 0;
    gws[t] = (t < n) ? lgw[e*4096 + start + t] : 0.f;
  }
  __syncthreads();
  for (int j = 0; j < 32; ++j) {
    float v = (j < n) ? feat[(size_t)rws[j]*256 + t] : 0.f;
    unsigned short h = f2bf(v);
    int us = (j*32 + ((t >> 3) ^ (j & 7)))*8 + (t & 7);
    fh[us] = h; fl[us] = f2bf(v - bf2f(h));
  }
  const int lane = t & 63, wv = t >> 6;
  const int lr = lane & 15, lq = lane >> 4;
  const int rh = wv & 1, qh = wv >> 1;
  const int arow = rh*16 + lr;
  const int rsw = arow & 7;
  const size_t ewb = (size_t)e << 18;

  f32x4 acc2[8];
  #pragma unroll
  for (int i = 0; i < 8; ++i) acc2[i] = (f32x4){0.f,0.f,0.f,0.f};

  __syncthreads();

  {
    f32x4 acc1[4];
    #pragma unroll
    for (int i = 0; i < 4; ++i) acc1[i] = (f32x4){0.f,0.f,0.f,0.f};
    #pragma unroll
    for (int ks = 0; ks < 8; ++ks) {
      int aoff = (arow*32 + ((ks*4 + lq) ^ rsw))*8;
      bf16x8 ah = *(const bf16x8*)&fh[aoff];
      bf16x8 al = *(const bf16x8*)&fl[aoff];
      #pragma unroll
      for (int ht = 0; ht < 4; ++ht) {
        int htile = c*8 + qh*4 + ht;
        size_t bo = ewb + ((size_t)(htile*8 + ks)*64 + lane)*8;
        bf16x8 bh = *(const bf16x8*)&w1th[bo];
        bf16x8 bl = *(const bf16x8*)&w1tl[bo];
        acc1[ht] = __builtin_amdgcn_mfma_f32_16x16x32_bf16(ah, bh, acc1[ht], 0, 0, 0);
        acc1[ht] = __builtin_amdgcn_mfma_f32_16x16x32_bf16(ah, bl, acc1[ht], 0, 0, 0);
        acc1[ht] = __builtin_amdgcn_mfma_f32_16x16x32_bf16(al, bh, acc1[ht], 0, 0, 0);
      }
    }
    __syncthreads();
    #pragma unroll
    for (int ht = 0; ht < 4; ++ht) {
      int hloc = qh*64 + ht*16 + lr;
      float bb = eb1[e*1024 + c*128 + hloc];
      #pragma unroll
      for (int r = 0; r < 4; ++r) {
        int orow = rh*16 + lq*4 + r;
        float v = fmaxf(acc1[ht][r] + bb, 0.f);
        unsigned short hh = f2bf(v);
        int us = (orow*16 + ((hloc >> 3) ^ (orow & 7)))*8 + (hloc & 7);
        h1h[us] = hh; h1l[us] = f2bf(v - bf2f(hh));
      }
    }
    __syncthreads();
    #pragma unroll
    for (int ks = 0; ks < 4; ++ks) {
      int aoff = (arow*16 + ((ks*4 + lq) ^ rsw))*8;
      bf16x8 ah = *(const bf16x8*)&h1h[aoff];
      bf16x8 al = *(const bf16x8*)&h1l[aoff];
      #pragma unroll
      for (int dt = 0; dt < 8; ++dt) {
        int dtile = qh*8 + dt;
        size_t bo = ewb + ((size_t)(dtile*32 + c*4 + ks)*64 + lane)*8;
        bf16x8 bh = *(const bf16x8*)&w2th[bo];
        bf16x8 bl = *(const bf16x8*)&w2tl[bo];
        acc2[dt] = __builtin_amdgcn_mfma_f32_16x16x32_bf16(ah, bh, acc2[dt], 0, 0, 0);
        acc2[dt] = __builtin_amdgcn_mfma_f32_16x16x32_bf16(ah, bl, acc2[dt], 0, 0, 0);
        acc2[dt] = __builtin_amdgcn_mfma_f32_16x16x32_bf16(al, bh, acc2[dt], 0, 0, 0);
      }
    }
  }
  #pragma unroll
  for (int dt = 0; dt < 8; ++dt) {
    int d = qh*128 + dt*16 + lr;
    float b2 = (c == 0) ? eb2[e*256 + d] : 0.f;
    #pragma unroll
    for (int r = 0; r < 4; ++r) {
      int orow = rh*16 + lq*4 + r;
      if (orow < n)
        atomicAdd(&moe[(size_t)rws[orow]*256 + d], gws[orow]*(acc2[dt][r] + b2));
    }
  }
}

// ================= load-balance loss
__global__ void k_lb(const float* __restrict__ gsum, float* __restrict__ out_lb) {
  int t = threadIdx.x;
  float term = 0.f;
  if (t < 16) {
    float D = gsum[t] * (1.f/4096.f);
    term = D * logf(D + 1e-8f);
  }
  #pragma unroll
  for (int o = 8; o > 0; o >>= 1) term += __shfl_down(term, o, 64);
  if (t == 0) *out_lb = term;
}

// ================= LayerNorm(moe + feat) in-place into moe
__global__ __launch_bounds__(256) void k_ln(const float* __restrict__ feat,
    float* __restrict__ moe, const float* __restrict__ g, const float* __restrict__ bp) {
  const int r = blockIdx.x, t = threadIdx.x;
  float v = moe[(size_t)r*256 + t] + feat[(size_t)r*256 + t];
  float s = v, q = v * v;
  #pragma unroll
  for (int o = 32; o > 0; o >>= 1) {
    s += __shfl_down(s, o, 64);
    q += __shfl_down(q, o, 64);
  }
  __shared__ float ss[4], qq[4];
  int wv = t >> 6;
  if ((t & 63) == 0) { ss[wv] = s; qq[wv] = q; }
  __syncthreads();
  float S = ss[0]+ss[1]+ss[2]+ss[3];
  float Q = qq[0]+qq[1]+qq[2]+qq[3];
  float mu  = S * (1.f/256.f);
  float var = Q * (1.f/256.f) - mu*mu;
  float inv = rsqrtf(var + 1e-5f);
  moe[(size_t)r*256 + t] = (v - mu) * inv * g[t] + bp[t];
}

// ================= output GEMM: [4096,256] @ [256,1000] + b
__global__ __launch_bounds__(256) void k_out(const float* __restrict__ y,
    const float* __restrict__ ow, const float* __restrict__ ob,
    float* __restrict__ out) {
  __shared__ float ys[32][256];
  const int t = threadIdx.x;
  const int r0 = blockIdx.x * 32;
  const int c = blockIdx.y * 256 + t;
  for (int i = t; i < 32*256; i += 256) {
    int r = i >> 8, k = i & 255;
    ys[r][k] = y[(size_t)(r0+r)*256 + k];
  }
  __syncthreads();
  if (c >= NCLS) return;
  float acc[32];
  {
    float bb = ob[c];
    #pragma unroll
    for (int r = 0; r < 32; ++r) acc[r] = bb;
  }
  #pragma unroll 4
  for (int k = 0; k < 256; ++k) {
    float wv = ow[(size_t)k*NCLS + c];
    #pragma unroll
    for (int r = 0; r < 32; ++r) acc[r] = fmaf(ys[r][k], wv, acc[r]);
  }
  for (int r = 0; r < 32; ++r) out[(size_t)(r0+r)*NCLS + c] = acc[r];
}

// ================= launch =================
extern "C" void kernel_launch(void* const* d_in, const int* in_sizes, int n_in,
                              void* d_out, int out_size, void* d_ws, size_t ws_size,
                              hipStream_t stream) {
  const float* x   = (const float*)d_in[0];
  const float* c1w = (const float*)d_in[1];
  const float* c1b = (const float*)d_in[2];
  const float* c2w = (const float*)d_in[3];
  const float* c2b = (const float*)d_in[4];
  const float* c3w = (const float*)d_in[5];
  const float* c3b = (const float*)d_in[6];
  const float* fcw = (const float*)d_in[7];
  const float* fcb = (const float*)d_in[8];
  const float* gw  = (const float*)d_in[9];
  const float* gb  = (const float*)d_in[10];
  const float* ew1 = (const float*)d_in[11];
  const float* eb1 = (const float*)d_in[12];
  const float* ew2 = (const float*)d_in[13];
  const float* eb2 = (const float*)d_in[14];
  const float* lng = (const float*)d_in[15];
  const float* lnb = (const float*)d_in[16];
  const float* ow  = (const float*)d_in[17];
  const float* ob  = (const float*)d_in[18];
  char* ws = (char*)d_ws;
  float* Bb   = (float*)(ws + OFF_B);
  float* P0   = (float*)(ws + OFF_P0);
  float* P1   = (float*)(ws + OFF_P1);
  float* C    = (float*)(ws + OFF_C);
  unsigned short* wBh = (unsigned short*)(ws + OFF_C);     // aliases C (C written after conv12)
  unsigned short* wBl = (unsigned short*)(ws + OFF_WBL);
  unsigned short* wA1h = (unsigned short*)(ws + OFF_WA1H);
  unsigned short* wA1l = (unsigned short*)(ws + OFF_WA1L);
  unsigned short* wAh = (unsigned short*)(ws + OFF_FEAT);  // aliases feat (written later)
  unsigned short* wAl = (unsigned short*)(ws + OFF_WAL);
  unsigned short* w1th = (unsigned short*)(ws + OFF_W1TH); // region dead after conv3
  unsigned short* w1tl = (unsigned short*)(ws + OFF_W1TL);
  unsigned short* w2th = (unsigned short*)(ws + OFF_W2TH);
  unsigned short* w2tl = (unsigned short*)(ws + OFF_W2TL);
  float* feat = (float*)(ws + OFF_FEAT);
  float* moe  = (float*)(ws + OFF_MOE);
  int*   cnt  = (int*)(ws + OFF_CNT);
  float* gsum = (float*)(ws + OFF_GSUM);
  int*   lrow = (int*)(ws + OFF_LROW);
  float* lgv  = (float*)(ws + OFF_LG);
  float* outp = (float*)d_out;

  hipMemsetAsync(ws + OFF_MOE, 0, 4194304 + 128, stream);

  hipLaunchKernelGGL(k_wt1b,   dim3(4),       dim3(256), 0, stream, c1w, wA1h, wA1l);
  hipLaunchKernelGGL(k_wt2b,   dim3(72),      dim3(256), 0, stream, c2w, wBh, wBl);
  hipLaunchKernelGGL(k_wt3b,   dim3(288),     dim3(256), 0, stream, c3w, wAh, wAl);
  hipLaunchKernelGGL(k_conv12, dim3(4096),    dim3(512), 0, stream, x, wA1h, wA1l, c1b, wBh, wBl, c2b, Bb);
  hipLaunchKernelGGL(k_conv3,  dim3(4096),    dim3(256), 0, stream, Bb, wAh, wAl, c3b, C);
  // Bb dead now -> build MoE packed/split weights in its region
  hipLaunchKernelGGL(k_pack,   dim3(16, 4, 16), dim3(256), 0, stream, ew1, w1th, w1tl, 256, 1024);
  hipLaunchKernelGGL(k_pack,   dim3(4, 16, 16), dim3(256), 0, stream, ew2, w2th, w2tl, 1024, 256);
  hipLaunchKernelGGL(k_fc,     dim3(64, 4, 2),dim3(256), 0, stream, C, fcw, P0, P1);
  hipLaunchKernelGGL(k_gate,   dim3(256),     dim3(256), 0, stream, P0, P1, fcb, gw, gb,
                     feat, cnt, gsum, lrow, lgv);
  hipLaunchKernelGGL(k_moe,    dim3(128, 16, 8), dim3(256), 0, stream, feat, w1th, w1tl, w2th, w2tl,
                     eb1, eb2, cnt, lrow, lgv, moe);
  hipLaunchKernelGGL(k_lb,     dim3(1),       dim3(64),  0, stream, gsum, outp + (size_t)NB*NCLS);
  hipLaunchKernelGGL(k_ln,     dim3(4096),    dim3(256), 0, stream, feat, moe, lng, lnb);
  hipLaunchKernelGGL(k_out,    dim3(128, 4),  dim3(256), 0, stream, moe, ow, ob, outp);
}

// Round 13
// 860.886 us; speedup vs baseline: 1.0453x; 1.0453x over previous
//
#include <hip/hip_runtime.h>
#include <hip/hip_bf16.h>

typedef short bf16x8 __attribute__((ext_vector_type(8)));
typedef float f32x4 __attribute__((ext_vector_type(4)));

// ---------------- problem sizes ----------------
#define NB   4096
#define NEXP 16
#define DDIM 256
#define HDIM 1024
#define NCLS 1000

// ---------------- workspace layout (bytes) ----------------
#define OFF_B    ((size_t)0)
#define OFF_P0   ((size_t)0)           // f32 [4096][256] FC partial (kq 0)
#define OFF_P1   ((size_t)4194304)     // f32 [4096][256] FC partial (kq 1)
// MoE packed/split weights (written after conv3, when Bb is dead):
#define OFF_W1TH ((size_t)8388608)     // bf16 packed [16][64 ht][8 ks][64 lane][8]  8 MB
#define OFF_W1TL ((size_t)16777216)
#define OFF_W2TH ((size_t)25165824)    // bf16 packed [16][16 dt][32 ks][64 lane][8] 8 MB
#define OFF_W2TL ((size_t)33554432)
#define OFF_WFCH ((size_t)41943040)    // fcw packed hi (1 MB)
#define OFF_WFCL ((size_t)42991616)    // fcw packed lo (1 MB)
#define OFF_P2   ((size_t)44040192)    // f32 [4096][256] FC partial (kq 2)
#define OFF_P3   ((size_t)48234496)    // f32 [4096][256] FC partial (kq 3)
#define OFF_CHH  ((size_t)67108864)    // conv3 out hi bf16 [4096][2048] (16.8 MB); ALSO wBh/wBl/wA1 before conv12
#define OFF_CHL  ((size_t)83886080)    // conv3 out lo bf16
#define OFF_WBL  ((size_t)67145728)    // OFF_CHH + 36864
#define OFF_WA1H ((size_t)67182592)
#define OFF_WA1L ((size_t)67184640)
#define OFF_FEAT ((size_t)100663296)   // f32 [4096][256]; ALSO wAh/wAl (288 KB) before k_gate
#define OFF_WAL  ((size_t)100810752)
#define OFF_MOE  ((size_t)104857600)   // f32 [4096][256]
#define OFF_CNT  ((size_t)109051904)   // int [16]
#define OFF_GSUM ((size_t)109051968)   // f32 [16]
#define OFF_LROW ((size_t)109052032)   // int [16][4096]
#define OFF_LG   ((size_t)109314176)   // f32 [16][4096]

__device__ inline unsigned short f2bf(float v) {
  __hip_bfloat16 h = __float2bfloat16(v);
  return *(unsigned short*)&h;
}
__device__ inline float bf2f(unsigned short u) {
  union { unsigned int i; float f; } c; c.i = ((unsigned int)u) << 16; return c.f;
}

// ====== conv1 weight prep: c1w[oc][27] -> wA1[oc][32 K] bf16 hi/lo (K=ic*9+tap, pad 32)
__global__ __launch_bounds__(256) void k_wt1b(const float* __restrict__ w,
    unsigned short* __restrict__ oh, unsigned short* __restrict__ ol) {
  int i = blockIdx.x*256 + threadIdx.x;   // over 32*32 = 1024
  if (i >= 1024) return;
  int k = i & 31, oc = i >> 5;
  float v = (k < 27) ? w[oc*27 + k] : 0.f;
  unsigned short h = f2bf(v);
  oh[i] = h;
  ol[i] = f2bf(v - bf2f(h));
}

// ====== conv2 weight prep: c2w[oc][ic][tap] -> wBh/wBl[tap][oc][ic] bf16 hi/lo ======
__global__ __launch_bounds__(256) void k_wt2b(const float* __restrict__ w,
    unsigned short* __restrict__ wBh, unsigned short* __restrict__ wBl) {
  int i = blockIdx.x*256 + threadIdx.x;   // over 9*64*32 = 18432
  if (i >= 9*64*32) return;
  int ic = i & 31, rem = i >> 5;
  int oc = rem & 63, tap = rem >> 6;
  float v = w[(oc*32 + ic)*9 + tap];
  unsigned short h = f2bf(v);
  wBh[i] = h;
  wBl[i] = f2bf(v - bf2f(h));
}

// ====== MFMA-native weight pack: in[e][R=k][C=n] -> packed[e][n/16][R/32][64 lane][8] hi/lo
__global__ __launch_bounds__(256) void k_pack(const float* __restrict__ in,
    unsigned short* __restrict__ oh, unsigned short* __restrict__ ol, int R, int C) {
  __shared__ float tile[64][65];
  const int t = threadIdx.x;
  const int e = blockIdx.z;
  const size_t eb = (size_t)e * R * C;
  const int c0 = blockIdx.x*64, r0 = blockIdx.y*64;
  const int cc = t & 63, r4 = t >> 6;
  #pragma unroll
  for (int j = 0; j < 16; ++j) {
    int rr = r4 + j*4;
    tile[rr][cc] = in[eb + (size_t)(r0+rr)*C + c0 + cc];
  }
  __syncthreads();
  const int K32 = R >> 5;
  #pragma unroll
  for (int j = 0; j < 16; ++j) {
    int idx = t + j*256;
    int jin = idx & 7, lane = (idx >> 3) & 63, ksl = (idx >> 9) & 1, ntl = idx >> 10;
    int kl = ksl*32 + ((lane >> 4) << 3) + jin;
    int nl = ntl*16 + (lane & 15);
    float v = tile[kl][nl];
    unsigned short h = f2bf(v);
    size_t o = eb + ((size_t)(((c0 >> 4) + ntl)*K32 + (r0 >> 5) + ksl)*64 + lane)*8 + jin;
    oh[o] = h;
    ol[o] = f2bf(v - bf2f(h));
  }
}

// im2col octet builder: K0 compile-time -> all ic/tap static. k = ic*9+tap.
template<int K0>
__device__ inline void build_oct(const float (*xs)[34][36], int Y, int X,
                                 unsigned int* hw, unsigned int* lw) {
  #pragma unroll
  for (int jj = 0; jj < 4; ++jj) {
    unsigned short hh[2], ll[2];
    #pragma unroll
    for (int b = 0; b < 2; ++b) {
      const int k = K0 + jj*2 + b;
      float v = 0.f;
      if (k < 27) {
        const int ic = k/9, tap = k - ic*9, dy = tap/3, dx = tap - dy*3;
        v = xs[ic][Y+dy][X+dx];
      }
      unsigned short h = f2bf(v);
      hh[b] = h; ll[b] = f2bf(v - bf2f(h));
    }
    hw[jj] = (unsigned int)hh[0] | ((unsigned int)hh[1] << 16);
    lw[jj] = (unsigned int)ll[0] | ((unsigned int)ll[1] << 16);
  }
}

// ============ fused conv1(bf16x2 MFMA im2col) + conv2(bf16x2 MFMA, 3-term) per image ========
__global__ __launch_bounds__(512, 4) void k_conv12(const float* __restrict__ x,
    const unsigned short* __restrict__ wA1h, const unsigned short* __restrict__ wA1l,
    const float* __restrict__ b1,
    const unsigned short* __restrict__ wBh, const unsigned short* __restrict__ wBl,
    const float* __restrict__ b2, float* __restrict__ outB) {
  __shared__ float xs[3][34][36];
  __shared__ unsigned short ishB[2][10368];
  __shared__ __align__(16) unsigned short i2ch[4096];
  __shared__ __align__(16) unsigned short i2cl[4096];
  __shared__ float bs1[32];
  __shared__ float bs2[64];
  const int t = threadIdx.x;
  const int img = blockIdx.x;
  for (int i = t; i < 3*34*36; i += 512) ((float*)xs)[i] = 0.f;
  {
    unsigned int* z = (unsigned int*)&ishB[0][0];
    for (int i = t; i < 10368; i += 512) z[i] = 0u;
  }
  __syncthreads();
  for (int i = t; i < 3072; i += 512) {
    int ic = i >> 10, rem = i & 1023, y = rem >> 5, xx = rem & 31;
    xs[ic][y+1][xx+1] = x[(size_t)img*3072 + i];
  }
  if (t < 32) bs1[t] = b1[t];
  else if (t >= 64 && t < 128) bs2[t-64] = b2[t-64];

  const int lane = t & 63, wvv = t >> 6;
  const int lr = lane & 15, lq = lane >> 4;

  const int oct1 = wvv & 1;
  const bf16x8 a1h = *(const bf16x8*)&wA1h[((oct1*16 + lr) << 5) + lq*8];
  const bf16x8 a1l = *(const bf16x8*)&wA1l[((oct1*16 + lr) << 5) + lq*8];
  __syncthreads();

  // ---- conv1 via MFMA: 8 passes of 4 pre-pool rows (128 px) ----
  {
    const int rp  = wvv >> 1;
    const int ly0 = (rp >> 1) << 1;
    const int xh  = rp & 1;
    const int koct = t >> 7;
    const int pixb = t & 127;
    const int bly = pixb >> 5, bX = pixb & 31;
    for (int ps = 0; ps < 8; ++ps) {
      if (ps) __syncthreads();
      {
        const int Y = ps*4 + bly;
        unsigned int hw[4], lw[4];
        if      (koct == 0) build_oct<0 >(xs, Y, bX, hw, lw);
        else if (koct == 1) build_oct<8 >(xs, Y, bX, hw, lw);
        else if (koct == 2) build_oct<16>(xs, Y, bX, hw, lw);
        else                build_oct<24>(xs, Y, bX, hw, lw);
        const int slot = pixb*4 + (koct ^ (pixb & 3));
        *reinterpret_cast<uint4*>(&i2ch[slot << 3]) = make_uint4(hw[0],hw[1],hw[2],hw[3]);
        *reinterpret_cast<uint4*>(&i2cl[slot << 3]) = make_uint4(lw[0],lw[1],lw[2],lw[3]);
      }
      __syncthreads();
      {
        const int ptA = ly0*2 + xh, ptB = (ly0+1)*2 + xh;
        const int pA = ptA*16 + lr, pB = ptB*16 + lr;
        const bf16x8 bhA = *(const bf16x8*)&i2ch[(pA*4 + (lq ^ (pA & 3))) << 3];
        const bf16x8 blA = *(const bf16x8*)&i2cl[(pA*4 + (lq ^ (pA & 3))) << 3];
        const bf16x8 bhB = *(const bf16x8*)&i2ch[(pB*4 + (lq ^ (pB & 3))) << 3];
        const bf16x8 blB = *(const bf16x8*)&i2cl[(pB*4 + (lq ^ (pB & 3))) << 3];
        f32x4 aA = (f32x4){0.f,0.f,0.f,0.f}, aB = (f32x4){0.f,0.f,0.f,0.f};
        aA = __builtin_amdgcn_mfma_f32_16x16x32_bf16(a1h, bhA, aA, 0, 0, 0);
        aB = __builtin_amdgcn_mfma_f32_16x16x32_bf16(a1h, bhB, aB, 0, 0, 0);
        aA = __builtin_amdgcn_mfma_f32_16x16x32_bf16(a1h, blA, aA, 0, 0, 0);
        aB = __builtin_amdgcn_mfma_f32_16x16x32_bf16(a1h, blB, aB, 0, 0, 0);
        aA = __builtin_amdgcn_mfma_f32_16x16x32_bf16(a1l, bhA, aA, 0, 0, 0);
        aB = __builtin_amdgcn_mfma_f32_16x16x32_bf16(a1l, bhB, aB, 0, 0, 0);
        #pragma unroll
        for (int r = 0; r < 4; ++r) {
          float v = fmaxf(aA[r], aB[r]);
          v = fmaxf(v, __shfl_xor(v, 1, 64));
          if ((lr & 1) == 0) {
            int oc = oct1*16 + lq*4 + r;
            int Xp = xh*8 + (lr >> 1);
            int Yp = ps*2 + (ly0 >> 1);
            float m = fmaxf(v + bs1[oc], 0.f);
            unsigned short h = f2bf(m);
            unsigned short l = f2bf(m - bf2f(h));
            int pl = (Yp+1)*18 + (Xp+1);
            int sl = pl*4 + ((oc >> 3) ^ ((pl >> 1) & 3));
            int us = (sl << 3) | (oc & 7);
            ishB[0][us] = h; ishB[1][us] = l;
          }
        }
      }
    }
  }
  __syncthreads();
  // ---- conv2 bf16x2 MFMA (3-term) + fused pool + relu ----
  {
    const int mtp = (wvv & 1)*2;
    const int rq = wvv >> 1;
    f32x4 acc[2][4];
    #pragma unroll
    for (int i = 0; i < 2; ++i)
      #pragma unroll
      for (int j = 0; j < 4; ++j) acc[i][j] = (f32x4){0.f,0.f,0.f,0.f};
    bf16x8 nAh[2], nAl[2];
    #pragma unroll
    for (int m = 0; m < 2; ++m) {
      int off = (((mtp+m)*16 + lr) << 5) + lq*8;
      nAh[m] = *(const bf16x8*)&wBh[off];
      nAl[m] = *(const bf16x8*)&wBl[off];
    }
    #pragma unroll
    for (int tap = 0; tap < 9; ++tap) {
      bf16x8 ah0 = nAh[0], al0 = nAl[0], ah1 = nAh[1], al1 = nAl[1];
      if (tap < 8) {
        #pragma unroll
        for (int m = 0; m < 2; ++m) {
          int off = (((tap+1)*64 + (mtp+m)*16 + lr) << 5) + lq*8;
          nAh[m] = *(const bf16x8*)&wBh[off];
          nAl[m] = *(const bf16x8*)&wBl[off];
        }
      }
      const int dy = tap/3, dx = tap - dy*3;
      #pragma unroll
      for (int j = 0; j < 4; ++j) {
        int pl = (rq*4 + j + dy)*18 + lr + dx;
        int sl = pl*4 + (lq ^ ((pl >> 1) & 3));
        bf16x8 bh = *(const bf16x8*)&ishB[0][sl << 3];
        bf16x8 bl = *(const bf16x8*)&ishB[1][sl << 3];
        acc[0][j] = __builtin_amdgcn_mfma_f32_16x16x32_bf16(ah0, bh, acc[0][j], 0, 0, 0);
        acc[1][j] = __builtin_amdgcn_mfma_f32_16x16x32_bf16(ah1, bh, acc[1][j], 0, 0, 0);
        acc[0][j] = __builtin_amdgcn_mfma_f32_16x16x32_bf16(ah0, bl, acc[0][j], 0, 0, 0);
        acc[1][j] = __builtin_amdgcn_mfma_f32_16x16x32_bf16(ah1, bl, acc[1][j], 0, 0, 0);
        acc[0][j] = __builtin_amdgcn_mfma_f32_16x16x32_bf16(al0, bh, acc[0][j], 0, 0, 0);
        acc[1][j] = __builtin_amdgcn_mfma_f32_16x16x32_bf16(al1, bh, acc[1][j], 0, 0, 0);
      }
    }
    __syncthreads();
    float* ps2 = (float*)&ishB[0][0];
    #pragma unroll
    for (int m = 0; m < 2; ++m)
      #pragma unroll
      for (int k = 0; k < 2; ++k)
        #pragma unroll
        for (int r = 0; r < 4; ++r) {
          float v = fmaxf(acc[m][2*k][r], acc[m][2*k+1][r]);
          v = fmaxf(v, __shfl_xor(v, 1, 64));
          if ((lr & 1) == 0) {
            int oc = (mtp + m)*16 + lq*4 + r;
            int Y = rq*2 + k, X = lr >> 1;
            ps2[oc*65 + Y*8 + X] = fmaxf(v + bs2[oc], 0.f);
          }
        }
    __syncthreads();
    float* op = outB + (size_t)img*4096;
    #pragma unroll
    for (int jj = 0; jj < 8; ++jj) {
      int i = jj*512 + t;
      op[i] = ps2[(i >> 6)*65 + (i & 63)];
    }
  }
}

// ================= conv3 weight prep: c3w[oc][ic][tap] -> wAh/wAl[tap][oc][ic] bf16 hi/lo
__global__ __launch_bounds__(256) void k_wt3b(const float* __restrict__ w,
    unsigned short* __restrict__ wAh, unsigned short* __restrict__ wAl) {
  int i = blockIdx.x*256 + threadIdx.x;   // over 9*128*64 = 73728
  if (i >= 9*128*64) return;
  int ic = i & 63, rem = i >> 6;
  int oc = rem & 127, tap = rem >> 7;
  float v = w[(oc*64 + ic)*9 + tap];
  unsigned short h = f2bf(v);
  wAh[i] = h;
  wAl[i] = f2bf(v - bf2f(h));
}

// ================= conv3 v5: bf16x2 split MFMA (3-term); emits C as bf16 hi/lo ==========
__global__ __launch_bounds__(256) void k_conv3(const float* __restrict__ inB,
    const unsigned short* __restrict__ wAh, const unsigned short* __restrict__ wAl,
    const float* __restrict__ bias,
    unsigned short* __restrict__ Chh, unsigned short* __restrict__ Chl) {
  __shared__ unsigned short ish[2][6400];
  const int t = threadIdx.x;
  const int img = blockIdx.x;
  {
    unsigned int* z = (unsigned int*)&ish[0][0];
    #pragma unroll
    for (int j = 0; j < 25; ++j) z[t + 256*j] = 0u;
  }
  __syncthreads();
  {
    const float* src = inB + (size_t)img*4096;
    #pragma unroll
    for (int j = 0; j < 16; ++j) {
      int f = t + 256*j;
      int ic = f >> 6, p = f & 63;
      int pl = ((p >> 3) + 1)*10 + (p & 7) + 1;
      float v = src[f];
      unsigned short h = f2bf(v);
      unsigned short l = f2bf(v - bf2f(h));
      int u = pl*64 + ic;
      int us = (((u >> 3) ^ (pl & 7)) << 3) | (u & 7);
      ish[0][us] = h; ish[1][us] = l;
    }
  }
  __syncthreads();

  const int lane = t & 63, wid = t >> 6;
  const int lr = lane & 15, lq = lane >> 4;
  const int mt0 = wid*2;
  const int yb = lr >> 3, xb = lr & 7;

  f32x4 acc[2][4];
  #pragma unroll
  for (int i = 0; i < 2; ++i)
    #pragma unroll
    for (int j = 0; j < 4; ++j) acc[i][j] = (f32x4){0.f,0.f,0.f,0.f};

  for (int tap = 0; tap < 9; ++tap) {
    const int dy = tap/3, dx = tap - dy*3;
    #pragma unroll
    for (int kc = 0; kc < 2; ++kc) {
      const int kb = kc*32 + lq*8;
      const int wbase = ((tap << 7) << 6) + kb;
      bf16x8 a0h = *(const bf16x8*)&wAh[wbase + ((mt0*16 + lr) << 6)];
      bf16x8 a0l = *(const bf16x8*)&wAl[wbase + ((mt0*16 + lr) << 6)];
      bf16x8 a1h = *(const bf16x8*)&wAh[wbase + (((mt0+1)*16 + lr) << 6)];
      bf16x8 a1l = *(const bf16x8*)&wAl[wbase + (((mt0+1)*16 + lr) << 6)];
      #pragma unroll
      for (int nt = 0; nt < 4; ++nt) {
        const int pl = (2*nt + yb + dy)*10 + xb + dx;
        const int u = pl*64 + kb;
        const int us = (((u >> 3) ^ (pl & 7)) << 3);
        bf16x8 bh = *(const bf16x8*)&ish[0][us];
        bf16x8 bl = *(const bf16x8*)&ish[1][us];
        acc[0][nt] = __builtin_amdgcn_mfma_f32_16x16x32_bf16(a0h, bh, acc[0][nt], 0, 0, 0);
        acc[0][nt] = __builtin_amdgcn_mfma_f32_16x16x32_bf16(a0h, bl, acc[0][nt], 0, 0, 0);
        acc[0][nt] = __builtin_amdgcn_mfma_f32_16x16x32_bf16(a0l, bh, acc[0][nt], 0, 0, 0);
        acc[1][nt] = __builtin_amdgcn_mfma_f32_16x16x32_bf16(a1h, bh, acc[1][nt], 0, 0, 0);
        acc[1][nt] = __builtin_amdgcn_mfma_f32_16x16x32_bf16(a1h, bl, acc[1][nt], 0, 0, 0);
        acc[1][nt] = __builtin_amdgcn_mfma_f32_16x16x32_bf16(a1l, bh, acc[1][nt], 0, 0, 0);
      }
    }
  }
  __syncthreads();
  float* stg = (float*)&ish[0][0];   // [128 oc][17]
  #pragma unroll
  for (int mtl = 0; mtl < 2; ++mtl)
    #pragma unroll
    for (int nt = 0; nt < 4; ++nt)
      #pragma unroll
      for (int r = 0; r < 4; ++r) {
        float v = acc[mtl][nt][r];
        v = fmaxf(v, __shfl_xor(v, 1, 64));
        v = fmaxf(v, __shfl_xor(v, 8, 64));
        if ((lane & 9) == 0) {
          int oc = (mt0 + mtl)*16 + lq*4 + r;
          int pix = nt*4 + (xb >> 1);
          stg[oc*17 + pix] = fmaxf(v + bias[oc], 0.f);
        }
      }
  __syncthreads();
  #pragma unroll
  for (int j = 0; j < 8; ++j) {
    int i = t + 256*j;
    float v = stg[(i >> 4)*17 + (i & 15)];
    unsigned short h = f2bf(v);
    Chh[(size_t)img*2048 + i] = h;
    Chl[(size_t)img*2048 + i] = f2bf(v - bf2f(h));
  }
}

// ================= FC GEMM v2: bf16x2 3-term MFMA, no LDS, split-K=4 =================
// grid (128, 1, 4): 32 rows/block, full 256 cols, K-quarter kq. A from Chh/Chl (row-major,
// 16B frags), B from packed wfh/wfl. Partials to P[kq], summed in k_gate.
__global__ __launch_bounds__(256) void k_fc(const unsigned short* __restrict__ Chh,
    const unsigned short* __restrict__ Chl,
    const unsigned short* __restrict__ wfh, const unsigned short* __restrict__ wfl,
    float* __restrict__ P0, float* __restrict__ P1,
    float* __restrict__ P2, float* __restrict__ P3) {
  const int t = threadIdx.x;
  const int r0 = blockIdx.x * 32;
  const int kq = blockIdx.z;
  float* __restrict__ P = (kq == 0) ? P0 : (kq == 1) ? P1 : (kq == 2) ? P2 : P3;
  const int lane = t & 63, wv = t >> 6;
  const int lr = lane & 15, lq = lane >> 4;
  f32x4 acc[2][4];
  #pragma unroll
  for (int i = 0; i < 2; ++i)
    #pragma unroll
    for (int j = 0; j < 4; ++j) acc[i][j] = (f32x4){0.f,0.f,0.f,0.f};
  #pragma unroll 4
  for (int ks = 0; ks < 16; ++ks) {
    bf16x8 ah[2], al[2];
    #pragma unroll
    for (int rt = 0; rt < 2; ++rt) {
      size_t ao = (size_t)(r0 + rt*16 + lr)*2048 + kq*512 + ks*32 + lq*8;
      ah[rt] = *(const bf16x8*)&Chh[ao];
      al[rt] = *(const bf16x8*)&Chl[ao];
    }
    #pragma unroll
    for (int nt = 0; nt < 4; ++nt) {
      size_t bo = ((size_t)((wv*4 + nt)*64 + kq*16 + ks)*64 + lane)*8;
      bf16x8 bh = *(const bf16x8*)&wfh[bo];
      bf16x8 bl = *(const bf16x8*)&wfl[bo];
      acc[0][nt] = __builtin_amdgcn_mfma_f32_16x16x32_bf16(ah[0], bh, acc[0][nt], 0, 0, 0);
      acc[1][nt] = __builtin_amdgcn_mfma_f32_16x16x32_bf16(ah[1], bh, acc[1][nt], 0, 0, 0);
      acc[0][nt] = __builtin_amdgcn_mfma_f32_16x16x32_bf16(ah[0], bl, acc[0][nt], 0, 0, 0);
      acc[1][nt] = __builtin_amdgcn_mfma_f32_16x16x32_bf16(ah[1], bl, acc[1][nt], 0, 0, 0);
      acc[0][nt] = __builtin_amdgcn_mfma_f32_16x16x32_bf16(al[0], bh, acc[0][nt], 0, 0, 0);
      acc[1][nt] = __builtin_amdgcn_mfma_f32_16x16x32_bf16(al[1], bh, acc[1][nt], 0, 0, 0);
    }
  }
  #pragma unroll
  for (int rt = 0; rt < 2; ++rt)
    #pragma unroll
    for (int nt = 0; nt < 4; ++nt)
      #pragma unroll
      for (int r = 0; r < 4; ++r)
        P[(size_t)(r0 + rt*16 + lq*4 + r)*256 + (wv*4 + nt)*16 + lr] = acc[rt][nt][r];
}

// ================= gate: feat = P0+P1+P2+P3+fcb; logits; top-2 softmax; expert lists
__global__ __launch_bounds__(256) void k_gate(const float* __restrict__ P0,
    const float* __restrict__ P1, const float* __restrict__ P2, const float* __restrict__ P3,
    const float* __restrict__ fcb,
    const float* __restrict__ gw, const float* __restrict__ gb,
    float* __restrict__ feat, int* __restrict__ cnt, float* __restrict__ gsum,
    int* __restrict__ lrow, float* __restrict__ lg) {
  __shared__ float ft[16][256];
  __shared__ float lgs[16][16];
  __shared__ float gwl[4096];
  const int t = threadIdx.x;
  const int r0 = blockIdx.x * 16;
  for (int i = t; i < 4096; i += 256) gwl[i] = gw[i];
  float bb = fcb[t];
  #pragma unroll
  for (int r = 0; r < 16; ++r) {
    size_t off = (size_t)(r0+r)*256 + t;
    float v = P0[off] + P1[off] + P2[off] + P3[off] + bb;
    ft[r][t] = v;
    feat[off] = v;
  }
  __syncthreads();
  {
    int r = t >> 4, e = t & 15;
    float s = gb[e];
    for (int k = 0; k < 256; ++k) s = fmaf(ft[r][k], gwl[k*16 + e], s);
    lgs[r][e] = s;
  }
  __syncthreads();
  if (t < 16) {
    int r = t;
    float v1 = -3.402823e38f, v2 = -3.402823e38f;
    int i1 = 0, i2 = 0;
    for (int e = 0; e < 16; ++e) {
      float v = lgs[r][e];
      if (v > v1)      { v2 = v1; i2 = i1; v1 = v; i1 = e; }
      else if (v > v2) { v2 = v;  i2 = e; }
    }
    float ex = __expf(v2 - v1);
    float g1 = 1.f / (1.f + ex);
    float g2 = ex  / (1.f + ex);
    int row = r0 + r;
    int p1 = atomicAdd(&cnt[i1], 1); lrow[i1*4096 + p1] = row; lg[i1*4096 + p1] = g1;
    int p2 = atomicAdd(&cnt[i2], 1); lrow[i2*4096 + p2] = row; lg[i2*4096 + p2] = g2;
    atomicAdd(&gsum[i1], g1);
    atomicAdd(&gsum[i2], g2);
  }
}

// ================= MoE v4: 32-row tiles x split-K(8), bf16x2 MFMA 3-term, packed weights
__global__ __launch_bounds__(256) void k_moe(const float* __restrict__ feat,
    const unsigned short* __restrict__ w1th, const unsigned short* __restrict__ w1tl,
    const unsigned short* __restrict__ w2th, const unsigned short* __restrict__ w2tl,
    const float* __restrict__ eb1, const float* __restrict__ eb2,
    const int* __restrict__ cnt, const int* __restrict__ lrow, const float* __restrict__ lgw,
    float* __restrict__ moe) {
  const int e = blockIdx.y;
  const int n_e = cnt[e];
  const int start = blockIdx.x * 32;
  if (start >= n_e) return;
  const int c = blockIdx.z;
  const int n = min(32, n_e - start);
  __shared__ unsigned short fh[8192], fl[8192];
  __shared__ unsigned short h1h[4096], h1l[4096];
  __shared__ int   rws[32];
  __shared__ float gws[32];
  const int t = threadIdx.x;
  if (t < 32) {
    rws[t] = (t < n) ? lrow[e*4096 + start + t] : 0;
    gws[t] = (t < n) ? lgw[e*4096 + start + t] : 0.f;
  }
  __syncthreads();
  for (int j = 0; j < 32; ++j) {
    float v = (j < n) ? feat[(size_t)rws[j]*256 + t] : 0.f;
    unsigned short h = f2bf(v);
    int us = (j*32 + ((t >> 3) ^ (j & 7)))*8 + (t & 7);
    fh[us] = h; fl[us] = f2bf(v - bf2f(h));
  }
  const int lane = t & 63, wv = t >> 6;
  const int lr = lane & 15, lq = lane >> 4;
  const int rh = wv & 1, qh = wv >> 1;
  const int arow = rh*16 + lr;
  const int rsw = arow & 7;
  const size_t ewb = (size_t)e << 18;

  f32x4 acc2[8];
  #pragma unroll
  for (int i = 0; i < 8; ++i) acc2[i] = (f32x4){0.f,0.f,0.f,0.f};

  __syncthreads();

  {
    f32x4 acc1[4];
    #pragma unroll
    for (int i = 0; i < 4; ++i) acc1[i] = (f32x4){0.f,0.f,0.f,0.f};
    #pragma unroll
    for (int ks = 0; ks < 8; ++ks) {
      int aoff = (arow*32 + ((ks*4 + lq) ^ rsw))*8;
      bf16x8 ah = *(const bf16x8*)&fh[aoff];
      bf16x8 al = *(const bf16x8*)&fl[aoff];
      #pragma unroll
      for (int ht = 0; ht < 4; ++ht) {
        int htile = c*8 + qh*4 + ht;
        size_t bo = ewb + ((size_t)(htile*8 + ks)*64 + lane)*8;
        bf16x8 bh = *(const bf16x8*)&w1th[bo];
        bf16x8 bl = *(const bf16x8*)&w1tl[bo];
        acc1[ht] = __builtin_amdgcn_mfma_f32_16x16x32_bf16(ah, bh, acc1[ht], 0, 0, 0);
        acc1[ht] = __builtin_amdgcn_mfma_f32_16x16x32_bf16(ah, bl, acc1[ht], 0, 0, 0);
        acc1[ht] = __builtin_amdgcn_mfma_f32_16x16x32_bf16(al, bh, acc1[ht], 0, 0, 0);
      }
    }
    __syncthreads();
    #pragma unroll
    for (int ht = 0; ht < 4; ++ht) {
      int hloc = qh*64 + ht*16 + lr;
      float bb = eb1[e*1024 + c*128 + hloc];
      #pragma unroll
      for (int r = 0; r < 4; ++r) {
        int orow = rh*16 + lq*4 + r;
        float v = fmaxf(acc1[ht][r] + bb, 0.f);
        unsigned short hh = f2bf(v);
        int us = (orow*16 + ((hloc >> 3) ^ (orow & 7)))*8 + (hloc & 7);
        h1h[us] = hh; h1l[us] = f2bf(v - bf2f(hh));
      }
    }
    __syncthreads();
    #pragma unroll
    for (int ks = 0; ks < 4; ++ks) {
      int aoff = (arow*16 + ((ks*4 + lq) ^ rsw))*8;
      bf16x8 ah = *(const bf16x8*)&h1h[aoff];
      bf16x8 al = *(const bf16x8*)&h1l[aoff];
      #pragma unroll
      for (int dt = 0; dt < 8; ++dt) {
        int dtile = qh*8 + dt;
        size_t bo = ewb + ((size_t)(dtile*32 + c*4 + ks)*64 + lane)*8;
        bf16x8 bh = *(const bf16x8*)&w2th[bo];
        bf16x8 bl = *(const bf16x8*)&w2tl[bo];
        acc2[dt] = __builtin_amdgcn_mfma_f32_16x16x32_bf16(ah, bh, acc2[dt], 0, 0, 0);
        acc2[dt] = __builtin_amdgcn_mfma_f32_16x16x32_bf16(ah, bl, acc2[dt], 0, 0, 0);
        acc2[dt] = __builtin_amdgcn_mfma_f32_16x16x32_bf16(al, bh, acc2[dt], 0, 0, 0);
      }
    }
  }
  #pragma unroll
  for (int dt = 0; dt < 8; ++dt) {
    int d = qh*128 + dt*16 + lr;
    float b2 = (c == 0) ? eb2[e*256 + d] : 0.f;
    #pragma unroll
    for (int r = 0; r < 4; ++r) {
      int orow = rh*16 + lq*4 + r;
      if (orow < n)
        atomicAdd(&moe[(size_t)rws[orow]*256 + d], gws[orow]*(acc2[dt][r] + b2));
    }
  }
}

// ================= load-balance loss
__global__ void k_lb(const float* __restrict__ gsum, float* __restrict__ out_lb) {
  int t = threadIdx.x;
  float term = 0.f;
  if (t < 16) {
    float D = gsum[t] * (1.f/4096.f);
    term = D * logf(D + 1e-8f);
  }
  #pragma unroll
  for (int o = 8; o > 0; o >>= 1) term += __shfl_down(term, o, 64);
  if (t == 0) *out_lb = term;
}

// ================= LayerNorm(moe + feat) in-place into moe
__global__ __launch_bounds__(256) void k_ln(const float* __restrict__ feat,
    float* __restrict__ moe, const float* __restrict__ g, const float* __restrict__ bp) {
  const int r = blockIdx.x, t = threadIdx.x;
  float v = moe[(size_t)r*256 + t] + feat[(size_t)r*256 + t];
  float s = v, q = v * v;
  #pragma unroll
  for (int o = 32; o > 0; o >>= 1) {
    s += __shfl_down(s, o, 64);
    q += __shfl_down(q, o, 64);
  }
  __shared__ float ss[4], qq[4];
  int wv = t >> 6;
  if ((t & 63) == 0) { ss[wv] = s; qq[wv] = q; }
  __syncthreads();
  float S = ss[0]+ss[1]+ss[2]+ss[3];
  float Q = qq[0]+qq[1]+qq[2]+qq[3];
  float mu  = S * (1.f/256.f);
  float var = Q * (1.f/256.f) - mu*mu;
  float inv = rsqrtf(var + 1e-5f);
  moe[(size_t)r*256 + t] = (v - mu) * inv * g[t] + bp[t];
}

// ================= output GEMM: [4096,256] @ [256,1000] + b
__global__ __launch_bounds__(256) void k_out(const float* __restrict__ y,
    const float* __restrict__ ow, const float* __restrict__ ob,
    float* __restrict__ out) {
  __shared__ float ys[32][256];
  const int t = threadIdx.x;
  const int r0 = blockIdx.x * 32;
  const int c = blockIdx.y * 256 + t;
  for (int i = t; i < 32*256; i += 256) {
    int r = i >> 8, k = i & 255;
    ys[r][k] = y[(size_t)(r0+r)*256 + k];
  }
  __syncthreads();
  if (c >= NCLS) return;
  float acc[32];
  {
    float bb = ob[c];
    #pragma unroll
    for (int r = 0; r < 32; ++r) acc[r] = bb;
  }
  #pragma unroll 4
  for (int k = 0; k < 256; ++k) {
    float wv = ow[(size_t)k*NCLS + c];
    #pragma unroll
    for (int r = 0; r < 32; ++r) acc[r] = fmaf(ys[r][k], wv, acc[r]);
  }
  for (int r = 0; r < 32; ++r) out[(size_t)(r0+r)*NCLS + c] = acc[r];
}

// ================= launch =================
extern "C" void kernel_launch(void* const* d_in, const int* in_sizes, int n_in,
                              void* d_out, int out_size, void* d_ws, size_t ws_size,
                              hipStream_t stream) {
  const float* x   = (const float*)d_in[0];
  const float* c1w = (const float*)d_in[1];
  const float* c1b = (const float*)d_in[2];
  const float* c2w = (const float*)d_in[3];
  const float* c2b = (const float*)d_in[4];
  const float* c3w = (const float*)d_in[5];
  const float* c3b = (const float*)d_in[6];
  const float* fcw = (const float*)d_in[7];
  const float* fcb = (const float*)d_in[8];
  const float* gw  = (const float*)d_in[9];
  const float* gb  = (const float*)d_in[10];
  const float* ew1 = (const float*)d_in[11];
  const float* eb1 = (const float*)d_in[12];
  const float* ew2 = (const float*)d_in[13];
  const float* eb2 = (const float*)d_in[14];
  const float* lng = (const float*)d_in[15];
  const float* lnb = (const float*)d_in[16];
  const float* ow  = (const float*)d_in[17];
  const float* ob  = (const float*)d_in[18];
  char* ws = (char*)d_ws;
  float* Bb   = (float*)(ws + OFF_B);
  float* P0   = (float*)(ws + OFF_P0);
  float* P1   = (float*)(ws + OFF_P1);
  float* P2   = (float*)(ws + OFF_P2);
  float* P3   = (float*)(ws + OFF_P3);
  unsigned short* Chh = (unsigned short*)(ws + OFF_CHH);
  unsigned short* Chl = (unsigned short*)(ws + OFF_CHL);
  unsigned short* wBh = (unsigned short*)(ws + OFF_CHH);   // aliases Chh (written after conv12)
  unsigned short* wBl = (unsigned short*)(ws + OFF_WBL);
  unsigned short* wA1h = (unsigned short*)(ws + OFF_WA1H);
  unsigned short* wA1l = (unsigned short*)(ws + OFF_WA1L);
  unsigned short* wAh = (unsigned short*)(ws + OFF_FEAT);  // aliases feat (written later)
  unsigned short* wAl = (unsigned short*)(ws + OFF_WAL);
  unsigned short* w1th = (unsigned short*)(ws + OFF_W1TH); // region dead after conv3
  unsigned short* w1tl = (unsigned short*)(ws + OFF_W1TL);
  unsigned short* w2th = (unsigned short*)(ws + OFF_W2TH);
  unsigned short* w2tl = (unsigned short*)(ws + OFF_W2TL);
  unsigned short* wfh = (unsigned short*)(ws + OFF_WFCH);
  unsigned short* wfl = (unsigned short*)(ws + OFF_WFCL);
  float* feat = (float*)(ws + OFF_FEAT);
  float* moe  = (float*)(ws + OFF_MOE);
  int*   cnt  = (int*)(ws + OFF_CNT);
  float* gsum = (float*)(ws + OFF_GSUM);
  int*   lrow = (int*)(ws + OFF_LROW);
  float* lgv  = (float*)(ws + OFF_LG);
  float* outp = (float*)d_out;

  hipMemsetAsync(ws + OFF_MOE, 0, 4194304 + 128, stream);

  hipLaunchKernelGGL(k_wt1b,   dim3(4),       dim3(256), 0, stream, c1w, wA1h, wA1l);
  hipLaunchKernelGGL(k_wt2b,   dim3(72),      dim3(256), 0, stream, c2w, wBh, wBl);
  hipLaunchKernelGGL(k_wt3b,   dim3(288),     dim3(256), 0, stream, c3w, wAh, wAl);
  hipLaunchKernelGGL(k_conv12, dim3(4096),    dim3(512), 0, stream, x, wA1h, wA1l, c1b, wBh, wBl, c2b, Bb);
  hipLaunchKernelGGL(k_conv3,  dim3(4096),    dim3(256), 0, stream, Bb, wAh, wAl, c3b, Chh, Chl);
  // Bb dead now -> build MoE + FC packed/split weights
  hipLaunchKernelGGL(k_pack,   dim3(16, 4, 16), dim3(256), 0, stream, ew1, w1th, w1tl, 256, 1024);
  hipLaunchKernelGGL(k_pack,   dim3(4, 16, 16), dim3(256), 0, stream, ew2, w2th, w2tl, 1024, 256);
  hipLaunchKernelGGL(k_pack,   dim3(4, 32, 1),  dim3(256), 0, stream, fcw, wfh, wfl, 2048, 256);
  hipLaunchKernelGGL(k_fc,     dim3(128, 1, 4), dim3(256), 0, stream, Chh, Chl, wfh, wfl, P0, P1, P2, P3);
  hipLaunchKernelGGL(k_gate,   dim3(256),     dim3(256), 0, stream, P0, P1, P2, P3, fcb, gw, gb,
                     feat, cnt, gsum, lrow, lgv);
  hipLaunchKernelGGL(k_moe,    dim3(128, 16, 8), dim3(256), 0, stream, feat, w1th, w1tl, w2th, w2tl,
                     eb1, eb2, cnt, lrow, lgv, moe);
  hipLaunchKernelGGL(k_lb,     dim3(1),       dim3(64),  0, stream, gsum, outp + (size_t)NB*NCLS);
  hipLaunchKernelGGL(k_ln,     dim3(4096),    dim3(256), 0, stream, feat, moe, lng, lnb);
  hipLaunchKernelGGL(k_out,    dim3(128, 4),  dim3(256), 0, stream, moe, ow, ob, outp);
}

// Round 15
// 843.218 us; speedup vs baseline: 1.0672x; 1.0210x over previous
//
#include <hip/hip_runtime.h>
#include <hip/hip_bf16.h>

typedef short bf16x8 __attribute__((ext_vector_type(8)));
typedef float f32x4 __attribute__((ext_vector_type(4)));

// ---------------- problem sizes ----------------
#define NB   4096
#define NEXP 16
#define DDIM 256
#define HDIM 1024
#define NCLS 1000

// ---------------- workspace layout (bytes) ----------------
// NOTE: Bb (conv2 out, 67 MB at offset 0) is live from conv12 until conv3 completes.
// ALL packed-weight regions below OFF_CHH alias Bb -> their pack kernels MUST run after conv3.
#define OFF_B    ((size_t)0)
#define OFF_P0   ((size_t)0)           // f32 [4096][256] FC partial (kq 0); ALSO yh after gate
#define OFF_P1   ((size_t)4194304)     // f32 [4096][256] FC partial (kq 1); ALSO yl after gate
#define OFF_W1TH ((size_t)8388608)     // bf16 packed [16][64 ht][8 ks][64 lane][8]  8 MB
#define OFF_W1TL ((size_t)16777216)
#define OFF_W2TH ((size_t)25165824)    // bf16 packed [16][16 dt][32 ks][64 lane][8] 8 MB
#define OFF_W2TL ((size_t)33554432)
#define OFF_WFCH ((size_t)41943040)    // fcw packed hi (1 MB)
#define OFF_WFCL ((size_t)42991616)    // fcw packed lo (1 MB)
#define OFF_P2   ((size_t)44040192)    // f32 [4096][256] FC partial (kq 2)
#define OFF_P3   ((size_t)48234496)    // f32 [4096][256] FC partial (kq 3)
#define OFF_OWH  ((size_t)52428800)    // ow packed hi [64 nt][8 ks][64][8] (512 KB)
#define OFF_OWL  ((size_t)53477376)
#define OFF_CHH  ((size_t)67108864)    // conv3 out hi bf16 [4096][2048]; ALSO wBh/wBl/wA1 before conv12
#define OFF_CHL  ((size_t)83886080)    // conv3 out lo bf16
#define OFF_WBL  ((size_t)67145728)
#define OFF_WA1H ((size_t)67182592)
#define OFF_WA1L ((size_t)67184640)
#define OFF_FEAT ((size_t)100663296)   // f32 [4096][256]; ALSO wAh/wAl (288 KB) before k_gate
#define OFF_WAL  ((size_t)100810752)
#define OFF_MOE  ((size_t)104857600)   // f32 [4096][256]
#define OFF_CNT  ((size_t)109051904)   // int [16]
#define OFF_GSUM ((size_t)109051968)   // f32 [16]
#define OFF_LROW ((size_t)109052032)   // int [16][4096]
#define OFF_LG   ((size_t)109314176)   // f32 [16][4096]

__device__ inline unsigned short f2bf(float v) {
  __hip_bfloat16 h = __float2bfloat16(v);
  return *(unsigned short*)&h;
}
__device__ inline float bf2f(unsigned short u) {
  union { unsigned int i; float f; } c; c.i = ((unsigned int)u) << 16; return c.f;
}

// ====== conv1 weight prep: c1w[oc][27] -> wA1[oc][32 K] bf16 hi/lo (K=ic*9+tap, pad 32)
__global__ __launch_bounds__(256) void k_wt1b(const float* __restrict__ w,
    unsigned short* __restrict__ oh, unsigned short* __restrict__ ol) {
  int i = blockIdx.x*256 + threadIdx.x;
  if (i >= 1024) return;
  int k = i & 31, oc = i >> 5;
  float v = (k < 27) ? w[oc*27 + k] : 0.f;
  unsigned short h = f2bf(v);
  oh[i] = h;
  ol[i] = f2bf(v - bf2f(h));
}

// ====== conv2 weight prep: c2w[oc][ic][tap] -> wBh/wBl[tap][oc][ic] bf16 hi/lo ======
__global__ __launch_bounds__(256) void k_wt2b(const float* __restrict__ w,
    unsigned short* __restrict__ wBh, unsigned short* __restrict__ wBl) {
  int i = blockIdx.x*256 + threadIdx.x;
  if (i >= 9*64*32) return;
  int ic = i & 31, rem = i >> 5;
  int oc = rem & 63, tap = rem >> 6;
  float v = w[(oc*32 + ic)*9 + tap];
  unsigned short h = f2bf(v);
  wBh[i] = h;
  wBl[i] = f2bf(v - bf2f(h));
}

// ====== MFMA-native weight pack: in[e][R=k][C=n] -> packed[e][n/16][R/32][64 lane][8] hi/lo
__global__ __launch_bounds__(256) void k_pack(const float* __restrict__ in,
    unsigned short* __restrict__ oh, unsigned short* __restrict__ ol, int R, int C) {
  __shared__ float tile[64][65];
  const int t = threadIdx.x;
  const int e = blockIdx.z;
  const size_t eb = (size_t)e * R * C;
  const int c0 = blockIdx.x*64, r0 = blockIdx.y*64;
  const int cc = t & 63, r4 = t >> 6;
  #pragma unroll
  for (int j = 0; j < 16; ++j) {
    int rr = r4 + j*4;
    tile[rr][cc] = in[eb + (size_t)(r0+rr)*C + c0 + cc];
  }
  __syncthreads();
  const int K32 = R >> 5;
  #pragma unroll
  for (int j = 0; j < 16; ++j) {
    int idx = t + j*256;
    int jin = idx & 7, lane = (idx >> 3) & 63, ksl = (idx >> 9) & 1, ntl = idx >> 10;
    int kl = ksl*32 + ((lane >> 4) << 3) + jin;
    int nl = ntl*16 + (lane & 15);
    float v = tile[kl][nl];
    unsigned short h = f2bf(v);
    size_t o = eb + ((size_t)(((c0 >> 4) + ntl)*K32 + (r0 >> 5) + ksl)*64 + lane)*8 + jin;
    oh[o] = h;
    ol[o] = f2bf(v - bf2f(h));
  }
}

// ====== ow pack: ow[256 k][1000 n] -> packed[64 nt][8 ks][64 lane][8] hi/lo, zero pad n>=1000
__global__ __launch_bounds__(256) void k_packo(const float* __restrict__ ow,
    unsigned short* __restrict__ oh, unsigned short* __restrict__ ol) {
  int i = blockIdx.x*256 + threadIdx.x;   // over 64*8*64*8 = 262144
  int j = i & 7, lane = (i >> 3) & 63, ks = (i >> 9) & 7, nt = i >> 12;
  int k = ks*32 + ((lane >> 4) << 3) + j;
  int n = nt*16 + (lane & 15);
  float v = (n < NCLS) ? ow[(size_t)k*NCLS + n] : 0.f;
  unsigned short h = f2bf(v);
  oh[i] = h;
  ol[i] = f2bf(v - bf2f(h));
}

// im2col octet builder: K0 compile-time -> all ic/tap static. k = ic*9+tap.
template<int K0>
__device__ inline void build_oct(const float (*xs)[34][36], int Y, int X,
                                 unsigned int* hw, unsigned int* lw) {
  #pragma unroll
  for (int jj = 0; jj < 4; ++jj) {
    unsigned short hh[2], ll[2];
    #pragma unroll
    for (int b = 0; b < 2; ++b) {
      const int k = K0 + jj*2 + b;
      float v = 0.f;
      if (k < 27) {
        const int ic = k/9, tap = k - ic*9, dy = tap/3, dx = tap - dy*3;
        v = xs[ic][Y+dy][X+dx];
      }
      unsigned short h = f2bf(v);
      hh[b] = h; ll[b] = f2bf(v - bf2f(h));
    }
    hw[jj] = (unsigned int)hh[0] | ((unsigned int)hh[1] << 16);
    lw[jj] = (unsigned int)ll[0] | ((unsigned int)ll[1] << 16);
  }
}

// ============ fused conv1(bf16x2 MFMA im2col) + conv2(bf16x2 MFMA, 3-term) per image ========
__global__ __launch_bounds__(512, 4) void k_conv12(const float* __restrict__ x,
    const unsigned short* __restrict__ wA1h, const unsigned short* __restrict__ wA1l,
    const float* __restrict__ b1,
    const unsigned short* __restrict__ wBh, const unsigned short* __restrict__ wBl,
    const float* __restrict__ b2, float* __restrict__ outB) {
  __shared__ float xs[3][34][36];
  __shared__ unsigned short ishB[2][10368];
  __shared__ __align__(16) unsigned short i2ch[5120];  // [128 px][40] padded rows (2-way banks)
  __shared__ __align__(16) unsigned short i2cl[5120];
  __shared__ float bs1[32];
  __shared__ float bs2[64];
  const int t = threadIdx.x;
  const int img = blockIdx.x;
  for (int i = t; i < 3*34*36; i += 512) ((float*)xs)[i] = 0.f;
  {
    unsigned int* z = (unsigned int*)&ishB[0][0];
    for (int i = t; i < 10368; i += 512) z[i] = 0u;
  }
  __syncthreads();
  for (int i = t; i < 3072; i += 512) {
    int ic = i >> 10, rem = i & 1023, y = rem >> 5, xx = rem & 31;
    xs[ic][y+1][xx+1] = x[(size_t)img*3072 + i];
  }
  if (t < 32) bs1[t] = b1[t];
  else if (t >= 64 && t < 128) bs2[t-64] = b2[t-64];

  const int lane = t & 63, wvv = t >> 6;
  const int lr = lane & 15, lq = lane >> 4;

  const int oct1 = wvv & 1;
  const bf16x8 a1h = *(const bf16x8*)&wA1h[((oct1*16 + lr) << 5) + lq*8];
  const bf16x8 a1l = *(const bf16x8*)&wA1l[((oct1*16 + lr) << 5) + lq*8];
  __syncthreads();

  // ---- conv1 via MFMA: 8 passes of 4 pre-pool rows (128 px) ----
  {
    const int rp  = wvv >> 1;
    const int ly0 = (rp >> 1) << 1;
    const int xh  = rp & 1;
    const int koct = t >> 7;             // wave-uniform
    const int pixb = t & 127;
    const int bly = pixb >> 5, bX = pixb & 31;
    for (int ps = 0; ps < 8; ++ps) {
      if (ps) __syncthreads();
      {
        const int Y = ps*4 + bly;
        unsigned int hw[4], lw[4];
        if      (koct == 0) build_oct<0 >(xs, Y, bX, hw, lw);
        else if (koct == 1) build_oct<8 >(xs, Y, bX, hw, lw);
        else if (koct == 2) build_oct<16>(xs, Y, bX, hw, lw);
        else                build_oct<24>(xs, Y, bX, hw, lw);
        const int base = pixb*40 + koct*8;
        *reinterpret_cast<uint4*>(&i2ch[base]) = make_uint4(hw[0],hw[1],hw[2],hw[3]);
        *reinterpret_cast<uint4*>(&i2cl[base]) = make_uint4(lw[0],lw[1],lw[2],lw[3]);
      }
      __syncthreads();
      {
        const int ptA = ly0*2 + xh, ptB = (ly0+1)*2 + xh;
        const int pA = ptA*16 + lr, pB = ptB*16 + lr;
        const bf16x8 bhA = *(const bf16x8*)&i2ch[pA*40 + lq*8];
        const bf16x8 blA = *(const bf16x8*)&i2cl[pA*40 + lq*8];
        const bf16x8 bhB = *(const bf16x8*)&i2ch[pB*40 + lq*8];
        const bf16x8 blB = *(const bf16x8*)&i2cl[pB*40 + lq*8];
        f32x4 aA = (f32x4){0.f,0.f,0.f,0.f}, aB = (f32x4){0.f,0.f,0.f,0.f};
        aA = __builtin_amdgcn_mfma_f32_16x16x32_bf16(a1h, bhA, aA, 0, 0, 0);
        aB = __builtin_amdgcn_mfma_f32_16x16x32_bf16(a1h, bhB, aB, 0, 0, 0);
        aA = __builtin_amdgcn_mfma_f32_16x16x32_bf16(a1h, blA, aA, 0, 0, 0);
        aB = __builtin_amdgcn_mfma_f32_16x16x32_bf16(a1h, blB, aB, 0, 0, 0);
        aA = __builtin_amdgcn_mfma_f32_16x16x32_bf16(a1l, bhA, aA, 0, 0, 0);
        aB = __builtin_amdgcn_mfma_f32_16x16x32_bf16(a1l, bhB, aB, 0, 0, 0);
        #pragma unroll
        for (int r = 0; r < 4; ++r) {
          float v = fmaxf(aA[r], aB[r]);
          v = fmaxf(v, __shfl_xor(v, 1, 64));
          if ((lr & 1) == 0) {
            int oc = oct1*16 + lq*4 + r;
            int Xp = xh*8 + (lr >> 1);
            int Yp = ps*2 + (ly0 >> 1);
            float m = fmaxf(v + bs1[oc], 0.f);
            unsigned short h = f2bf(m);
            unsigned short l = f2bf(m - bf2f(h));
            int pl = (Yp+1)*18 + (Xp+1);
            int sl = pl*4 + ((oc >> 3) ^ ((pl >> 1) & 3));
            int us = (sl << 3) | (oc & 7);
            ishB[0][us] = h; ishB[1][us] = l;
          }
        }
      }
    }
  }
  __syncthreads();
  // ---- conv2 bf16x2 MFMA (3-term) + fused pool + relu ----
  {
    const int mtp = (wvv & 1)*2;
    const int rq = wvv >> 1;
    f32x4 acc[2][4];
    #pragma unroll
    for (int i = 0; i < 2; ++i)
      #pragma unroll
      for (int j = 0; j < 4; ++j) acc[i][j] = (f32x4){0.f,0.f,0.f,0.f};
    bf16x8 nAh[2], nAl[2];
    #pragma unroll
    for (int m = 0; m < 2; ++m) {
      int off = (((mtp+m)*16 + lr) << 5) + lq*8;
      nAh[m] = *(const bf16x8*)&wBh[off];
      nAl[m] = *(const bf16x8*)&wBl[off];
    }
    #pragma unroll
    for (int tap = 0; tap < 9; ++tap) {
      bf16x8 ah0 = nAh[0], al0 = nAl[0], ah1 = nAh[1], al1 = nAl[1];
      if (tap < 8) {
        #pragma unroll
        for (int m = 0; m < 2; ++m) {
          int off = (((tap+1)*64 + (mtp+m)*16 + lr) << 5) + lq*8;
          nAh[m] = *(const bf16x8*)&wBh[off];
          nAl[m] = *(const bf16x8*)&wBl[off];
        }
      }
      const int dy = tap/3, dx = tap - dy*3;
      #pragma unroll
      for (int j = 0; j < 4; ++j) {
        int pl = (rq*4 + j + dy)*18 + lr + dx;
        int sl = pl*4 + (lq ^ ((pl >> 1) & 3));
        bf16x8 bh = *(const bf16x8*)&ishB[0][sl << 3];
        bf16x8 bl = *(const bf16x8*)&ishB[1][sl << 3];
        acc[0][j] = __builtin_amdgcn_mfma_f32_16x16x32_bf16(ah0, bh, acc[0][j], 0, 0, 0);
        acc[1][j] = __builtin_amdgcn_mfma_f32_16x16x32_bf16(ah1, bh, acc[1][j], 0, 0, 0);
        acc[0][j] = __builtin_amdgcn_mfma_f32_16x16x32_bf16(ah0, bl, acc[0][j], 0, 0, 0);
        acc[1][j] = __builtin_amdgcn_mfma_f32_16x16x32_bf16(ah1, bl, acc[1][j], 0, 0, 0);
        acc[0][j] = __builtin_amdgcn_mfma_f32_16x16x32_bf16(al0, bh, acc[0][j], 0, 0, 0);
        acc[1][j] = __builtin_amdgcn_mfma_f32_16x16x32_bf16(al1, bh, acc[1][j], 0, 0, 0);
      }
    }
    __syncthreads();
    float* ps2 = (float*)&ishB[0][0];
    #pragma unroll
    for (int m = 0; m < 2; ++m)
      #pragma unroll
      for (int k = 0; k < 2; ++k)
        #pragma unroll
        for (int r = 0; r < 4; ++r) {
          float v = fmaxf(acc[m][2*k][r], acc[m][2*k+1][r]);
          v = fmaxf(v, __shfl_xor(v, 1, 64));
          if ((lr & 1) == 0) {
            int oc = (mtp + m)*16 + lq*4 + r;
            int Y = rq*2 + k, X = lr >> 1;
            ps2[oc*65 + Y*8 + X] = fmaxf(v + bs2[oc], 0.f);
          }
        }
    __syncthreads();
    float* op = outB + (size_t)img*4096;
    #pragma unroll
    for (int jj = 0; jj < 8; ++jj) {
      int i = jj*512 + t;
      op[i] = ps2[(i >> 6)*65 + (i & 63)];
    }
  }
}

// ================= conv3 weight prep: c3w[oc][ic][tap] -> wAh/wAl[tap][oc][ic] bf16 hi/lo
__global__ __launch_bounds__(256) void k_wt3b(const float* __restrict__ w,
    unsigned short* __restrict__ wAh, unsigned short* __restrict__ wAl) {
  int i = blockIdx.x*256 + threadIdx.x;
  if (i >= 9*128*64) return;
  int ic = i & 63, rem = i >> 6;
  int oc = rem & 127, tap = rem >> 7;
  float v = w[(oc*64 + ic)*9 + tap];
  unsigned short h = f2bf(v);
  wAh[i] = h;
  wAl[i] = f2bf(v - bf2f(h));
}

// ================= conv3 v5: bf16x2 split MFMA (3-term); emits C as bf16 hi/lo ==========
__global__ __launch_bounds__(256) void k_conv3(const float* __restrict__ inB,
    const unsigned short* __restrict__ wAh, const unsigned short* __restrict__ wAl,
    const float* __restrict__ bias,
    unsigned short* __restrict__ Chh, unsigned short* __restrict__ Chl) {
  __shared__ unsigned short ish[2][6400];
  const int t = threadIdx.x;
  const int img = blockIdx.x;
  {
    unsigned int* z = (unsigned int*)&ish[0][0];
    #pragma unroll
    for (int j = 0; j < 25; ++j) z[t + 256*j] = 0u;
  }
  __syncthreads();
  {
    const float* src = inB + (size_t)img*4096;
    #pragma unroll
    for (int j = 0; j < 16; ++j) {
      int f = t + 256*j;
      int ic = f >> 6, p = f & 63;
      int pl = ((p >> 3) + 1)*10 + (p & 7) + 1;
      float v = src[f];
      unsigned short h = f2bf(v);
      unsigned short l = f2bf(v - bf2f(h));
      int u = pl*64 + ic;
      int us = (((u >> 3) ^ (pl & 7)) << 3) | (u & 7);
      ish[0][us] = h; ish[1][us] = l;
    }
  }
  __syncthreads();

  const int lane = t & 63, wid = t >> 6;
  const int lr = lane & 15, lq = lane >> 4;
  const int mt0 = wid*2;
  const int yb = lr >> 3, xb = lr & 7;

  f32x4 acc[2][4];
  #pragma unroll
  for (int i = 0; i < 2; ++i)
    #pragma unroll
    for (int j = 0; j < 4; ++j) acc[i][j] = (f32x4){0.f,0.f,0.f,0.f};

  for (int tap = 0; tap < 9; ++tap) {
    const int dy = tap/3, dx = tap - dy*3;
    #pragma unroll
    for (int kc = 0; kc < 2; ++kc) {
      const int kb = kc*32 + lq*8;
      const int wbase = ((tap << 7) << 6) + kb;
      bf16x8 a0h = *(const bf16x8*)&wAh[wbase + ((mt0*16 + lr) << 6)];
      bf16x8 a0l = *(const bf16x8*)&wAl[wbase + ((mt0*16 + lr) << 6)];
      bf16x8 a1h = *(const bf16x8*)&wAh[wbase + (((mt0+1)*16 + lr) << 6)];
      bf16x8 a1l = *(const bf16x8*)&wAl[wbase + (((mt0+1)*16 + lr) << 6)];
      #pragma unroll
      for (int nt = 0; nt < 4; ++nt) {
        const int pl = (2*nt + yb + dy)*10 + xb + dx;
        const int u = pl*64 + kb;
        const int us = (((u >> 3) ^ (pl & 7)) << 3);
        bf16x8 bh = *(const bf16x8*)&ish[0][us];
        bf16x8 bl = *(const bf16x8*)&ish[1][us];
        acc[0][nt] = __builtin_amdgcn_mfma_f32_16x16x32_bf16(a0h, bh, acc[0][nt], 0, 0, 0);
        acc[0][nt] = __builtin_amdgcn_mfma_f32_16x16x32_bf16(a0h, bl, acc[0][nt], 0, 0, 0);
        acc[0][nt] = __builtin_amdgcn_mfma_f32_16x16x32_bf16(a0l, bh, acc[0][nt], 0, 0, 0);
        acc[1][nt] = __builtin_amdgcn_mfma_f32_16x16x32_bf16(a1h, bh, acc[1][nt], 0, 0, 0);
        acc[1][nt] = __builtin_amdgcn_mfma_f32_16x16x32_bf16(a1h, bl, acc[1][nt], 0, 0, 0);
        acc[1][nt] = __builtin_amdgcn_mfma_f32_16x16x32_bf16(a1l, bh, acc[1][nt], 0, 0, 0);
      }
    }
  }
  __syncthreads();
  float* stg = (float*)&ish[0][0];   // [128 oc][17]
  #pragma unroll
  for (int mtl = 0; mtl < 2; ++mtl)
    #pragma unroll
    for (int nt = 0; nt < 4; ++nt)
      #pragma unroll
      for (int r = 0; r < 4; ++r) {
        float v = acc[mtl][nt][r];
        v = fmaxf(v, __shfl_xor(v, 1, 64));
        v = fmaxf(v, __shfl_xor(v, 8, 64));
        if ((lane & 9) == 0) {
          int oc = (mt0 + mtl)*16 + lq*4 + r;
          int pix = nt*4 + (xb >> 1);
          stg[oc*17 + pix] = fmaxf(v + bias[oc], 0.f);
        }
      }
  __syncthreads();
  #pragma unroll
  for (int j = 0; j < 8; ++j) {
    int i = t + 256*j;
    float v = stg[(i >> 4)*17 + (i & 15)];
    unsigned short h = f2bf(v);
    Chh[(size_t)img*2048 + i] = h;
    Chl[(size_t)img*2048 + i] = f2bf(v - bf2f(h));
  }
}

// ================= FC GEMM v2: bf16x2 3-term MFMA, no LDS, split-K=4 =================
__global__ __launch_bounds__(256) void k_fc(const unsigned short* __restrict__ Chh,
    const unsigned short* __restrict__ Chl,
    const unsigned short* __restrict__ wfh, const unsigned short* __restrict__ wfl,
    float* __restrict__ P0, float* __restrict__ P1,
    float* __restrict__ P2, float* __restrict__ P3) {
  const int t = threadIdx.x;
  const int r0 = blockIdx.x * 32;
  const int kq = blockIdx.z;
  float* __restrict__ P = (kq == 0) ? P0 : (kq == 1) ? P1 : (kq == 2) ? P2 : P3;
  const int lane = t & 63, wv = t >> 6;
  const int lr = lane & 15, lq = lane >> 4;
  f32x4 acc[2][4];
  #pragma unroll
  for (int i = 0; i < 2; ++i)
    #pragma unroll
    for (int j = 0; j < 4; ++j) acc[i][j] = (f32x4){0.f,0.f,0.f,0.f};
  #pragma unroll 4
  for (int ks = 0; ks < 16; ++ks) {
    bf16x8 ah[2], al[2];
    #pragma unroll
    for (int rt = 0; rt < 2; ++rt) {
      size_t ao = (size_t)(r0 + rt*16 + lr)*2048 + kq*512 + ks*32 + lq*8;
      ah[rt] = *(const bf16x8*)&Chh[ao];
      al[rt] = *(const bf16x8*)&Chl[ao];
    }
    #pragma unroll
    for (int nt = 0; nt < 4; ++nt) {
      size_t bo = ((size_t)((wv*4 + nt)*64 + kq*16 + ks)*64 + lane)*8;
      bf16x8 bh = *(const bf16x8*)&wfh[bo];
      bf16x8 bl = *(const bf16x8*)&wfl[bo];
      acc[0][nt] = __builtin_amdgcn_mfma_f32_16x16x32_bf16(ah[0], bh, acc[0][nt], 0, 0, 0);
      acc[1][nt] = __builtin_amdgcn_mfma_f32_16x16x32_bf16(ah[1], bh, acc[1][nt], 0, 0, 0);
      acc[0][nt] = __builtin_amdgcn_mfma_f32_16x16x32_bf16(ah[0], bl, acc[0][nt], 0, 0, 0);
      acc[1][nt] = __builtin_amdgcn_mfma_f32_16x16x32_bf16(ah[1], bl, acc[1][nt], 0, 0, 0);
      acc[0][nt] = __builtin_amdgcn_mfma_f32_16x16x32_bf16(al[0], bh, acc[0][nt], 0, 0, 0);
      acc[1][nt] = __builtin_amdgcn_mfma_f32_16x16x32_bf16(al[1], bh, acc[1][nt], 0, 0, 0);
    }
  }
  #pragma unroll
  for (int rt = 0; rt < 2; ++rt)
    #pragma unroll
    for (int nt = 0; nt < 4; ++nt)
      #pragma unroll
      for (int r = 0; r < 4; ++r)
        P[(size_t)(r0 + rt*16 + lq*4 + r)*256 + (wv*4 + nt)*16 + lr] = acc[rt][nt][r];
}

// ================= gate: feat = P0+P1+P2+P3+fcb; logits; top-2 softmax; expert lists
__global__ __launch_bounds__(256) void k_gate(const float* __restrict__ P0,
    const float* __restrict__ P1, const float* __restrict__ P2, const float* __restrict__ P3,
    const float* __restrict__ fcb,
    const float* __restrict__ gw, const float* __restrict__ gb,
    float* __restrict__ feat, int* __restrict__ cnt, float* __restrict__ gsum,
    int* __restrict__ lrow, float* __restrict__ lg) {
  __shared__ float ft[16][256];
  __shared__ float lgs[16][16];
  __shared__ float gwl[4096];
  const int t = threadIdx.x;
  const int r0 = blockIdx.x * 16;
  for (int i = t; i < 4096; i += 256) gwl[i] = gw[i];
  float bb = fcb[t];
  #pragma unroll
  for (int r = 0; r < 16; ++r) {
    size_t off = (size_t)(r0+r)*256 + t;
    float v = P0[off] + P1[off] + P2[off] + P3[off] + bb;
    ft[r][t] = v;
    feat[off] = v;
  }
  __syncthreads();
  {
    int r = t >> 4, e = t & 15;
    float s = gb[e];
    for (int k = 0; k < 256; ++k) s = fmaf(ft[r][k], gwl[k*16 + e], s);
    lgs[r][e] = s;
  }
  __syncthreads();
  if (t < 16) {
    int r = t;
    float v1 = -3.402823e38f, v2 = -3.402823e38f;
    int i1 = 0, i2 = 0;
    for (int e = 0; e < 16; ++e) {
      float v = lgs[r][e];
      if (v > v1)      { v2 = v1; i2 = i1; v1 = v; i1 = e; }
      else if (v > v2) { v2 = v;  i2 = e; }
    }
    float ex = __expf(v2 - v1);
    float g1 = 1.f / (1.f + ex);
    float g2 = ex  / (1.f + ex);
    int row = r0 + r;
    int p1 = atomicAdd(&cnt[i1], 1); lrow[i1*4096 + p1] = row; lg[i1*4096 + p1] = g1;
    int p2 = atomicAdd(&cnt[i2], 1); lrow[i2*4096 + p2] = row; lg[i2*4096 + p2] = g2;
    atomicAdd(&gsum[i1], g1);
    atomicAdd(&gsum[i2], g2);
  }
}

// ================= MoE v4: 32-row tiles x split-K(8), bf16x2 MFMA 3-term, packed weights
__global__ __launch_bounds__(256) void k_moe(const float* __restrict__ feat,
    const unsigned short* __restrict__ w1th, const unsigned short* __restrict__ w1tl,
    const unsigned short* __restrict__ w2th, const unsigned short* __restrict__ w2tl,
    const float* __restrict__ eb1, const float* __restrict__ eb2,
    const int* __restrict__ cnt, const int* __restrict__ lrow, const float* __restrict__ lgw,
    float* __restrict__ moe) {
  const int e = blockIdx.y;
  const int n_e = cnt[e];
  const int start = blockIdx.x * 32;
  if (start >= n_e) return;
  const int c = blockIdx.z;
  const int n = min(32, n_e - start);
  __shared__ unsigned short fh[8192], fl[8192];
  __shared__ unsigned short h1h[4096], h1l[4096];
  __shared__ int   rws[32];
  __shared__ float gws[32];
  const int t = threadIdx.x;
  if (t < 32) {
    rws[t] = (t < n) ? lrow[e*4096 + start + t] : 0;
    gws[t] = (t < n) ? lgw[e*4096 + start + t] : 0.f;
  }
  __syncthreads();
  for (int j = 0; j < 32; ++j) {
    float v = (j < n) ? feat[(size_t)rws[j]*256 + t] : 0.f;
    unsigned short h = f2bf(v);
    int us = (j*32 + ((t >> 3) ^ (j & 7)))*8 + (t & 7);
    fh[us] = h; fl[us] = f2bf(v - bf2f(h));
  }
  const int lane = t & 63, wv = t >> 6;
  const int lr = lane & 15, lq = lane >> 4;
  const int rh = wv & 1, qh = wv >> 1;
  const int arow = rh*16 + lr;
  const int rsw = arow & 7;
  const size_t ewb = (size_t)e << 18;

  f32x4 acc2[8];
  #pragma unroll
  for (int i = 0; i < 8; ++i) acc2[i] = (f32x4){0.f,0.f,0.f,0.f};

  __syncthreads();

  {
    f32x4 acc1[4];
    #pragma unroll
    for (int i = 0; i < 4; ++i) acc1[i] = (f32x4){0.f,0.f,0.f,0.f};
    #pragma unroll
    for (int ks = 0; ks < 8; ++ks) {
      int aoff = (arow*32 + ((ks*4 + lq) ^ rsw))*8;
      bf16x8 ah = *(const bf16x8*)&fh[aoff];
      bf16x8 al = *(const bf16x8*)&fl[aoff];
      #pragma unroll
      for (int ht = 0; ht < 4; ++ht) {
        int htile = c*8 + qh*4 + ht;
        size_t bo = ewb + ((size_t)(htile*8 + ks)*64 + lane)*8;
        bf16x8 bh = *(const bf16x8*)&w1th[bo];
        bf16x8 bl = *(const bf16x8*)&w1tl[bo];
        acc1[ht] = __builtin_amdgcn_mfma_f32_16x16x32_bf16(ah, bh, acc1[ht], 0, 0, 0);
        acc1[ht] = __builtin_amdgcn_mfma_f32_16x16x32_bf16(ah, bl, acc1[ht], 0, 0, 0);
        acc1[ht] = __builtin_amdgcn_mfma_f32_16x16x32_bf16(al, bh, acc1[ht], 0, 0, 0);
      }
    }
    __syncthreads();
    #pragma unroll
    for (int ht = 0; ht < 4; ++ht) {
      int hloc = qh*64 + ht*16 + lr;
      float bb = eb1[e*1024 + c*128 + hloc];
      #pragma unroll
      for (int r = 0; r < 4; ++r) {
        int orow = rh*16 + lq*4 + r;
        float v = fmaxf(acc1[ht][r] + bb, 0.f);
        unsigned short hh = f2bf(v);
        int us = (orow*16 + ((hloc >> 3) ^ (orow & 7)))*8 + (hloc & 7);
        h1h[us] = hh; h1l[us] = f2bf(v - bf2f(hh));
      }
    }
    __syncthreads();
    #pragma unroll
    for (int ks = 0; ks < 4; ++ks) {
      int aoff = (arow*16 + ((ks*4 + lq) ^ rsw))*8;
      bf16x8 ah = *(const bf16x8*)&h1h[aoff];
      bf16x8 al = *(const bf16x8*)&h1l[aoff];
      #pragma unroll
      for (int dt = 0; dt < 8; ++dt) {
        int dtile = qh*8 + dt;
        size_t bo = ewb + ((size_t)(dtile*32 + c*4 + ks)*64 + lane)*8;
        bf16x8 bh = *(const bf16x8*)&w2th[bo];
        bf16x8 bl = *(const bf16x8*)&w2tl[bo];
        acc2[dt] = __builtin_amdgcn_mfma_f32_16x16x32_bf16(ah, bh, acc2[dt], 0, 0, 0);
        acc2[dt] = __builtin_amdgcn_mfma_f32_16x16x32_bf16(ah, bl, acc2[dt], 0, 0, 0);
        acc2[dt] = __builtin_amdgcn_mfma_f32_16x16x32_bf16(al, bh, acc2[dt], 0, 0, 0);
      }
    }
  }
  #pragma unroll
  for (int dt = 0; dt < 8; ++dt) {
    int d = qh*128 + dt*16 + lr;
    float b2 = (c == 0) ? eb2[e*256 + d] : 0.f;
    #pragma unroll
    for (int r = 0; r < 4; ++r) {
      int orow = rh*16 + lq*4 + r;
      if (orow < n)
        atomicAdd(&moe[(size_t)rws[orow]*256 + d], gws[orow]*(acc2[dt][r] + b2));
    }
  }
}

// ================= load-balance loss
__global__ void k_lb(const float* __restrict__ gsum, float* __restrict__ out_lb) {
  int t = threadIdx.x;
  float term = 0.f;
  if (t < 16) {
    float D = gsum[t] * (1.f/4096.f);
    term = D * logf(D + 1e-8f);
  }
  #pragma unroll
  for (int o = 8; o > 0; o >>= 1) term += __shfl_down(term, o, 64);
  if (t == 0) *out_lb = term;
}

// ================= LayerNorm(moe + feat) -> y bf16 hi/lo =================
__global__ __launch_bounds__(256) void k_ln(const float* __restrict__ feat,
    const float* __restrict__ moe, const float* __restrict__ g, const float* __restrict__ bp,
    unsigned short* __restrict__ yh, unsigned short* __restrict__ yl) {
  const int r = blockIdx.x, t = threadIdx.x;
  float v = moe[(size_t)r*256 + t] + feat[(size_t)r*256 + t];
  float s = v, q = v * v;
  #pragma unroll
  for (int o = 32; o > 0; o >>= 1) {
    s += __shfl_down(s, o, 64);
    q += __shfl_down(q, o, 64);
  }
  __shared__ float ss[4], qq[4];
  int wv = t >> 6;
  if ((t & 63) == 0) { ss[wv] = s; qq[wv] = q; }
  __syncthreads();
  float S = ss[0]+ss[1]+ss[2]+ss[3];
  float Q = qq[0]+qq[1]+qq[2]+qq[3];
  float mu  = S * (1.f/256.f);
  float var = Q * (1.f/256.f) - mu*mu;
  float inv = rsqrtf(var + 1e-5f);
  float y = (v - mu) * inv * g[t] + bp[t];
  unsigned short h = f2bf(y);
  yh[(size_t)r*256 + t] = h;
  yl[(size_t)r*256 + t] = f2bf(y - bf2f(h));
}

// ================= output GEMM v2: bf16x2 3-term MFMA, no LDS =================
// grid (128, 16): 32 rows x 64 cols per block; packed ow (1024 cols, zero-padded).
__global__ __launch_bounds__(256) void k_out(const unsigned short* __restrict__ yh,
    const unsigned short* __restrict__ yl,
    const unsigned short* __restrict__ owh, const unsigned short* __restrict__ owl,
    const float* __restrict__ ob, float* __restrict__ out) {
  const int t = threadIdx.x;
  const int r0 = blockIdx.x * 32;
  const int lane = t & 63, wv = t >> 6;
  const int lr = lane & 15, lq = lane >> 4;
  const int ntile = blockIdx.y*4 + wv;
  f32x4 acc[2];
  acc[0] = (f32x4){0.f,0.f,0.f,0.f};
  acc[1] = (f32x4){0.f,0.f,0.f,0.f};
  #pragma unroll
  for (int ks = 0; ks < 8; ++ks) {
    bf16x8 bh = *(const bf16x8*)&owh[((size_t)(ntile*8 + ks)*64 + lane)*8];
    bf16x8 bl = *(const bf16x8*)&owl[((size_t)(ntile*8 + ks)*64 + lane)*8];
    #pragma unroll
    for (int rt = 0; rt < 2; ++rt) {
      size_t ao = (size_t)(r0 + rt*16 + lr)*256 + ks*32 + lq*8;
      bf16x8 ah = *(const bf16x8*)&yh[ao];
      bf16x8 al = *(const bf16x8*)&yl[ao];
      acc[rt] = __builtin_amdgcn_mfma_f32_16x16x32_bf16(ah, bh, acc[rt], 0, 0, 0);
      acc[rt] = __builtin_amdgcn_mfma_f32_16x16x32_bf16(ah, bl, acc[rt], 0, 0, 0);
      acc[rt] = __builtin_amdgcn_mfma_f32_16x16x32_bf16(al, bh, acc[rt], 0, 0, 0);
    }
  }
  const int col = ntile*16 + lr;
  if (col < NCLS) {
    float bb = ob[col];
    #pragma unroll
    for (int rt = 0; rt < 2; ++rt)
      #pragma unroll
      for (int r = 0; r < 4; ++r)
        out[(size_t)(r0 + rt*16 + lq*4 + r)*NCLS + col] = acc[rt][r] + bb;
  }
}

// ================= launch =================
extern "C" void kernel_launch(void* const* d_in, const int* in_sizes, int n_in,
                              void* d_out, int out_size, void* d_ws, size_t ws_size,
                              hipStream_t stream) {
  const float* x   = (const float*)d_in[0];
  const float* c1w = (const float*)d_in[1];
  const float* c1b = (const float*)d_in[2];
  const float* c2w = (const float*)d_in[3];
  const float* c2b = (const float*)d_in[4];
  const float* c3w = (const float*)d_in[5];
  const float* c3b = (const float*)d_in[6];
  const float* fcw = (const float*)d_in[7];
  const float* fcb = (const float*)d_in[8];
  const float* gw  = (const float*)d_in[9];
  const float* gb  = (const float*)d_in[10];
  const float* ew1 = (const float*)d_in[11];
  const float* eb1 = (const float*)d_in[12];
  const float* ew2 = (const float*)d_in[13];
  const float* eb2 = (const float*)d_in[14];
  const float* lng = (const float*)d_in[15];
  const float* lnb = (const float*)d_in[16];
  const float* ow  = (const float*)d_in[17];
  const float* ob  = (const float*)d_in[18];
  char* ws = (char*)d_ws;
  float* Bb   = (float*)(ws + OFF_B);
  float* P0   = (float*)(ws + OFF_P0);
  float* P1   = (float*)(ws + OFF_P1);
  float* P2   = (float*)(ws + OFF_P2);
  float* P3   = (float*)(ws + OFF_P3);
  unsigned short* Chh = (unsigned short*)(ws + OFF_CHH);
  unsigned short* Chl = (unsigned short*)(ws + OFF_CHL);
  unsigned short* wBh = (unsigned short*)(ws + OFF_CHH);   // aliases Chh (written after conv12)
  unsigned short* wBl = (unsigned short*)(ws + OFF_WBL);
  unsigned short* wA1h = (unsigned short*)(ws + OFF_WA1H);
  unsigned short* wA1l = (unsigned short*)(ws + OFF_WA1L);
  unsigned short* wAh = (unsigned short*)(ws + OFF_FEAT);  // aliases feat (written later)
  unsigned short* wAl = (unsigned short*)(ws + OFF_WAL);
  unsigned short* w1th = (unsigned short*)(ws + OFF_W1TH);
  unsigned short* w1tl = (unsigned short*)(ws + OFF_W1TL);
  unsigned short* w2th = (unsigned short*)(ws + OFF_W2TH);
  unsigned short* w2tl = (unsigned short*)(ws + OFF_W2TL);
  unsigned short* wfh = (unsigned short*)(ws + OFF_WFCH);
  unsigned short* wfl = (unsigned short*)(ws + OFF_WFCL);
  unsigned short* owph = (unsigned short*)(ws + OFF_OWH);
  unsigned short* owpl = (unsigned short*)(ws + OFF_OWL);
  unsigned short* yh = (unsigned short*)(ws + OFF_P0);     // aliases P0 (dead after gate)
  unsigned short* yl = (unsigned short*)(ws + OFF_P1);     // aliases P1
  float* feat = (float*)(ws + OFF_FEAT);
  float* moe  = (float*)(ws + OFF_MOE);
  int*   cnt  = (int*)(ws + OFF_CNT);
  float* gsum = (float*)(ws + OFF_GSUM);
  int*   lrow = (int*)(ws + OFF_LROW);
  float* lgv  = (float*)(ws + OFF_LG);
  float* outp = (float*)d_out;

  hipMemsetAsync(ws + OFF_MOE, 0, 4194304 + 128, stream);

  hipLaunchKernelGGL(k_wt1b,   dim3(4),       dim3(256), 0, stream, c1w, wA1h, wA1l);
  hipLaunchKernelGGL(k_wt2b,   dim3(72),      dim3(256), 0, stream, c2w, wBh, wBl);
  hipLaunchKernelGGL(k_wt3b,   dim3(288),     dim3(256), 0, stream, c3w, wAh, wAl);
  hipLaunchKernelGGL(k_conv12, dim3(4096),    dim3(512), 0, stream, x, wA1h, wA1l, c1b, wBh, wBl, c2b, Bb);
  hipLaunchKernelGGL(k_conv3,  dim3(4096),    dim3(256), 0, stream, Bb, wAh, wAl, c3b, Chh, Chl);
  // Bb dead now -> build ALL packed weights that live in its region
  hipLaunchKernelGGL(k_pack,   dim3(16, 4, 16), dim3(256), 0, stream, ew1, w1th, w1tl, 256, 1024);
  hipLaunchKernelGGL(k_pack,   dim3(4, 16, 16), dim3(256), 0, stream, ew2, w2th, w2tl, 1024, 256);
  hipLaunchKernelGGL(k_pack,   dim3(4, 32, 1),  dim3(256), 0, stream, fcw, wfh, wfl, 2048, 256);
  hipLaunchKernelGGL(k_packo,  dim3(1024),    dim3(256), 0, stream, ow, owph, owpl);
  hipLaunchKernelGGL(k_fc,     dim3(128, 1, 4), dim3(256), 0, stream, Chh, Chl, wfh, wfl, P0, P1, P2, P3);
  hipLaunchKernelGGL(k_gate,   dim3(256),     dim3(256), 0, stream, P0, P1, P2, P3, fcb, gw, gb,
                     feat, cnt, gsum, lrow, lgv);
  hipLaunchKernelGGL(k_moe,    dim3(128, 16, 8), dim3(256), 0, stream, feat, w1th, w1tl, w2th, w2tl,
                     eb1, eb2, cnt, lrow, lgv, moe);
  hipLaunchKernelGGL(k_lb,     dim3(1),       dim3(64),  0, stream, gsum, outp + (size_t)NB*NCLS);
  hipLaunchKernelGGL(k_ln,     dim3(4096),    dim3(256), 0, stream, feat, moe, lng, lnb, yh, yl);
  hipLaunchKernelGGL(k_out,    dim3(128, 16), dim3(256), 0, stream, yh, yl, owph, owpl, ob, outp);
}

// Round 16
// 831.569 us; speedup vs baseline: 1.0821x; 1.0140x over previous
//
#include <hip/hip_runtime.h>
#include <hip/hip_bf16.h>

typedef short bf16x8 __attribute__((ext_vector_type(8)));
typedef float f32x4 __attribute__((ext_vector_type(4)));

// ---------------- problem sizes ----------------
#define NB   4096
#define NEXP 16
#define DDIM 256
#define HDIM 1024
#define NCLS 1000

// ---------------- workspace layout (bytes) ----------------
// NOTE: Bb (conv2 out, 67 MB at offset 0) is live from conv12 until conv3 completes.
// ALL packed-weight regions below OFF_CHH alias Bb -> their pack kernels MUST run after conv3.
#define OFF_B    ((size_t)0)
#define OFF_P0   ((size_t)0)           // f32 [4096][256] FC partial (kq 0); ALSO yh after gate
#define OFF_P1   ((size_t)4194304)     // f32 [4096][256] FC partial (kq 1); ALSO yl after gate
#define OFF_W1TH ((size_t)8388608)     // bf16 packed [16][64 ht][8 ks][64 lane][8]  8 MB
#define OFF_W1TL ((size_t)16777216)
#define OFF_W2TH ((size_t)25165824)    // bf16 packed [16][16 dt][32 ks][64 lane][8] 8 MB
#define OFF_W2TL ((size_t)33554432)
#define OFF_WFCH ((size_t)41943040)    // fcw packed hi (1 MB)
#define OFF_WFCL ((size_t)42991616)    // fcw packed lo (1 MB)
#define OFF_P2   ((size_t)44040192)    // f32 [4096][256] FC partial (kq 2)
#define OFF_P3   ((size_t)48234496)    // f32 [4096][256] FC partial (kq 3)
#define OFF_OWH  ((size_t)52428800)    // ow packed hi [64 nt][8 ks][64][8] (512 KB)
#define OFF_OWL  ((size_t)53477376)
#define OFF_CHH  ((size_t)67108864)    // conv3 out hi bf16 [4096][2048]; ALSO wBh/wBl/wA1 before conv12
#define OFF_CHL  ((size_t)83886080)    // conv3 out lo bf16
#define OFF_WBL  ((size_t)67145728)
#define OFF_WA1H ((size_t)67182592)
#define OFF_WA1L ((size_t)67184640)
#define OFF_FEAT ((size_t)100663296)   // f32 [4096][256]; ALSO wAh/wAl (288 KB) before k_gate
#define OFF_WAL  ((size_t)100810752)
#define OFF_MOE  ((size_t)104857600)   // f32 [4096][256]
#define OFF_CNT  ((size_t)109051904)   // int [16]
#define OFF_GSUM ((size_t)109051968)   // f32 [16]
#define OFF_LROW ((size_t)109052032)   // int [16][4096]
#define OFF_LG   ((size_t)109314176)   // f32 [16][4096]

__device__ inline unsigned short f2bf(float v) {
  __hip_bfloat16 h = __float2bfloat16(v);
  return *(unsigned short*)&h;
}
__device__ inline float bf2f(unsigned short u) {
  union { unsigned int i; float f; } c; c.i = ((unsigned int)u) << 16; return c.f;
}

// ====== conv1 weight prep: c1w[oc][27] -> wA1[oc][32 K] bf16 hi/lo (K=ic*9+tap, pad 32)
__global__ __launch_bounds__(256) void k_wt1b(const float* __restrict__ w,
    unsigned short* __restrict__ oh, unsigned short* __restrict__ ol) {
  int i = blockIdx.x*256 + threadIdx.x;
  if (i >= 1024) return;
  int k = i & 31, oc = i >> 5;
  float v = (k < 27) ? w[oc*27 + k] : 0.f;
  unsigned short h = f2bf(v);
  oh[i] = h;
  ol[i] = f2bf(v - bf2f(h));
}

// ====== conv2 weight prep: c2w[oc][ic][tap] -> wBh/wBl[tap][oc][ic] bf16 hi/lo ======
__global__ __launch_bounds__(256) void k_wt2b(const float* __restrict__ w,
    unsigned short* __restrict__ wBh, unsigned short* __restrict__ wBl) {
  int i = blockIdx.x*256 + threadIdx.x;
  if (i >= 9*64*32) return;
  int ic = i & 31, rem = i >> 5;
  int oc = rem & 63, tap = rem >> 6;
  float v = w[(oc*32 + ic)*9 + tap];
  unsigned short h = f2bf(v);
  wBh[i] = h;
  wBl[i] = f2bf(v - bf2f(h));
}

// ====== MFMA-native weight pack: in[e][R=k][C=n] -> packed[e][n/16][R/32][64 lane][8] hi/lo
__global__ __launch_bounds__(256) void k_pack(const float* __restrict__ in,
    unsigned short* __restrict__ oh, unsigned short* __restrict__ ol, int R, int C) {
  __shared__ float tile[64][65];
  const int t = threadIdx.x;
  const int e = blockIdx.z;
  const size_t eb = (size_t)e * R * C;
  const int c0 = blockIdx.x*64, r0 = blockIdx.y*64;
  const int cc = t & 63, r4 = t >> 6;
  #pragma unroll
  for (int j = 0; j < 16; ++j) {
    int rr = r4 + j*4;
    tile[rr][cc] = in[eb + (size_t)(r0+rr)*C + c0 + cc];
  }
  __syncthreads();
  const int K32 = R >> 5;
  #pragma unroll
  for (int j = 0; j < 16; ++j) {
    int idx = t + j*256;
    int jin = idx & 7, lane = (idx >> 3) & 63, ksl = (idx >> 9) & 1, ntl = idx >> 10;
    int kl = ksl*32 + ((lane >> 4) << 3) + jin;
    int nl = ntl*16 + (lane & 15);
    float v = tile[kl][nl];
    unsigned short h = f2bf(v);
    size_t o = eb + ((size_t)(((c0 >> 4) + ntl)*K32 + (r0 >> 5) + ksl)*64 + lane)*8 + jin;
    oh[o] = h;
    ol[o] = f2bf(v - bf2f(h));
  }
}

// ====== ow pack: ow[256 k][1000 n] -> packed[64 nt][8 ks][64 lane][8] hi/lo, zero pad n>=1000
__global__ __launch_bounds__(256) void k_packo(const float* __restrict__ ow,
    unsigned short* __restrict__ oh, unsigned short* __restrict__ ol) {
  int i = blockIdx.x*256 + threadIdx.x;   // over 64*8*64*8 = 262144
  int j = i & 7, lane = (i >> 3) & 63, ks = (i >> 9) & 7, nt = i >> 12;
  int k = ks*32 + ((lane >> 4) << 3) + j;
  int n = nt*16 + (lane & 15);
  float v = (n < NCLS) ? ow[(size_t)k*NCLS + n] : 0.f;
  unsigned short h = f2bf(v);
  oh[i] = h;
  ol[i] = f2bf(v - bf2f(h));
}

// ============ fused conv1(reg-im2col bf16x2 MFMA) + conv2(bf16x2 MFMA, 3-term) per image ====
// conv1: each wave builds its own B-fragments in registers straight from xs (no i2c LDS,
// no build/consume barriers). Wave = (oct1, row-pair ly0, col-half xh); per pass 2 B-builds
// + 6 MFMAs. Per-lane koff[8] table maps k=(lane>>4)*8+j -> xs offset (k>=27 -> zero).
__global__ __launch_bounds__(512, 4) void k_conv12(const float* __restrict__ x,
    const unsigned short* __restrict__ wA1h, const unsigned short* __restrict__ wA1l,
    const float* __restrict__ b1,
    const unsigned short* __restrict__ wBh, const unsigned short* __restrict__ wBl,
    const float* __restrict__ b2, float* __restrict__ outB) {
  __shared__ float xs[3][34][36];           // padded input image (14.7 KB)
  __shared__ unsigned short ishB[2][10368]; // conv1-out hi/lo swizzled (41.5 KB); reused for store
  __shared__ float bs1[32];
  __shared__ float bs2[64];
  const int t = threadIdx.x;
  const int img = blockIdx.x;
  for (int i = t; i < 3*34*36; i += 512) ((float*)xs)[i] = 0.f;
  {
    unsigned int* z = (unsigned int*)&ishB[0][0];
    for (int i = t; i < 10368; i += 512) z[i] = 0u;
  }
  __syncthreads();
  for (int i = t; i < 3072; i += 512) {
    int ic = i >> 10, rem = i & 1023, y = rem >> 5, xx = rem & 31;
    xs[ic][y+1][xx+1] = x[(size_t)img*3072 + i];
  }
  if (t < 32) bs1[t] = b1[t];
  else if (t >= 64 && t < 128) bs2[t-64] = b2[t-64];

  const int lane = t & 63, wvv = t >> 6;
  const int lr = lane & 15, lq = lane >> 4;

  const int oct1 = wvv & 1;
  const bf16x8 a1h = *(const bf16x8*)&wA1h[((oct1*16 + lr) << 5) + lq*8];
  const bf16x8 a1l = *(const bf16x8*)&wA1l[((oct1*16 + lr) << 5) + lq*8];

  // per-lane k -> xs offset table (k = lq*8 + j); koff < 0 marks padded k (>= 27)
  int koff[8];
  #pragma unroll
  for (int j = 0; j < 8; ++j) {
    int k = lq*8 + j;
    if (k < 27) {
      int ic = k/9, tap = k - ic*9, dy = tap/3, dx = tap - dy*3;
      koff[j] = ic*34*36 + dy*36 + dx;
    } else koff[j] = -1;
  }
  __syncthreads();

  // ---- conv1 via MFMA, barrier-free: 8 passes of 4 pre-pool rows ----
  {
    const int rp  = wvv >> 1;
    const int ly0 = (rp >> 1) << 1;      // 0 or 2
    const int xh  = rp & 1;
    const int X   = xh*16 + lr;          // column for this lane's B elements
    const float* xsf = &xs[0][0][0];
    for (int ps = 0; ps < 8; ++ps) {
      // build B-frags for rows YA = ps*4+ly0 and YB = YA+1, in registers
      const int baseA = (ps*4 + ly0)*36 + X;
      union { unsigned int u[4]; bf16x8 v; } bhA, blA, bhB, blB;
      #pragma unroll
      for (int jj = 0; jj < 4; ++jj) {
        unsigned short h0A, l0A, h1A, l1A, h0B, l0B, h1B, l1B;
        {
          float vA = (koff[2*jj]   >= 0) ? xsf[koff[2*jj]   + baseA] : 0.f;
          float vB = (koff[2*jj]   >= 0) ? xsf[koff[2*jj]   + baseA + 36] : 0.f;
          h0A = f2bf(vA); l0A = f2bf(vA - bf2f(h0A));
          h0B = f2bf(vB); l0B = f2bf(vB - bf2f(h0B));
        }
        {
          float vA = (koff[2*jj+1] >= 0) ? xsf[koff[2*jj+1] + baseA] : 0.f;
          float vB = (koff[2*jj+1] >= 0) ? xsf[koff[2*jj+1] + baseA + 36] : 0.f;
          h1A = f2bf(vA); l1A = f2bf(vA - bf2f(h1A));
          h1B = f2bf(vB); l1B = f2bf(vB - bf2f(h1B));
        }
        bhA.u[jj] = (unsigned int)h0A | ((unsigned int)h1A << 16);
        blA.u[jj] = (unsigned int)l0A | ((unsigned int)l1A << 16);
        bhB.u[jj] = (unsigned int)h0B | ((unsigned int)h1B << 16);
        blB.u[jj] = (unsigned int)l0B | ((unsigned int)l1B << 16);
      }
      f32x4 aA = (f32x4){0.f,0.f,0.f,0.f}, aB = (f32x4){0.f,0.f,0.f,0.f};
      aA = __builtin_amdgcn_mfma_f32_16x16x32_bf16(a1h, bhA.v, aA, 0, 0, 0);
      aB = __builtin_amdgcn_mfma_f32_16x16x32_bf16(a1h, bhB.v, aB, 0, 0, 0);
      aA = __builtin_amdgcn_mfma_f32_16x16x32_bf16(a1h, blA.v, aA, 0, 0, 0);
      aB = __builtin_amdgcn_mfma_f32_16x16x32_bf16(a1h, blB.v, aB, 0, 0, 0);
      aA = __builtin_amdgcn_mfma_f32_16x16x32_bf16(a1l, bhA.v, aA, 0, 0, 0);
      aB = __builtin_amdgcn_mfma_f32_16x16x32_bf16(a1l, bhB.v, aB, 0, 0, 0);
      #pragma unroll
      for (int r = 0; r < 4; ++r) {
        float v = fmaxf(aA[r], aB[r]);             // y-pool (row pair in-registers)
        v = fmaxf(v, __shfl_xor(v, 1, 64));        // x-pool (col pair)
        if ((lr & 1) == 0) {
          int oc = oct1*16 + lq*4 + r;             // D row = (lane>>4)*4+reg
          int Xp = xh*8 + (lr >> 1);
          int Yp = ps*2 + (ly0 >> 1);
          float m = fmaxf(v + bs1[oc], 0.f);
          unsigned short h = f2bf(m);
          unsigned short l = f2bf(m - bf2f(h));
          int pl = (Yp+1)*18 + (Xp+1);
          int sl = pl*4 + ((oc >> 3) ^ ((pl >> 1) & 3));
          int us = (sl << 3) | (oc & 7);
          ishB[0][us] = h; ishB[1][us] = l;
        }
      }
    }
  }
  __syncthreads();
  // ---- conv2 bf16x2 MFMA (3-term) + fused pool + relu ----
  {
    const int mtp = (wvv & 1)*2;
    const int rq = wvv >> 1;
    f32x4 acc[2][4];
    #pragma unroll
    for (int i = 0; i < 2; ++i)
      #pragma unroll
      for (int j = 0; j < 4; ++j) acc[i][j] = (f32x4){0.f,0.f,0.f,0.f};
    bf16x8 nAh[2], nAl[2];
    #pragma unroll
    for (int m = 0; m < 2; ++m) {
      int off = (((mtp+m)*16 + lr) << 5) + lq*8;
      nAh[m] = *(const bf16x8*)&wBh[off];
      nAl[m] = *(const bf16x8*)&wBl[off];
    }
    #pragma unroll
    for (int tap = 0; tap < 9; ++tap) {
      bf16x8 ah0 = nAh[0], al0 = nAl[0], ah1 = nAh[1], al1 = nAl[1];
      if (tap < 8) {
        #pragma unroll
        for (int m = 0; m < 2; ++m) {
          int off = (((tap+1)*64 + (mtp+m)*16 + lr) << 5) + lq*8;
          nAh[m] = *(const bf16x8*)&wBh[off];
          nAl[m] = *(const bf16x8*)&wBl[off];
        }
      }
      const int dy = tap/3, dx = tap - dy*3;
      #pragma unroll
      for (int j = 0; j < 4; ++j) {
        int pl = (rq*4 + j + dy)*18 + lr + dx;
        int sl = pl*4 + (lq ^ ((pl >> 1) & 3));
        bf16x8 bh = *(const bf16x8*)&ishB[0][sl << 3];
        bf16x8 bl = *(const bf16x8*)&ishB[1][sl << 3];
        acc[0][j] = __builtin_amdgcn_mfma_f32_16x16x32_bf16(ah0, bh, acc[0][j], 0, 0, 0);
        acc[1][j] = __builtin_amdgcn_mfma_f32_16x16x32_bf16(ah1, bh, acc[1][j], 0, 0, 0);
        acc[0][j] = __builtin_amdgcn_mfma_f32_16x16x32_bf16(ah0, bl, acc[0][j], 0, 0, 0);
        acc[1][j] = __builtin_amdgcn_mfma_f32_16x16x32_bf16(ah1, bl, acc[1][j], 0, 0, 0);
        acc[0][j] = __builtin_amdgcn_mfma_f32_16x16x32_bf16(al0, bh, acc[0][j], 0, 0, 0);
        acc[1][j] = __builtin_amdgcn_mfma_f32_16x16x32_bf16(al1, bh, acc[1][j], 0, 0, 0);
      }
    }
    __syncthreads();
    float* ps2 = (float*)&ishB[0][0];
    #pragma unroll
    for (int m = 0; m < 2; ++m)
      #pragma unroll
      for (int k = 0; k < 2; ++k)
        #pragma unroll
        for (int r = 0; r < 4; ++r) {
          float v = fmaxf(acc[m][2*k][r], acc[m][2*k+1][r]);
          v = fmaxf(v, __shfl_xor(v, 1, 64));
          if ((lr & 1) == 0) {
            int oc = (mtp + m)*16 + lq*4 + r;
            int Y = rq*2 + k, X = lr >> 1;
            ps2[oc*65 + Y*8 + X] = fmaxf(v + bs2[oc], 0.f);
          }
        }
    __syncthreads();
    float* op = outB + (size_t)img*4096;
    #pragma unroll
    for (int jj = 0; jj < 8; ++jj) {
      int i = jj*512 + t;
      op[i] = ps2[(i >> 6)*65 + (i & 63)];
    }
  }
}

// ================= conv3 weight prep: c3w[oc][ic][tap] -> wAh/wAl[tap][oc][ic] bf16 hi/lo
__global__ __launch_bounds__(256) void k_wt3b(const float* __restrict__ w,
    unsigned short* __restrict__ wAh, unsigned short* __restrict__ wAl) {
  int i = blockIdx.x*256 + threadIdx.x;
  if (i >= 9*128*64) return;
  int ic = i & 63, rem = i >> 6;
  int oc = rem & 127, tap = rem >> 7;
  float v = w[(oc*64 + ic)*9 + tap];
  unsigned short h = f2bf(v);
  wAh[i] = h;
  wAl[i] = f2bf(v - bf2f(h));
}

// ================= conv3 v5: bf16x2 split MFMA (3-term); emits C as bf16 hi/lo ==========
__global__ __launch_bounds__(256) void k_conv3(const float* __restrict__ inB,
    const unsigned short* __restrict__ wAh, const unsigned short* __restrict__ wAl,
    const float* __restrict__ bias,
    unsigned short* __restrict__ Chh, unsigned short* __restrict__ Chl) {
  __shared__ unsigned short ish[2][6400];
  const int t = threadIdx.x;
  const int img = blockIdx.x;
  {
    unsigned int* z = (unsigned int*)&ish[0][0];
    #pragma unroll
    for (int j = 0; j < 25; ++j) z[t + 256*j] = 0u;
  }
  __syncthreads();
  {
    const float* src = inB + (size_t)img*4096;
    #pragma unroll
    for (int j = 0; j < 16; ++j) {
      int f = t + 256*j;
      int ic = f >> 6, p = f & 63;
      int pl = ((p >> 3) + 1)*10 + (p & 7) + 1;
      float v = src[f];
      unsigned short h = f2bf(v);
      unsigned short l = f2bf(v - bf2f(h));
      int u = pl*64 + ic;
      int us = (((u >> 3) ^ (pl & 7)) << 3) | (u & 7);
      ish[0][us] = h; ish[1][us] = l;
    }
  }
  __syncthreads();

  const int lane = t & 63, wid = t >> 6;
  const int lr = lane & 15, lq = lane >> 4;
  const int mt0 = wid*2;
  const int yb = lr >> 3, xb = lr & 7;

  f32x4 acc[2][4];
  #pragma unroll
  for (int i = 0; i < 2; ++i)
    #pragma unroll
    for (int j = 0; j < 4; ++j) acc[i][j] = (f32x4){0.f,0.f,0.f,0.f};

  for (int tap = 0; tap < 9; ++tap) {
    const int dy = tap/3, dx = tap - dy*3;
    #pragma unroll
    for (int kc = 0; kc < 2; ++kc) {
      const int kb = kc*32 + lq*8;
      const int wbase = ((tap << 7) << 6) + kb;
      bf16x8 a0h = *(const bf16x8*)&wAh[wbase + ((mt0*16 + lr) << 6)];
      bf16x8 a0l = *(const bf16x8*)&wAl[wbase + ((mt0*16 + lr) << 6)];
      bf16x8 a1h = *(const bf16x8*)&wAh[wbase + (((mt0+1)*16 + lr) << 6)];
      bf16x8 a1l = *(const bf16x8*)&wAl[wbase + (((mt0+1)*16 + lr) << 6)];
      #pragma unroll
      for (int nt = 0; nt < 4; ++nt) {
        const int pl = (2*nt + yb + dy)*10 + xb + dx;
        const int u = pl*64 + kb;
        const int us = (((u >> 3) ^ (pl & 7)) << 3);
        bf16x8 bh = *(const bf16x8*)&ish[0][us];
        bf16x8 bl = *(const bf16x8*)&ish[1][us];
        acc[0][nt] = __builtin_amdgcn_mfma_f32_16x16x32_bf16(a0h, bh, acc[0][nt], 0, 0, 0);
        acc[0][nt] = __builtin_amdgcn_mfma_f32_16x16x32_bf16(a0h, bl, acc[0][nt], 0, 0, 0);
        acc[0][nt] = __builtin_amdgcn_mfma_f32_16x16x32_bf16(a0l, bh, acc[0][nt], 0, 0, 0);
        acc[1][nt] = __builtin_amdgcn_mfma_f32_16x16x32_bf16(a1h, bh, acc[1][nt], 0, 0, 0);
        acc[1][nt] = __builtin_amdgcn_mfma_f32_16x16x32_bf16(a1h, bl, acc[1][nt], 0, 0, 0);
        acc[1][nt] = __builtin_amdgcn_mfma_f32_16x16x32_bf16(a1l, bh, acc[1][nt], 0, 0, 0);
      }
    }
  }
  __syncthreads();
  float* stg = (float*)&ish[0][0];   // [128 oc][17]
  #pragma unroll
  for (int mtl = 0; mtl < 2; ++mtl)
    #pragma unroll
    for (int nt = 0; nt < 4; ++nt)
      #pragma unroll
      for (int r = 0; r < 4; ++r) {
        float v = acc[mtl][nt][r];
        v = fmaxf(v, __shfl_xor(v, 1, 64));
        v = fmaxf(v, __shfl_xor(v, 8, 64));
        if ((lane & 9) == 0) {
          int oc = (mt0 + mtl)*16 + lq*4 + r;
          int pix = nt*4 + (xb >> 1);
          stg[oc*17 + pix] = fmaxf(v + bias[oc], 0.f);
        }
      }
  __syncthreads();
  #pragma unroll
  for (int j = 0; j < 8; ++j) {
    int i = t + 256*j;
    float v = stg[(i >> 4)*17 + (i & 15)];
    unsigned short h = f2bf(v);
    Chh[(size_t)img*2048 + i] = h;
    Chl[(size_t)img*2048 + i] = f2bf(v - bf2f(h));
  }
}

// ================= FC GEMM v2: bf16x2 3-term MFMA, no LDS, split-K=4 =================
__global__ __launch_bounds__(256) void k_fc(const unsigned short* __restrict__ Chh,
    const unsigned short* __restrict__ Chl,
    const unsigned short* __restrict__ wfh, const unsigned short* __restrict__ wfl,
    float* __restrict__ P0, float* __restrict__ P1,
    float* __restrict__ P2, float* __restrict__ P3) {
  const int t = threadIdx.x;
  const int r0 = blockIdx.x * 32;
  const int kq = blockIdx.z;
  float* __restrict__ P = (kq == 0) ? P0 : (kq == 1) ? P1 : (kq == 2) ? P2 : P3;
  const int lane = t & 63, wv = t >> 6;
  const int lr = lane & 15, lq = lane >> 4;
  f32x4 acc[2][4];
  #pragma unroll
  for (int i = 0; i < 2; ++i)
    #pragma unroll
    for (int j = 0; j < 4; ++j) acc[i][j] = (f32x4){0.f,0.f,0.f,0.f};
  #pragma unroll 4
  for (int ks = 0; ks < 16; ++ks) {
    bf16x8 ah[2], al[2];
    #pragma unroll
    for (int rt = 0; rt < 2; ++rt) {
      size_t ao = (size_t)(r0 + rt*16 + lr)*2048 + kq*512 + ks*32 + lq*8;
      ah[rt] = *(const bf16x8*)&Chh[ao];
      al[rt] = *(const bf16x8*)&Chl[ao];
    }
    #pragma unroll
    for (int nt = 0; nt < 4; ++nt) {
      size_t bo = ((size_t)((wv*4 + nt)*64 + kq*16 + ks)*64 + lane)*8;
      bf16x8 bh = *(const bf16x8*)&wfh[bo];
      bf16x8 bl = *(const bf16x8*)&wfl[bo];
      acc[0][nt] = __builtin_amdgcn_mfma_f32_16x16x32_bf16(ah[0], bh, acc[0][nt], 0, 0, 0);
      acc[1][nt] = __builtin_amdgcn_mfma_f32_16x16x32_bf16(ah[1], bh, acc[1][nt], 0, 0, 0);
      acc[0][nt] = __builtin_amdgcn_mfma_f32_16x16x32_bf16(ah[0], bl, acc[0][nt], 0, 0, 0);
      acc[1][nt] = __builtin_amdgcn_mfma_f32_16x16x32_bf16(ah[1], bl, acc[1][nt], 0, 0, 0);
      acc[0][nt] = __builtin_amdgcn_mfma_f32_16x16x32_bf16(al[0], bh, acc[0][nt], 0, 0, 0);
      acc[1][nt] = __builtin_amdgcn_mfma_f32_16x16x32_bf16(al[1], bh, acc[1][nt], 0, 0, 0);
    }
  }
  #pragma unroll
  for (int rt = 0; rt < 2; ++rt)
    #pragma unroll
    for (int nt = 0; nt < 4; ++nt)
      #pragma unroll
      for (int r = 0; r < 4; ++r)
        P[(size_t)(r0 + rt*16 + lq*4 + r)*256 + (wv*4 + nt)*16 + lr] = acc[rt][nt][r];
}

// ================= gate: feat = P0+P1+P2+P3+fcb; logits; top-2 softmax; expert lists
__global__ __launch_bounds__(256) void k_gate(const float* __restrict__ P0,
    const float* __restrict__ P1, const float* __restrict__ P2, const float* __restrict__ P3,
    const float* __restrict__ fcb,
    const float* __restrict__ gw, const float* __restrict__ gb,
    float* __restrict__ feat, int* __restrict__ cnt, float* __restrict__ gsum,
    int* __restrict__ lrow, float* __restrict__ lg) {
  __shared__ float ft[16][256];
  __shared__ float lgs[16][16];
  __shared__ float gwl[4096];
  const int t = threadIdx.x;
  const int r0 = blockIdx.x * 16;
  for (int i = t; i < 4096; i += 256) gwl[i] = gw[i];
  float bb = fcb[t];
  #pragma unroll
  for (int r = 0; r < 16; ++r) {
    size_t off = (size_t)(r0+r)*256 + t;
    float v = P0[off] + P1[off] + P2[off] + P3[off] + bb;
    ft[r][t] = v;
    feat[off] = v;
  }
  __syncthreads();
  {
    int r = t >> 4, e = t & 15;
    float s = gb[e];
    for (int k = 0; k < 256; ++k) s = fmaf(ft[r][k], gwl[k*16 + e], s);
    lgs[r][e] = s;
  }
  __syncthreads();
  if (t < 16) {
    int r = t;
    float v1 = -3.402823e38f, v2 = -3.402823e38f;
    int i1 = 0, i2 = 0;
    for (int e = 0; e < 16; ++e) {
      float v = lgs[r][e];
      if (v > v1)      { v2 = v1; i2 = i1; v1 = v; i1 = e; }
      else if (v > v2) { v2 = v;  i2 = e; }
    }
    float ex = __expf(v2 - v1);
    float g1 = 1.f / (1.f + ex);
    float g2 = ex  / (1.f + ex);
    int row = r0 + r;
    int p1 = atomicAdd(&cnt[i1], 1); lrow[i1*4096 + p1] = row; lg[i1*4096 + p1] = g1;
    int p2 = atomicAdd(&cnt[i2], 1); lrow[i2*4096 + p2] = row; lg[i2*4096 + p2] = g2;
    atomicAdd(&gsum[i1], g1);
    atomicAdd(&gsum[i2], g2);
  }
}

// ================= MoE v4: 32-row tiles x split-K(8), bf16x2 MFMA 3-term, packed weights
__global__ __launch_bounds__(256) void k_moe(const float* __restrict__ feat,
    const unsigned short* __restrict__ w1th, const unsigned short* __restrict__ w1tl,
    const unsigned short* __restrict__ w2th, const unsigned short* __restrict__ w2tl,
    const float* __restrict__ eb1, const float* __restrict__ eb2,
    const int* __restrict__ cnt, const int* __restrict__ lrow, const float* __restrict__ lgw,
    float* __restrict__ moe) {
  const int e = blockIdx.y;
  const int n_e = cnt[e];
  const int start = blockIdx.x * 32;
  if (start >= n_e) return;
  const int c = blockIdx.z;
  const int n = min(32, n_e - start);
  __shared__ unsigned short fh[8192], fl[8192];
  __shared__ unsigned short h1h[4096], h1l[4096];
  __shared__ int   rws[32];
  __shared__ float gws[32];
  const int t = threadIdx.x;
  if (t < 32) {
    rws[t] = (t < n) ? lrow[e*4096 + start + t] : 0;
    gws[t] = (t < n) ? lgw[e*4096 + start + t] : 0.f;
  }
  __syncthreads();
  for (int j = 0; j < 32; ++j) {
    float v = (j < n) ? feat[(size_t)rws[j]*256 + t] : 0.f;
    unsigned short h = f2bf(v);
    int us = (j*32 + ((t >> 3) ^ (j & 7)))*8 + (t & 7);
    fh[us] = h; fl[us] = f2bf(v - bf2f(h));
  }
  const int lane = t & 63, wv = t >> 6;
  const int lr = lane & 15, lq = lane >> 4;
  const int rh = wv & 1, qh = wv >> 1;
  const int arow = rh*16 + lr;
  const int rsw = arow & 7;
  const size_t ewb = (size_t)e << 18;

  f32x4 acc2[8];
  #pragma unroll
  for (int i = 0; i < 8; ++i) acc2[i] = (f32x4){0.f,0.f,0.f,0.f};

  __syncthreads();

  {
    f32x4 acc1[4];
    #pragma unroll
    for (int i = 0; i < 4; ++i) acc1[i] = (f32x4){0.f,0.f,0.f,0.f};
    #pragma unroll
    for (int ks = 0; ks < 8; ++ks) {
      int aoff = (arow*32 + ((ks*4 + lq) ^ rsw))*8;
      bf16x8 ah = *(const bf16x8*)&fh[aoff];
      bf16x8 al = *(const bf16x8*)&fl[aoff];
      #pragma unroll
      for (int ht = 0; ht < 4; ++ht) {
        int htile = c*8 + qh*4 + ht;
        size_t bo = ewb + ((size_t)(htile*8 + ks)*64 + lane)*8;
        bf16x8 bh = *(const bf16x8*)&w1th[bo];
        bf16x8 bl = *(const bf16x8*)&w1tl[bo];
        acc1[ht] = __builtin_amdgcn_mfma_f32_16x16x32_bf16(ah, bh, acc1[ht], 0, 0, 0);
        acc1[ht] = __builtin_amdgcn_mfma_f32_16x16x32_bf16(ah, bl, acc1[ht], 0, 0, 0);
        acc1[ht] = __builtin_amdgcn_mfma_f32_16x16x32_bf16(al, bh, acc1[ht], 0, 0, 0);
      }
    }
    __syncthreads();
    #pragma unroll
    for (int ht = 0; ht < 4; ++ht) {
      int hloc = qh*64 + ht*16 + lr;
      float bb = eb1[e*1024 + c*128 + hloc];
      #pragma unroll
      for (int r = 0; r < 4; ++r) {
        int orow = rh*16 + lq*4 + r;
        float v = fmaxf(acc1[ht][r] + bb, 0.f);
        unsigned short hh = f2bf(v);
        int us = (orow*16 + ((hloc >> 3) ^ (orow & 7)))*8 + (hloc & 7);
        h1h[us] = hh; h1l[us] = f2bf(v - bf2f(hh));
      }
    }
    __syncthreads();
    #pragma unroll
    for (int ks = 0; ks < 4; ++ks) {
      int aoff = (arow*16 + ((ks*4 + lq) ^ rsw))*8;
      bf16x8 ah = *(const bf16x8*)&h1h[aoff];
      bf16x8 al = *(const bf16x8*)&h1l[aoff];
      #pragma unroll
      for (int dt = 0; dt < 8; ++dt) {
        int dtile = qh*8 + dt;
        size_t bo = ewb + ((size_t)(dtile*32 + c*4 + ks)*64 + lane)*8;
        bf16x8 bh = *(const bf16x8*)&w2th[bo];
        bf16x8 bl = *(const bf16x8*)&w2tl[bo];
        acc2[dt] = __builtin_amdgcn_mfma_f32_16x16x32_bf16(ah, bh, acc2[dt], 0, 0, 0);
        acc2[dt] = __builtin_amdgcn_mfma_f32_16x16x32_bf16(ah, bl, acc2[dt], 0, 0, 0);
        acc2[dt] = __builtin_amdgcn_mfma_f32_16x16x32_bf16(al, bh, acc2[dt], 0, 0, 0);
      }
    }
  }
  #pragma unroll
  for (int dt = 0; dt < 8; ++dt) {
    int d = qh*128 + dt*16 + lr;
    float b2 = (c == 0) ? eb2[e*256 + d] : 0.f;
    #pragma unroll
    for (int r = 0; r < 4; ++r) {
      int orow = rh*16 + lq*4 + r;
      if (orow < n)
        atomicAdd(&moe[(size_t)rws[orow]*256 + d], gws[orow]*(acc2[dt][r] + b2));
    }
  }
}

// ================= load-balance loss
__global__ void k_lb(const float* __restrict__ gsum, float* __restrict__ out_lb) {
  int t = threadIdx.x;
  float term = 0.f;
  if (t < 16) {
    float D = gsum[t] * (1.f/4096.f);
    term = D * logf(D + 1e-8f);
  }
  #pragma unroll
  for (int o = 8; o > 0; o >>= 1) term += __shfl_down(term, o, 64);
  if (t == 0) *out_lb = term;
}

// ================= LayerNorm(moe + feat) -> y bf16 hi/lo =================
__global__ __launch_bounds__(256) void k_ln(const float* __restrict__ feat,
    const float* __restrict__ moe, const float* __restrict__ g, const float* __restrict__ bp,
    unsigned short* __restrict__ yh, unsigned short* __restrict__ yl) {
  const int r = blockIdx.x, t = threadIdx.x;
  float v = moe[(size_t)r*256 + t] + feat[(size_t)r*256 + t];
  float s = v, q = v * v;
  #pragma unroll
  for (int o = 32; o > 0; o >>= 1) {
    s += __shfl_down(s, o, 64);
    q += __shfl_down(q, o, 64);
  }
  __shared__ float ss[4], qq[4];
  int wv = t >> 6;
  if ((t & 63) == 0) { ss[wv] = s; qq[wv] = q; }
  __syncthreads();
  float S = ss[0]+ss[1]+ss[2]+ss[3];
  float Q = qq[0]+qq[1]+qq[2]+qq[3];
  float mu  = S * (1.f/256.f);
  float var = Q * (1.f/256.f) - mu*mu;
  float inv = rsqrtf(var + 1e-5f);
  float y = (v - mu) * inv * g[t] + bp[t];
  unsigned short h = f2bf(y);
  yh[(size_t)r*256 + t] = h;
  yl[(size_t)r*256 + t] = f2bf(y - bf2f(h));
}

// ================= output GEMM v2: bf16x2 3-term MFMA, no LDS =================
__global__ __launch_bounds__(256) void k_out(const unsigned short* __restrict__ yh,
    const unsigned short* __restrict__ yl,
    const unsigned short* __restrict__ owh, const unsigned short* __restrict__ owl,
    const float* __restrict__ ob, float* __restrict__ out) {
  const int t = threadIdx.x;
  const int r0 = blockIdx.x * 32;
  const int lane = t & 63, wv = t >> 6;
  const int lr = lane & 15, lq = lane >> 4;
  const int ntile = blockIdx.y*4 + wv;
  f32x4 acc[2];
  acc[0] = (f32x4){0.f,0.f,0.f,0.f};
  acc[1] = (f32x4){0.f,0.f,0.f,0.f};
  #pragma unroll
  for (int ks = 0; ks < 8; ++ks) {
    bf16x8 bh = *(const bf16x8*)&owh[((size_t)(ntile*8 + ks)*64 + lane)*8];
    bf16x8 bl = *(const bf16x8*)&owl[((size_t)(ntile*8 + ks)*64 + lane)*8];
    #pragma unroll
    for (int rt = 0; rt < 2; ++rt) {
      size_t ao = (size_t)(r0 + rt*16 + lr)*256 + ks*32 + lq*8;
      bf16x8 ah = *(const bf16x8*)&yh[ao];
      bf16x8 al = *(const bf16x8*)&yl[ao];
      acc[rt] = __builtin_amdgcn_mfma_f32_16x16x32_bf16(ah, bh, acc[rt], 0, 0, 0);
      acc[rt] = __builtin_amdgcn_mfma_f32_16x16x32_bf16(ah, bl, acc[rt], 0, 0, 0);
      acc[rt] = __builtin_amdgcn_mfma_f32_16x16x32_bf16(al, bh, acc[rt], 0, 0, 0);
    }
  }
  const int col = ntile*16 + lr;
  if (col < NCLS) {
    float bb = ob[col];
    #pragma unroll
    for (int rt = 0; rt < 2; ++rt)
      #pragma unroll
      for (int r = 0; r < 4; ++r)
        out[(size_t)(r0 + rt*16 + lq*4 + r)*NCLS + col] = acc[rt][r] + bb;
  }
}

// ================= launch =================
extern "C" void kernel_launch(void* const* d_in, const int* in_sizes, int n_in,
                              void* d_out, int out_size, void* d_ws, size_t ws_size,
                              hipStream_t stream) {
  const float* x   = (const float*)d_in[0];
  const float* c1w = (const float*)d_in[1];
  const float* c1b = (const float*)d_in[2];
  const float* c2w = (const float*)d_in[3];
  const float* c2b = (const float*)d_in[4];
  const float* c3w = (const float*)d_in[5];
  const float* c3b = (const float*)d_in[6];
  const float* fcw = (const float*)d_in[7];
  const float* fcb = (const float*)d_in[8];
  const float* gw  = (const float*)d_in[9];
  const float* gb  = (const float*)d_in[10];
  const float* ew1 = (const float*)d_in[11];
  const float* eb1 = (const float*)d_in[12];
  const float* ew2 = (const float*)d_in[13];
  const float* eb2 = (const float*)d_in[14];
  const float* lng = (const float*)d_in[15];
  const float* lnb = (const float*)d_in[16];
  const float* ow  = (const float*)d_in[17];
  const float* ob  = (const float*)d_in[18];
  char* ws = (char*)d_ws;
  float* Bb   = (float*)(ws + OFF_B);
  float* P0   = (float*)(ws + OFF_P0);
  float* P1   = (float*)(ws + OFF_P1);
  float* P2   = (float*)(ws + OFF_P2);
  float* P3   = (float*)(ws + OFF_P3);
  unsigned short* Chh = (unsigned short*)(ws + OFF_CHH);
  unsigned short* Chl = (unsigned short*)(ws + OFF_CHL);
  unsigned short* wBh = (unsigned short*)(ws + OFF_CHH);   // aliases Chh (written after conv12)
  unsigned short* wBl = (unsigned short*)(ws + OFF_WBL);
  unsigned short* wA1h = (unsigned short*)(ws + OFF_WA1H);
  unsigned short* wA1l = (unsigned short*)(ws + OFF_WA1L);
  unsigned short* wAh = (unsigned short*)(ws + OFF_FEAT);  // aliases feat (written later)
  unsigned short* wAl = (unsigned short*)(ws + OFF_WAL);
  unsigned short* w1th = (unsigned short*)(ws + OFF_W1TH);
  unsigned short* w1tl = (unsigned short*)(ws + OFF_W1TL);
  unsigned short* w2th = (unsigned short*)(ws + OFF_W2TH);
  unsigned short* w2tl = (unsigned short*)(ws + OFF_W2TL);
  unsigned short* wfh = (unsigned short*)(ws + OFF_WFCH);
  unsigned short* wfl = (unsigned short*)(ws + OFF_WFCL);
  unsigned short* owph = (unsigned short*)(ws + OFF_OWH);
  unsigned short* owpl = (unsigned short*)(ws + OFF_OWL);
  unsigned short* yh = (unsigned short*)(ws + OFF_P0);     // aliases P0 (dead after gate)
  unsigned short* yl = (unsigned short*)(ws + OFF_P1);     // aliases P1
  float* feat = (float*)(ws + OFF_FEAT);
  float* moe  = (float*)(ws + OFF_MOE);
  int*   cnt  = (int*)(ws + OFF_CNT);
  float* gsum = (float*)(ws + OFF_GSUM);
  int*   lrow = (int*)(ws + OFF_LROW);
  float* lgv  = (float*)(ws + OFF_LG);
  float* outp = (float*)d_out;

  hipMemsetAsync(ws + OFF_MOE, 0, 4194304 + 128, stream);

  hipLaunchKernelGGL(k_wt1b,   dim3(4),       dim3(256), 0, stream, c1w, wA1h, wA1l);
  hipLaunchKernelGGL(k_wt2b,   dim3(72),      dim3(256), 0, stream, c2w, wBh, wBl);
  hipLaunchKernelGGL(k_wt3b,   dim3(288),     dim3(256), 0, stream, c3w, wAh, wAl);
  hipLaunchKernelGGL(k_conv12, dim3(4096),    dim3(512), 0, stream, x, wA1h, wA1l, c1b, wBh, wBl, c2b, Bb);
  hipLaunchKernelGGL(k_conv3,  dim3(4096),    dim3(256), 0, stream, Bb, wAh, wAl, c3b, Chh, Chl);
  // Bb dead now -> build ALL packed weights that live in its region
  hipLaunchKernelGGL(k_pack,   dim3(16, 4, 16), dim3(256), 0, stream, ew1, w1th, w1tl, 256, 1024);
  hipLaunchKernelGGL(k_pack,   dim3(4, 16, 16), dim3(256), 0, stream, ew2, w2th, w2tl, 1024, 256);
  hipLaunchKernelGGL(k_pack,   dim3(4, 32, 1),  dim3(256), 0, stream, fcw, wfh, wfl, 2048, 256);
  hipLaunchKernelGGL(k_packo,  dim3(1024),    dim3(256), 0, stream, ow, owph, owpl);
  hipLaunchKernelGGL(k_fc,     dim3(128, 1, 4), dim3(256), 0, stream, Chh, Chl, wfh, wfl, P0, P1, P2, P3);
  hipLaunchKernelGGL(k_gate,   dim3(256),     dim3(256), 0, stream, P0, P1, P2, P3, fcb, gw, gb,
                     feat, cnt, gsum, lrow, lgv);
  hipLaunchKernelGGL(k_moe,    dim3(128, 16, 8), dim3(256), 0, stream, feat, w1th, w1tl, w2th, w2tl,
                     eb1, eb2, cnt, lrow, lgv, moe);
  hipLaunchKernelGGL(k_lb,     dim3(1),       dim3(64),  0, stream, gsum, outp + (size_t)NB*NCLS);
  hipLaunchKernelGGL(k_ln,     dim3(4096),    dim3(256), 0, stream, feat, moe, lng, lnb, yh, yl);
  hipLaunchKernelGGL(k_out,    dim3(128, 16), dim3(256), 0, stream, yh, yl, owph, owpl, ob, outp);
}

// Round 17
// 808.593 us; speedup vs baseline: 1.1129x; 1.0284x over previous
//
#include <hip/hip_runtime.h>
#include <hip/hip_bf16.h>

typedef short bf16x8 __attribute__((ext_vector_type(8)));
typedef float f32x4 __attribute__((ext_vector_type(4)));

// ---------------- problem sizes ----------------
#define NB   4096
#define NEXP 16
#define DDIM 256
#define HDIM 1024
#define NCLS 1000

// ---------------- workspace layout (bytes) ----------------
// NOTE: Bb (conv2 out, 67 MB at offset 0) is live from conv12 until conv3 completes.
// ALL packed-weight regions below OFF_CHH alias Bb -> their pack kernels MUST run after conv3.
#define OFF_B    ((size_t)0)
#define OFF_P0   ((size_t)0)           // f32 [4096][256] FC partial (kq 0); ALSO yh after gate
#define OFF_P1   ((size_t)4194304)     // f32 [4096][256] FC partial (kq 1); ALSO yl after gate
#define OFF_W1TH ((size_t)8388608)     // bf16 packed [16][64 ht][8 ks][64 lane][8]  8 MB
#define OFF_W1TL ((size_t)16777216)
#define OFF_W2TH ((size_t)25165824)    // bf16 packed [16][16 dt][32 ks][64 lane][8] 8 MB
#define OFF_W2TL ((size_t)33554432)
#define OFF_WFCH ((size_t)41943040)    // fcw packed hi (1 MB)
#define OFF_WFCL ((size_t)42991616)    // fcw packed lo (1 MB)
#define OFF_P2   ((size_t)44040192)    // f32 [4096][256] FC partial (kq 2)
#define OFF_P3   ((size_t)48234496)    // f32 [4096][256] FC partial (kq 3)
#define OFF_OWH  ((size_t)52428800)    // ow packed hi [64 nt][8 ks][64][8] (512 KB)
#define OFF_OWL  ((size_t)53477376)
#define OFF_CHH  ((size_t)67108864)    // conv3 out hi bf16 [4096][2048]; ALSO wBh/wBl/wA1 before conv12
#define OFF_CHL  ((size_t)83886080)    // conv3 out lo bf16
#define OFF_WBL  ((size_t)67145728)
#define OFF_WA1H ((size_t)67182592)
#define OFF_WA1L ((size_t)67184640)
#define OFF_FEAT ((size_t)100663296)   // f32 [4096][256]; ALSO wAh/wAl (288 KB) before k_gate
#define OFF_WAL  ((size_t)100810752)
#define OFF_MOE  ((size_t)104857600)   // f32 [4096][256]
#define OFF_CNT  ((size_t)109051904)   // int [16]
#define OFF_GSUM ((size_t)109051968)   // f32 [16]
#define OFF_LROW ((size_t)109052032)   // int [16][4096]
#define OFF_LG   ((size_t)109314176)   // f32 [16][4096]

__device__ inline unsigned short f2bf(float v) {
  __hip_bfloat16 h = __float2bfloat16(v);
  return *(unsigned short*)&h;
}
__device__ inline float bf2f(unsigned short u) {
  union { unsigned int i; float f; } c; c.i = ((unsigned int)u) << 16; return c.f;
}

// ====== conv1 weight prep: c1w[oc][27] -> wA1[oc][32 K] bf16 hi/lo (K=ic*9+tap, pad 32)
__global__ __launch_bounds__(256) void k_wt1b(const float* __restrict__ w,
    unsigned short* __restrict__ oh, unsigned short* __restrict__ ol) {
  int i = blockIdx.x*256 + threadIdx.x;
  if (i >= 1024) return;
  int k = i & 31, oc = i >> 5;
  float v = (k < 27) ? w[oc*27 + k] : 0.f;
  unsigned short h = f2bf(v);
  oh[i] = h;
  ol[i] = f2bf(v - bf2f(h));
}

// ====== conv2 weight prep: c2w[oc][ic][tap] -> wBh/wBl[tap][oc][ic] bf16 hi/lo ======
__global__ __launch_bounds__(256) void k_wt2b(const float* __restrict__ w,
    unsigned short* __restrict__ wBh, unsigned short* __restrict__ wBl) {
  int i = blockIdx.x*256 + threadIdx.x;
  if (i >= 9*64*32) return;
  int ic = i & 31, rem = i >> 5;
  int oc = rem & 63, tap = rem >> 6;
  float v = w[(oc*32 + ic)*9 + tap];
  unsigned short h = f2bf(v);
  wBh[i] = h;
  wBl[i] = f2bf(v - bf2f(h));
}

// ====== MFMA-native weight pack: in[e][R=k][C=n] -> packed[e][n/16][R/32][64 lane][8] hi/lo
__global__ __launch_bounds__(256) void k_pack(const float* __restrict__ in,
    unsigned short* __restrict__ oh, unsigned short* __restrict__ ol, int R, int C) {
  __shared__ float tile[64][65];
  const int t = threadIdx.x;
  const int e = blockIdx.z;
  const size_t eb = (size_t)e * R * C;
  const int c0 = blockIdx.x*64, r0 = blockIdx.y*64;
  const int cc = t & 63, r4 = t >> 6;
  #pragma unroll
  for (int j = 0; j < 16; ++j) {
    int rr = r4 + j*4;
    tile[rr][cc] = in[eb + (size_t)(r0+rr)*C + c0 + cc];
  }
  __syncthreads();
  const int K32 = R >> 5;
  #pragma unroll
  for (int j = 0; j < 16; ++j) {
    int idx = t + j*256;
    int jin = idx & 7, lane = (idx >> 3) & 63, ksl = (idx >> 9) & 1, ntl = idx >> 10;
    int kl = ksl*32 + ((lane >> 4) << 3) + jin;
    int nl = ntl*16 + (lane & 15);
    float v = tile[kl][nl];
    unsigned short h = f2bf(v);
    size_t o = eb + ((size_t)(((c0 >> 4) + ntl)*K32 + (r0 >> 5) + ksl)*64 + lane)*8 + jin;
    oh[o] = h;
    ol[o] = f2bf(v - bf2f(h));
  }
}

// ====== ow pack: ow[256 k][1000 n] -> packed[64 nt][8 ks][64 lane][8] hi/lo, zero pad n>=1000
__global__ __launch_bounds__(256) void k_packo(const float* __restrict__ ow,
    unsigned short* __restrict__ oh, unsigned short* __restrict__ ol) {
  int i = blockIdx.x*256 + threadIdx.x;   // over 64*8*64*8 = 262144
  int j = i & 7, lane = (i >> 3) & 63, ks = (i >> 9) & 7, nt = i >> 12;
  int k = ks*32 + ((lane >> 4) << 3) + j;
  int n = nt*16 + (lane & 15);
  float v = (n < NCLS) ? ow[(size_t)k*NCLS + n] : 0.f;
  unsigned short h = f2bf(v);
  oh[i] = h;
  ol[i] = f2bf(v - bf2f(h));
}

// ============ fused conv1(reg-im2col bf16x2 MFMA) + conv2(bf16x2 MFMA, 3-term) per image ====
// conv1: xs pre-converted to packed u32 (lo<<16 | hi) at load; per-pass build is 16 u32 LDS
// loads + v_perm_b32 pairs (no cvt chains in loop). Wave = (oct1, row-pair ly0, col-half xh).
__global__ __launch_bounds__(512, 4) void k_conv12(const float* __restrict__ x,
    const unsigned short* __restrict__ wA1h, const unsigned short* __restrict__ wA1l,
    const float* __restrict__ b1,
    const unsigned short* __restrict__ wBh, const unsigned short* __restrict__ wBl,
    const float* __restrict__ b2, float* __restrict__ outB) {
  __shared__ unsigned int xsu[3*34*36];     // packed bf16 hi/lo image (14.7 KB)
  __shared__ unsigned short ishB[2][10368]; // conv1-out hi/lo swizzled (41.5 KB); reused for store
  __shared__ float bs1[32];
  __shared__ float bs2[64];
  const int t = threadIdx.x;
  const int img = blockIdx.x;
  for (int i = t; i < 3*34*36; i += 512) xsu[i] = 0u;
  {
    unsigned int* z = (unsigned int*)&ishB[0][0];
    for (int i = t; i < 10368; i += 512) z[i] = 0u;
  }
  __syncthreads();
  for (int i = t; i < 3072; i += 512) {
    int ic = i >> 10, rem = i & 1023, y = rem >> 5, xx = rem & 31;
    float v = x[(size_t)img*3072 + i];
    unsigned short h = f2bf(v);
    unsigned short l = f2bf(v - bf2f(h));
    xsu[ic*34*36 + (y+1)*36 + (xx+1)] = ((unsigned int)l << 16) | (unsigned int)h;
  }
  if (t < 32) bs1[t] = b1[t];
  else if (t >= 64 && t < 128) bs2[t-64] = b2[t-64];

  const int lane = t & 63, wvv = t >> 6;
  const int lr = lane & 15, lq = lane >> 4;

  const int oct1 = wvv & 1;
  const bf16x8 a1h = *(const bf16x8*)&wA1h[((oct1*16 + lr) << 5) + lq*8];
  const bf16x8 a1l = *(const bf16x8*)&wA1l[((oct1*16 + lr) << 5) + lq*8];

  // per-lane k -> xsu offset table (k = lq*8 + j); koff < 0 marks padded k (>= 27)
  int koff[8];
  #pragma unroll
  for (int j = 0; j < 8; ++j) {
    int k = lq*8 + j;
    if (k < 27) {
      int ic = k/9, tap = k - ic*9, dy = tap/3, dx = tap - dy*3;
      koff[j] = ic*34*36 + dy*36 + dx;
    } else koff[j] = -1;
  }
  __syncthreads();

  // ---- conv1 via MFMA, barrier-free: 8 passes of 4 pre-pool rows ----
  {
    const int rp  = wvv >> 1;
    const int ly0 = (rp >> 1) << 1;      // 0 or 2
    const int xh  = rp & 1;
    const int X   = xh*16 + lr;          // column for this lane's B elements
    for (int ps = 0; ps < 8; ++ps) {
      const int baseA = (ps*4 + ly0)*36 + X;
      union { unsigned int u[4]; bf16x8 v; } bhA, blA, bhB, blB;
      #pragma unroll
      for (int jj = 0; jj < 4; ++jj) {
        unsigned int e0A = (koff[2*jj]   >= 0) ? xsu[koff[2*jj]   + baseA] : 0u;
        unsigned int e1A = (koff[2*jj+1] >= 0) ? xsu[koff[2*jj+1] + baseA] : 0u;
        unsigned int e0B = (koff[2*jj]   >= 0) ? xsu[koff[2*jj]   + baseA + 36] : 0u;
        unsigned int e1B = (koff[2*jj+1] >= 0) ? xsu[koff[2*jj+1] + baseA + 36] : 0u;
        bhA.u[jj] = __builtin_amdgcn_perm(e1A, e0A, 0x05040100u);  // h1<<16 | h0
        blA.u[jj] = __builtin_amdgcn_perm(e1A, e0A, 0x07060302u);  // l1<<16 | l0
        bhB.u[jj] = __builtin_amdgcn_perm(e1B, e0B, 0x05040100u);
        blB.u[jj] = __builtin_amdgcn_perm(e1B, e0B, 0x07060302u);
      }
      f32x4 aA = (f32x4){0.f,0.f,0.f,0.f}, aB = (f32x4){0.f,0.f,0.f,0.f};
      aA = __builtin_amdgcn_mfma_f32_16x16x32_bf16(a1h, bhA.v, aA, 0, 0, 0);
      aB = __builtin_amdgcn_mfma_f32_16x16x32_bf16(a1h, bhB.v, aB, 0, 0, 0);
      aA = __builtin_amdgcn_mfma_f32_16x16x32_bf16(a1h, blA.v, aA, 0, 0, 0);
      aB = __builtin_amdgcn_mfma_f32_16x16x32_bf16(a1h, blB.v, aB, 0, 0, 0);
      aA = __builtin_amdgcn_mfma_f32_16x16x32_bf16(a1l, bhA.v, aA, 0, 0, 0);
      aB = __builtin_amdgcn_mfma_f32_16x16x32_bf16(a1l, bhB.v, aB, 0, 0, 0);
      #pragma unroll
      for (int r = 0; r < 4; ++r) {
        float v = fmaxf(aA[r], aB[r]);             // y-pool (row pair in-registers)
        v = fmaxf(v, __shfl_xor(v, 1, 64));        // x-pool (col pair)
        if ((lr & 1) == 0) {
          int oc = oct1*16 + lq*4 + r;             // D row = (lane>>4)*4+reg
          int Xp = xh*8 + (lr >> 1);
          int Yp = ps*2 + (ly0 >> 1);
          float m = fmaxf(v + bs1[oc], 0.f);
          unsigned short h = f2bf(m);
          unsigned short l = f2bf(m - bf2f(h));
          int pl = (Yp+1)*18 + (Xp+1);
          int sl = pl*4 + ((oc >> 3) ^ ((pl >> 1) & 3));
          int us = (sl << 3) | (oc & 7);
          ishB[0][us] = h; ishB[1][us] = l;
        }
      }
    }
  }
  __syncthreads();
  // ---- conv2 bf16x2 MFMA (3-term) + fused pool + relu ----
  {
    const int mtp = (wvv & 1)*2;
    const int rq = wvv >> 1;
    f32x4 acc[2][4];
    #pragma unroll
    for (int i = 0; i < 2; ++i)
      #pragma unroll
      for (int j = 0; j < 4; ++j) acc[i][j] = (f32x4){0.f,0.f,0.f,0.f};
    bf16x8 nAh[2], nAl[2];
    #pragma unroll
    for (int m = 0; m < 2; ++m) {
      int off = (((mtp+m)*16 + lr) << 5) + lq*8;
      nAh[m] = *(const bf16x8*)&wBh[off];
      nAl[m] = *(const bf16x8*)&wBl[off];
    }
    #pragma unroll
    for (int tap = 0; tap < 9; ++tap) {
      bf16x8 ah0 = nAh[0], al0 = nAl[0], ah1 = nAh[1], al1 = nAl[1];
      if (tap < 8) {
        #pragma unroll
        for (int m = 0; m < 2; ++m) {
          int off = (((tap+1)*64 + (mtp+m)*16 + lr) << 5) + lq*8;
          nAh[m] = *(const bf16x8*)&wBh[off];
          nAl[m] = *(const bf16x8*)&wBl[off];
        }
      }
      const int dy = tap/3, dx = tap - dy*3;
      #pragma unroll
      for (int j = 0; j < 4; ++j) {
        int pl = (rq*4 + j + dy)*18 + lr + dx;
        int sl = pl*4 + (lq ^ ((pl >> 1) & 3));
        bf16x8 bh = *(const bf16x8*)&ishB[0][sl << 3];
        bf16x8 bl = *(const bf16x8*)&ishB[1][sl << 3];
        acc[0][j] = __builtin_amdgcn_mfma_f32_16x16x32_bf16(ah0, bh, acc[0][j], 0, 0, 0);
        acc[1][j] = __builtin_amdgcn_mfma_f32_16x16x32_bf16(ah1, bh, acc[1][j], 0, 0, 0);
        acc[0][j] = __builtin_amdgcn_mfma_f32_16x16x32_bf16(ah0, bl, acc[0][j], 0, 0, 0);
        acc[1][j] = __builtin_amdgcn_mfma_f32_16x16x32_bf16(ah1, bl, acc[1][j], 0, 0, 0);
        acc[0][j] = __builtin_amdgcn_mfma_f32_16x16x32_bf16(al0, bh, acc[0][j], 0, 0, 0);
        acc[1][j] = __builtin_amdgcn_mfma_f32_16x16x32_bf16(al1, bh, acc[1][j], 0, 0, 0);
      }
    }
    __syncthreads();
    float* ps2 = (float*)&ishB[0][0];
    #pragma unroll
    for (int m = 0; m < 2; ++m)
      #pragma unroll
      for (int k = 0; k < 2; ++k)
        #pragma unroll
        for (int r = 0; r < 4; ++r) {
          float v = fmaxf(acc[m][2*k][r], acc[m][2*k+1][r]);
          v = fmaxf(v, __shfl_xor(v, 1, 64));
          if ((lr & 1) == 0) {
            int oc = (mtp + m)*16 + lq*4 + r;
            int Y = rq*2 + k, X = lr >> 1;
            ps2[oc*65 + Y*8 + X] = fmaxf(v + bs2[oc], 0.f);
          }
        }
    __syncthreads();
    float* op = outB + (size_t)img*4096;
    #pragma unroll
    for (int jj = 0; jj < 8; ++jj) {
      int i = jj*512 + t;
      op[i] = ps2[(i >> 6)*65 + (i & 63)];
    }
  }
}

// ================= conv3 weight prep: c3w[oc][ic][tap] -> wAh/wAl[tap][oc][ic] bf16 hi/lo
__global__ __launch_bounds__(256) void k_wt3b(const float* __restrict__ w,
    unsigned short* __restrict__ wAh, unsigned short* __restrict__ wAl) {
  int i = blockIdx.x*256 + threadIdx.x;
  if (i >= 9*128*64) return;
  int ic = i & 63, rem = i >> 6;
  int oc = rem & 127, tap = rem >> 7;
  float v = w[(oc*64 + ic)*9 + tap];
  unsigned short h = f2bf(v);
  wAh[i] = h;
  wAl[i] = f2bf(v - bf2f(h));
}

// ================= conv3 v5: bf16x2 split MFMA (3-term); emits C as bf16 hi/lo ==========
__global__ __launch_bounds__(256) void k_conv3(const float* __restrict__ inB,
    const unsigned short* __restrict__ wAh, const unsigned short* __restrict__ wAl,
    const float* __restrict__ bias,
    unsigned short* __restrict__ Chh, unsigned short* __restrict__ Chl) {
  __shared__ unsigned short ish[2][6400];
  const int t = threadIdx.x;
  const int img = blockIdx.x;
  {
    unsigned int* z = (unsigned int*)&ish[0][0];
    #pragma unroll
    for (int j = 0; j < 25; ++j) z[t + 256*j] = 0u;
  }
  __syncthreads();
  {
    const float* src = inB + (size_t)img*4096;
    #pragma unroll
    for (int j = 0; j < 16; ++j) {
      int f = t + 256*j;
      int ic = f >> 6, p = f & 63;
      int pl = ((p >> 3) + 1)*10 + (p & 7) + 1;
      float v = src[f];
      unsigned short h = f2bf(v);
      unsigned short l = f2bf(v - bf2f(h));
      int u = pl*64 + ic;
      int us = (((u >> 3) ^ (pl & 7)) << 3) | (u & 7);
      ish[0][us] = h; ish[1][us] = l;
    }
  }
  __syncthreads();

  const int lane = t & 63, wid = t >> 6;
  const int lr = lane & 15, lq = lane >> 4;
  const int mt0 = wid*2;
  const int yb = lr >> 3, xb = lr & 7;

  f32x4 acc[2][4];
  #pragma unroll
  for (int i = 0; i < 2; ++i)
    #pragma unroll
    for (int j = 0; j < 4; ++j) acc[i][j] = (f32x4){0.f,0.f,0.f,0.f};

  for (int tap = 0; tap < 9; ++tap) {
    const int dy = tap/3, dx = tap - dy*3;
    #pragma unroll
    for (int kc = 0; kc < 2; ++kc) {
      const int kb = kc*32 + lq*8;
      const int wbase = ((tap << 7) << 6) + kb;
      bf16x8 a0h = *(const bf16x8*)&wAh[wbase + ((mt0*16 + lr) << 6)];
      bf16x8 a0l = *(const bf16x8*)&wAl[wbase + ((mt0*16 + lr) << 6)];
      bf16x8 a1h = *(const bf16x8*)&wAh[wbase + (((mt0+1)*16 + lr) << 6)];
      bf16x8 a1l = *(const bf16x8*)&wAl[wbase + (((mt0+1)*16 + lr) << 6)];
      #pragma unroll
      for (int nt = 0; nt < 4; ++nt) {
        const int pl = (2*nt + yb + dy)*10 + xb + dx;
        const int u = pl*64 + kb;
        const int us = (((u >> 3) ^ (pl & 7)) << 3);
        bf16x8 bh = *(const bf16x8*)&ish[0][us];
        bf16x8 bl = *(const bf16x8*)&ish[1][us];
        acc[0][nt] = __builtin_amdgcn_mfma_f32_16x16x32_bf16(a0h, bh, acc[0][nt], 0, 0, 0);
        acc[0][nt] = __builtin_amdgcn_mfma_f32_16x16x32_bf16(a0h, bl, acc[0][nt], 0, 0, 0);
        acc[0][nt] = __builtin_amdgcn_mfma_f32_16x16x32_bf16(a0l, bh, acc[0][nt], 0, 0, 0);
        acc[1][nt] = __builtin_amdgcn_mfma_f32_16x16x32_bf16(a1h, bh, acc[1][nt], 0, 0, 0);
        acc[1][nt] = __builtin_amdgcn_mfma_f32_16x16x32_bf16(a1h, bl, acc[1][nt], 0, 0, 0);
        acc[1][nt] = __builtin_amdgcn_mfma_f32_16x16x32_bf16(a1l, bh, acc[1][nt], 0, 0, 0);
      }
    }
  }
  __syncthreads();
  float* stg = (float*)&ish[0][0];   // [128 oc][17]
  #pragma unroll
  for (int mtl = 0; mtl < 2; ++mtl)
    #pragma unroll
    for (int nt = 0; nt < 4; ++nt)
      #pragma unroll
      for (int r = 0; r < 4; ++r) {
        float v = acc[mtl][nt][r];
        v = fmaxf(v, __shfl_xor(v, 1, 64));
        v = fmaxf(v, __shfl_xor(v, 8, 64));
        if ((lane & 9) == 0) {
          int oc = (mt0 + mtl)*16 + lq*4 + r;
          int pix = nt*4 + (xb >> 1);
          stg[oc*17 + pix] = fmaxf(v + bias[oc], 0.f);
        }
      }
  __syncthreads();
  #pragma unroll
  for (int j = 0; j < 8; ++j) {
    int i = t + 256*j;
    float v = stg[(i >> 4)*17 + (i & 15)];
    unsigned short h = f2bf(v);
    Chh[(size_t)img*2048 + i] = h;
    Chl[(size_t)img*2048 + i] = f2bf(v - bf2f(h));
  }
}

// ================= FC GEMM v2: bf16x2 3-term MFMA, no LDS, split-K=4 =================
__global__ __launch_bounds__(256) void k_fc(const unsigned short* __restrict__ Chh,
    const unsigned short* __restrict__ Chl,
    const unsigned short* __restrict__ wfh, const unsigned short* __restrict__ wfl,
    float* __restrict__ P0, float* __restrict__ P1,
    float* __restrict__ P2, float* __restrict__ P3) {
  const int t = threadIdx.x;
  const int r0 = blockIdx.x * 32;
  const int kq = blockIdx.z;
  float* __restrict__ P = (kq == 0) ? P0 : (kq == 1) ? P1 : (kq == 2) ? P2 : P3;
  const int lane = t & 63, wv = t >> 6;
  const int lr = lane & 15, lq = lane >> 4;
  f32x4 acc[2][4];
  #pragma unroll
  for (int i = 0; i < 2; ++i)
    #pragma unroll
    for (int j = 0; j < 4; ++j) acc[i][j] = (f32x4){0.f,0.f,0.f,0.f};
  #pragma unroll 4
  for (int ks = 0; ks < 16; ++ks) {
    bf16x8 ah[2], al[2];
    #pragma unroll
    for (int rt = 0; rt < 2; ++rt) {
      size_t ao = (size_t)(r0 + rt*16 + lr)*2048 + kq*512 + ks*32 + lq*8;
      ah[rt] = *(const bf16x8*)&Chh[ao];
      al[rt] = *(const bf16x8*)&Chl[ao];
    }
    #pragma unroll
    for (int nt = 0; nt < 4; ++nt) {
      size_t bo = ((size_t)((wv*4 + nt)*64 + kq*16 + ks)*64 + lane)*8;
      bf16x8 bh = *(const bf16x8*)&wfh[bo];
      bf16x8 bl = *(const bf16x8*)&wfl[bo];
      acc[0][nt] = __builtin_amdgcn_mfma_f32_16x16x32_bf16(ah[0], bh, acc[0][nt], 0, 0, 0);
      acc[1][nt] = __builtin_amdgcn_mfma_f32_16x16x32_bf16(ah[1], bh, acc[1][nt], 0, 0, 0);
      acc[0][nt] = __builtin_amdgcn_mfma_f32_16x16x32_bf16(ah[0], bl, acc[0][nt], 0, 0, 0);
      acc[1][nt] = __builtin_amdgcn_mfma_f32_16x16x32_bf16(ah[1], bl, acc[1][nt], 0, 0, 0);
      acc[0][nt] = __builtin_amdgcn_mfma_f32_16x16x32_bf16(al[0], bh, acc[0][nt], 0, 0, 0);
      acc[1][nt] = __builtin_amdgcn_mfma_f32_16x16x32_bf16(al[1], bh, acc[1][nt], 0, 0, 0);
    }
  }
  #pragma unroll
  for (int rt = 0; rt < 2; ++rt)
    #pragma unroll
    for (int nt = 0; nt < 4; ++nt)
      #pragma unroll
      for (int r = 0; r < 4; ++r)
        P[(size_t)(r0 + rt*16 + lq*4 + r)*256 + (wv*4 + nt)*16 + lr] = acc[rt][nt][r];
}

// ================= gate: feat = P0+P1+P2+P3+fcb; logits; top-2 softmax; expert lists
__global__ __launch_bounds__(256) void k_gate(const float* __restrict__ P0,
    const float* __restrict__ P1, const float* __restrict__ P2, const float* __restrict__ P3,
    const float* __restrict__ fcb,
    const float* __restrict__ gw, const float* __restrict__ gb,
    float* __restrict__ feat, int* __restrict__ cnt, float* __restrict__ gsum,
    int* __restrict__ lrow, float* __restrict__ lg) {
  __shared__ float ft[16][256];
  __shared__ float lgs[16][16];
  __shared__ float gwl[4096];
  const int t = threadIdx.x;
  const int r0 = blockIdx.x * 16;
  for (int i = t; i < 4096; i += 256) gwl[i] = gw[i];
  float bb = fcb[t];
  #pragma unroll
  for (int r = 0; r < 16; ++r) {
    size_t off = (size_t)(r0+r)*256 + t;
    float v = P0[off] + P1[off] + P2[off] + P3[off] + bb;
    ft[r][t] = v;
    feat[off] = v;
  }
  __syncthreads();
  {
    int r = t >> 4, e = t & 15;
    float s = gb[e];
    for (int k = 0; k < 256; ++k) s = fmaf(ft[r][k], gwl[k*16 + e], s);
    lgs[r][e] = s;
  }
  __syncthreads();
  if (t < 16) {
    int r = t;
    float v1 = -3.402823e38f, v2 = -3.402823e38f;
    int i1 = 0, i2 = 0;
    for (int e = 0; e < 16; ++e) {
      float v = lgs[r][e];
      if (v > v1)      { v2 = v1; i2 = i1; v1 = v; i1 = e; }
      else if (v > v2) { v2 = v;  i2 = e; }
    }
    float ex = __expf(v2 - v1);
    float g1 = 1.f / (1.f + ex);
    float g2 = ex  / (1.f + ex);
    int row = r0 + r;
    int p1 = atomicAdd(&cnt[i1], 1); lrow[i1*4096 + p1] = row; lg[i1*4096 + p1] = g1;
    int p2 = atomicAdd(&cnt[i2], 1); lrow[i2*4096 + p2] = row; lg[i2*4096 + p2] = g2;
    atomicAdd(&gsum[i1], g1);
    atomicAdd(&gsum[i2], g2);
  }
}

// ================= MoE v4: 32-row tiles x split-K(8), bf16x2 MFMA 3-term, packed weights
__global__ __launch_bounds__(256) void k_moe(const float* __restrict__ feat,
    const unsigned short* __restrict__ w1th, const unsigned short* __restrict__ w1tl,
    const unsigned short* __restrict__ w2th, const unsigned short* __restrict__ w2tl,
    const float* __restrict__ eb1, const float* __restrict__ eb2,
    const int* __restrict__ cnt, const int* __restrict__ lrow, const float* __restrict__ lgw,
    float* __restrict__ moe) {
  const int e = blockIdx.y;
  const int n_e = cnt[e];
  const int start = blockIdx.x * 32;
  if (start >= n_e) return;
  const int c = blockIdx.z;
  const int n = min(32, n_e - start);
  __shared__ unsigned short fh[8192], fl[8192];
  __shared__ unsigned short h1h[4096], h1l[4096];
  __shared__ int   rws[32];
  __shared__ float gws[32];
  const int t = threadIdx.x;
  if (t < 32) {
    rws[t] = (t < n) ? lrow[e*4096 + start + t] : 0;
    gws[t] = (t < n) ? lgw[e*4096 + start + t] : 0.f;
  }
  __syncthreads();
  for (int j = 0; j < 32; ++j) {
    float v = (j < n) ? feat[(size_t)rws[j]*256 + t] : 0.f;
    unsigned short h = f2bf(v);
    int us = (j*32 + ((t >> 3) ^ (j & 7)))*8 + (t & 7);
    fh[us] = h; fl[us] = f2bf(v - bf2f(h));
  }
  const int lane = t & 63, wv = t >> 6;
  const int lr = lane & 15, lq = lane >> 4;
  const int rh = wv & 1, qh = wv >> 1;
  const int arow = rh*16 + lr;
  const int rsw = arow & 7;
  const size_t ewb = (size_t)e << 18;

  f32x4 acc2[8];
  #pragma unroll
  for (int i = 0; i < 8; ++i) acc2[i] = (f32x4){0.f,0.f,0.f,0.f};

  __syncthreads();

  {
    f32x4 acc1[4];
    #pragma unroll
    for (int i = 0; i < 4; ++i) acc1[i] = (f32x4){0.f,0.f,0.f,0.f};
    #pragma unroll
    for (int ks = 0; ks < 8; ++ks) {
      int aoff = (arow*32 + ((ks*4 + lq) ^ rsw))*8;
      bf16x8 ah = *(const bf16x8*)&fh[aoff];
      bf16x8 al = *(const bf16x8*)&fl[aoff];
      #pragma unroll
      for (int ht = 0; ht < 4; ++ht) {
        int htile = c*8 + qh*4 + ht;
        size_t bo = ewb + ((size_t)(htile*8 + ks)*64 + lane)*8;
        bf16x8 bh = *(const bf16x8*)&w1th[bo];
        bf16x8 bl = *(const bf16x8*)&w1tl[bo];
        acc1[ht] = __builtin_amdgcn_mfma_f32_16x16x32_bf16(ah, bh, acc1[ht], 0, 0, 0);
        acc1[ht] = __builtin_amdgcn_mfma_f32_16x16x32_bf16(ah, bl, acc1[ht], 0, 0, 0);
        acc1[ht] = __builtin_amdgcn_mfma_f32_16x16x32_bf16(al, bh, acc1[ht], 0, 0, 0);
      }
    }
    __syncthreads();
    #pragma unroll
    for (int ht = 0; ht < 4; ++ht) {
      int hloc = qh*64 + ht*16 + lr;
      float bb = eb1[e*1024 + c*128 + hloc];
      #pragma unroll
      for (int r = 0; r < 4; ++r) {
        int orow = rh*16 + lq*4 + r;
        float v = fmaxf(acc1[ht][r] + bb, 0.f);
        unsigned short hh = f2bf(v);
        int us = (orow*16 + ((hloc >> 3) ^ (orow & 7)))*8 + (hloc & 7);
        h1h[us] = hh; h1l[us] = f2bf(v - bf2f(hh));
      }
    }
    __syncthreads();
    #pragma unroll
    for (int ks = 0; ks < 4; ++ks) {
      int aoff = (arow*16 + ((ks*4 + lq) ^ rsw))*8;
      bf16x8 ah = *(const bf16x8*)&h1h[aoff];
      bf16x8 al = *(const bf16x8*)&h1l[aoff];
      #pragma unroll
      for (int dt = 0; dt < 8; ++dt) {
        int dtile = qh*8 + dt;
        size_t bo = ewb + ((size_t)(dtile*32 + c*4 + ks)*64 + lane)*8;
        bf16x8 bh = *(const bf16x8*)&w2th[bo];
        bf16x8 bl = *(const bf16x8*)&w2tl[bo];
        acc2[dt] = __builtin_amdgcn_mfma_f32_16x16x32_bf16(ah, bh, acc2[dt], 0, 0, 0);
        acc2[dt] = __builtin_amdgcn_mfma_f32_16x16x32_bf16(ah, bl, acc2[dt], 0, 0, 0);
        acc2[dt] = __builtin_amdgcn_mfma_f32_16x16x32_bf16(al, bh, acc2[dt], 0, 0, 0);
      }
    }
  }
  #pragma unroll
  for (int dt = 0; dt < 8; ++dt) {
    int d = qh*128 + dt*16 + lr;
    float b2 = (c == 0) ? eb2[e*256 + d] : 0.f;
    #pragma unroll
    for (int r = 0; r < 4; ++r) {
      int orow = rh*16 + lq*4 + r;
      if (orow < n)
        atomicAdd(&moe[(size_t)rws[orow]*256 + d], gws[orow]*(acc2[dt][r] + b2));
    }
  }
}

// ================= load-balance loss
__global__ void k_lb(const float* __restrict__ gsum, float* __restrict__ out_lb) {
  int t = threadIdx.x;
  float term = 0.f;
  if (t < 16) {
    float D = gsum[t] * (1.f/4096.f);
    term = D * logf(D + 1e-8f);
  }
  #pragma unroll
  for (int o = 8; o > 0; o >>= 1) term += __shfl_down(term, o, 64);
  if (t == 0) *out_lb = term;
}

// ================= LayerNorm(moe + feat) -> y bf16 hi/lo =================
__global__ __launch_bounds__(256) void k_ln(const float* __restrict__ feat,
    const float* __restrict__ moe, const float* __restrict__ g, const float* __restrict__ bp,
    unsigned short* __restrict__ yh, unsigned short* __restrict__ yl) {
  const int r = blockIdx.x, t = threadIdx.x;
  float v = moe[(size_t)r*256 + t] + feat[(size_t)r*256 + t];
  float s = v, q = v * v;
  #pragma unroll
  for (int o = 32; o > 0; o >>= 1) {
    s += __shfl_down(s, o, 64);
    q += __shfl_down(q, o, 64);
  }
  __shared__ float ss[4], qq[4];
  int wv = t >> 6;
  if ((t & 63) == 0) { ss[wv] = s; qq[wv] = q; }
  __syncthreads();
  float S = ss[0]+ss[1]+ss[2]+ss[3];
  float Q = qq[0]+qq[1]+qq[2]+qq[3];
  float mu  = S * (1.f/256.f);
  float var = Q * (1.f/256.f) - mu*mu;
  float inv = rsqrtf(var + 1e-5f);
  float y = (v - mu) * inv * g[t] + bp[t];
  unsigned short h = f2bf(y);
  yh[(size_t)r*256 + t] = h;
  yl[(size_t)r*256 + t] = f2bf(y - bf2f(h));
}

// ================= output GEMM v2: bf16x2 3-term MFMA, no LDS =================
__global__ __launch_bounds__(256) void k_out(const unsigned short* __restrict__ yh,
    const unsigned short* __restrict__ yl,
    const unsigned short* __restrict__ owh, const unsigned short* __restrict__ owl,
    const float* __restrict__ ob, float* __restrict__ out) {
  const int t = threadIdx.x;
  const int r0 = blockIdx.x * 32;
  const int lane = t & 63, wv = t >> 6;
  const int lr = lane & 15, lq = lane >> 4;
  const int ntile = blockIdx.y*4 + wv;
  f32x4 acc[2];
  acc[0] = (f32x4){0.f,0.f,0.f,0.f};
  acc[1] = (f32x4){0.f,0.f,0.f,0.f};
  #pragma unroll
  for (int ks = 0; ks < 8; ++ks) {
    bf16x8 bh = *(const bf16x8*)&owh[((size_t)(ntile*8 + ks)*64 + lane)*8];
    bf16x8 bl = *(const bf16x8*)&owl[((size_t)(ntile*8 + ks)*64 + lane)*8];
    #pragma unroll
    for (int rt = 0; rt < 2; ++rt) {
      size_t ao = (size_t)(r0 + rt*16 + lr)*256 + ks*32 + lq*8;
      bf16x8 ah = *(const bf16x8*)&yh[ao];
      bf16x8 al = *(const bf16x8*)&yl[ao];
      acc[rt] = __builtin_amdgcn_mfma_f32_16x16x32_bf16(ah, bh, acc[rt], 0, 0, 0);
      acc[rt] = __builtin_amdgcn_mfma_f32_16x16x32_bf16(ah, bl, acc[rt], 0, 0, 0);
      acc[rt] = __builtin_amdgcn_mfma_f32_16x16x32_bf16(al, bh, acc[rt], 0, 0, 0);
    }
  }
  const int col = ntile*16 + lr;
  if (col < NCLS) {
    float bb = ob[col];
    #pragma unroll
    for (int rt = 0; rt < 2; ++rt)
      #pragma unroll
      for (int r = 0; r < 4; ++r)
        out[(size_t)(r0 + rt*16 + lq*4 + r)*NCLS + col] = acc[rt][r] + bb;
  }
}

// ================= launch =================
extern "C" void kernel_launch(void* const* d_in, const int* in_sizes, int n_in,
                              void* d_out, int out_size, void* d_ws, size_t ws_size,
                              hipStream_t stream) {
  const float* x   = (const float*)d_in[0];
  const float* c1w = (const float*)d_in[1];
  const float* c1b = (const float*)d_in[2];
  const float* c2w = (const float*)d_in[3];
  const float* c2b = (const float*)d_in[4];
  const float* c3w = (const float*)d_in[5];
  const float* c3b = (const float*)d_in[6];
  const float* fcw = (const float*)d_in[7];
  const float* fcb = (const float*)d_in[8];
  const float* gw  = (const float*)d_in[9];
  const float* gb  = (const float*)d_in[10];
  const float* ew1 = (const float*)d_in[11];
  const float* eb1 = (const float*)d_in[12];
  const float* ew2 = (const float*)d_in[13];
  const float* eb2 = (const float*)d_in[14];
  const float* lng = (const float*)d_in[15];
  const float* lnb = (const float*)d_in[16];
  const float* ow  = (const float*)d_in[17];
  const float* ob  = (const float*)d_in[18];
  char* ws = (char*)d_ws;
  float* Bb   = (float*)(ws + OFF_B);
  float* P0   = (float*)(ws + OFF_P0);
  float* P1   = (float*)(ws + OFF_P1);
  float* P2   = (float*)(ws + OFF_P2);
  float* P3   = (float*)(ws + OFF_P3);
  unsigned short* Chh = (unsigned short*)(ws + OFF_CHH);
  unsigned short* Chl = (unsigned short*)(ws + OFF_CHL);
  unsigned short* wBh = (unsigned short*)(ws + OFF_CHH);   // aliases Chh (written after conv12)
  unsigned short* wBl = (unsigned short*)(ws + OFF_WBL);
  unsigned short* wA1h = (unsigned short*)(ws + OFF_WA1H);
  unsigned short* wA1l = (unsigned short*)(ws + OFF_WA1L);
  unsigned short* wAh = (unsigned short*)(ws + OFF_FEAT);  // aliases feat (written later)
  unsigned short* wAl = (unsigned short*)(ws + OFF_WAL);
  unsigned short* w1th = (unsigned short*)(ws + OFF_W1TH);
  unsigned short* w1tl = (unsigned short*)(ws + OFF_W1TL);
  unsigned short* w2th = (unsigned short*)(ws + OFF_W2TH);
  unsigned short* w2tl = (unsigned short*)(ws + OFF_W2TL);
  unsigned short* wfh = (unsigned short*)(ws + OFF_WFCH);
  unsigned short* wfl = (unsigned short*)(ws + OFF_WFCL);
  unsigned short* owph = (unsigned short*)(ws + OFF_OWH);
  unsigned short* owpl = (unsigned short*)(ws + OFF_OWL);
  unsigned short* yh = (unsigned short*)(ws + OFF_P0);     // aliases P0 (dead after gate)
  unsigned short* yl = (unsigned short*)(ws + OFF_P1);     // aliases P1
  float* feat = (float*)(ws + OFF_FEAT);
  float* moe  = (float*)(ws + OFF_MOE);
  int*   cnt  = (int*)(ws + OFF_CNT);
  float* gsum = (float*)(ws + OFF_GSUM);
  int*   lrow = (int*)(ws + OFF_LROW);
  float* lgv  = (float*)(ws + OFF_LG);
  float* outp = (float*)d_out;

  hipMemsetAsync(ws + OFF_MOE, 0, 4194304 + 128, stream);

  hipLaunchKernelGGL(k_wt1b,   dim3(4),       dim3(256), 0, stream, c1w, wA1h, wA1l);
  hipLaunchKernelGGL(k_wt2b,   dim3(72),      dim3(256), 0, stream, c2w, wBh, wBl);
  hipLaunchKernelGGL(k_wt3b,   dim3(288),     dim3(256), 0, stream, c3w, wAh, wAl);
  hipLaunchKernelGGL(k_conv12, dim3(4096),    dim3(512), 0, stream, x, wA1h, wA1l, c1b, wBh, wBl, c2b, Bb);
  hipLaunchKernelGGL(k_conv3,  dim3(4096),    dim3(256), 0, stream, Bb, wAh, wAl, c3b, Chh, Chl);
  // Bb dead now -> build ALL packed weights that live in its region
  hipLaunchKernelGGL(k_pack,   dim3(16, 4, 16), dim3(256), 0, stream, ew1, w1th, w1tl, 256, 1024);
  hipLaunchKernelGGL(k_pack,   dim3(4, 16, 16), dim3(256), 0, stream, ew2, w2th, w2tl, 1024, 256);
  hipLaunchKernelGGL(k_pack,   dim3(4, 32, 1),  dim3(256), 0, stream, fcw, wfh, wfl, 2048, 256);
  hipLaunchKernelGGL(k_packo,  dim3(1024),    dim3(256), 0, stream, ow, owph, owpl);
  hipLaunchKernelGGL(k_fc,     dim3(128, 1, 4), dim3(256), 0, stream, Chh, Chl, wfh, wfl, P0, P1, P2, P3);
  hipLaunchKernelGGL(k_gate,   dim3(256),     dim3(256), 0, stream, P0, P1, P2, P3, fcb, gw, gb,
                     feat, cnt, gsum, lrow, lgv);
  hipLaunchKernelGGL(k_moe,    dim3(128, 16, 8), dim3(256), 0, stream, feat, w1th, w1tl, w2th, w2tl,
                     eb1, eb2, cnt, lrow, lgv, moe);
  hipLaunchKernelGGL(k_lb,     dim3(1),       dim3(64),  0, stream, gsum, outp + (size_t)NB*NCLS);
  hipLaunchKernelGGL(k_ln,     dim3(4096),    dim3(256), 0, stream, feat, moe, lng, lnb, yh, yl);
  hipLaunchKernelGGL(k_out,    dim3(128, 16), dim3(256), 0, stream, yh, yl, owph, owpl, ob, outp);
}